// Round 1
// baseline (104986.584 us; speedup 1.0000x reference)
//
#include <hip/hip_runtime.h>

// ---------------------------------------------------------------------------
// MotionGenerator RNN for MI355X (gfx950).
//  - encoder: im2col + bf16 MFMA GEMM (weights are [out,in] == B^T layout)
//  - decoder: persistent kernel, 16 blocks x 256 thr, custom grid barrier,
//             4 barriers/step * 540 steps. fp32 recurrence carry, bf16 GEMMs.
// ws usage ~193 MB.
// ---------------------------------------------------------------------------

typedef unsigned short u16;
typedef __attribute__((ext_vector_type(8))) short short8;
typedef __attribute__((ext_vector_type(4))) float f32x4;

#define GELU_FLG 1
#define BF16_FLG 2
#define DEC_BLOCKS 16

__device__ __forceinline__ float b2f(u16 h){
  union { unsigned u; float f; } c; c.u = ((unsigned)h) << 16; return c.f;
}
__device__ __forceinline__ u16 f2b(float f){
  union { float f; unsigned u; } c; c.f = f;
  return (u16)((c.u + 0x7fffu + ((c.u >> 16) & 1u)) >> 16);   // RNE
}
__device__ __forceinline__ short8 ld8(const u16* p){
  return *reinterpret_cast<const short8*>(p);
}
__device__ __forceinline__ f32x4 mfma16(short8 a, short8 b, f32x4 c){
  return __builtin_amdgcn_mfma_f32_16x16x32_bf16(a, b, c, 0, 0, 0);
}
__device__ __forceinline__ float gelu_f(float x){
  return 0.5f * x * (1.f + erff(x * 0.70710678118654752f));   // exact gelu
}

// ---------------- elementwise / gather kernels ----------------

__global__ void f2b_k(const float* __restrict__ s, u16* __restrict__ d, int n){
  int i = blockIdx.x * 256 + threadIdx.x;
  if (i < n) d[i] = f2b(s[i]);
}

__global__ void gather_xc_k(const float* __restrict__ mo, const float* __restrict__ lxm,
                            u16* __restrict__ xc, u16* __restrict__ pre_mo, int* __restrict__ cnt){
  int i = blockIdx.x * 256 + threadIdx.x;
  if (i == 0) *cnt = 0;                      // zero decoder barrier counter
  if (i >= 32 * 384) return;
  int n = i / 384, c = i - n * 384;
  float v = (c < 256) ? mo[(size_t)(n * 256 + c) * 600 + 29]
                      : lxm[(size_t)(n * 128 + (c - 256)) * 20];
  u16 h = f2b(v);
  xc[i] = h;
  if (c < 256) pre_mo[n * 256 + c] = h;
}

__global__ void lxm_g_k(const float* __restrict__ lxm, u16* __restrict__ o){
  int i = blockIdx.x * 256 + threadIdx.x;
  if (i >= 18 * 32 * 128) return;
  int c = i & 127, rest = i >> 7;
  int n = rest & 31, b = rest >> 5;
  o[i] = f2b(lxm[(size_t)(n * 128 + c) * 20 + 1 + b]);
}

__global__ void split_h_k(const float* __restrict__ hraw, u16* __restrict__ h0, u16* __restrict__ h1,
                          float* __restrict__ h0f, float* __restrict__ h1f){
  int i = blockIdx.x * 256 + threadIdx.x;
  if (i >= 32 * 1024) return;
  int n = i >> 10, c = i & 1023;
  float a = hraw[(size_t)n * 2048 + c];
  float b = hraw[(size_t)n * 2048 + 1024 + c];
  h0[i] = f2b(a); h1[i] = f2b(b);
  h0f[i] = a;     h1f[i] = b;
}

// ---------------- im2col kernels (chunked by output row) ----------------

__global__ void im2col0_k(const float* __restrict__ aud, u16* __restrict__ A, int row0, long long tot){
  long long i = (long long)blockIdx.x * 256 + threadIdx.x;
  if (i >= tot) return;
  int k = (int)(i % 896);
  int row = row0 + (int)(i / 896);
  int ci = k / 7, kk = k - ci * 7;
  int p = row % 84, bn = row / 84;
  int b = bn >> 5, n = bn & 31;
  A[i] = f2b(aud[(size_t)(n * 128 + ci) * 600 + b * 30 + p + kk]);
}

__global__ void im2col1_k(const u16* __restrict__ O0, u16* __restrict__ A, int row0, long long tot){
  long long i = (long long)blockIdx.x * 256 + threadIdx.x;
  if (i >= tot) return;
  int k = (int)(i % 1280);
  int row = row0 + (int)(i / 1280);
  int ci = k / 5, kk = k - ci * 5;
  int p = row % 80, bn = row / 80;
  A[i] = O0[(size_t)(bn * 84 + p + kk) * 256 + ci];
}

__global__ void im2col2_k(const u16* __restrict__ O1, u16* __restrict__ A, int row0, long long tot){
  long long i = (long long)blockIdx.x * 256 + threadIdx.x;
  if (i >= tot) return;
  int k = (int)(i & 1023);
  int row = row0 + (int)(i >> 10);
  int ci = k >> 2, kk = k & 3;
  int p = row % 40, bn = row / 40;
  int pos = 2 * p - 1 + kk;                      // stride 2, pad 1
  A[i] = (pos >= 0 && pos < 80) ? O1[(size_t)(bn * 80 + pos) * 256 + ci] : (u16)0;
}

// ---------------- GEMM: C[M,N] = A[M,K] @ W[N,K]^T  (bf16 MFMA) ----------------
// wave -> 16 rows x 64 cols; block (4 waves) -> 64x64 tile.

__global__ void gemm_bt(const u16* __restrict__ A, int lda,
                        const u16* __restrict__ W, const float* __restrict__ bias,
                        void* __restrict__ outp, int M, int N, int K, int flags){
  const int lane = threadIdx.x & 63, widx = threadIdx.x >> 6;
  const int m0 = blockIdx.x * 64 + widx * 16;
  if (m0 >= M) return;
  const int n0 = blockIdx.y * 64;
  const int r = lane & 15, g4 = lane >> 4;
  const u16* arow = A + (size_t)(m0 + r) * lda + g4 * 8;
  const u16* wrow = W + (size_t)(n0 + r) * K + g4 * 8;
  f32x4 acc[4];
  const f32x4 FZ = {0.f, 0.f, 0.f, 0.f};
  acc[0] = FZ; acc[1] = FZ; acc[2] = FZ; acc[3] = FZ;
  for (int k = 0; k < K; k += 32){
    short8 a = ld8(arow + k);
    #pragma unroll
    for (int j = 0; j < 4; ++j)
      acc[j] = mfma16(a, ld8(wrow + (size_t)j * 16 * K + k), acc[j]);
  }
  #pragma unroll
  for (int j = 0; j < 4; ++j){
    int col = n0 + j * 16 + r;
    float bv = bias ? bias[col] : 0.f;
    #pragma unroll
    for (int q = 0; q < 4; ++q){
      int row = m0 + g4 * 4 + q;
      float v = acc[j][q] + bv;
      if (flags & GELU_FLG) v = gelu_f(v);
      if (flags & BF16_FLG) ((u16*)outp)[(size_t)row * N + col] = f2b(v);
      else                  ((float*)outp)[(size_t)row * N + col] = v;
    }
  }
}

// ---------------- encoder LayerNorm -> aud_seq (bf16) ----------------
// rid = (b*30+p2)*32 + n ; reads gelu'd fc output O3[(b*32+n)*40+p2, 256]

__global__ void enc_ln_k(const float* __restrict__ O3, const float* __restrict__ g,
                         const float* __restrict__ bb, u16* __restrict__ aud_seq){
  int rid = blockIdx.x * 4 + (threadIdx.x >> 6);
  int lane = threadIdx.x & 63;
  int b = rid / 960, rem = rid - b * 960;
  int p2 = rem >> 5, n = rem & 31;
  int orow = (b * 32 + n) * 40 + p2;
  const float4 v = *reinterpret_cast<const float4*>(O3 + (size_t)orow * 256 + lane * 4);
  float s  = v.x + v.y + v.z + v.w;
  float s2 = v.x * v.x + v.y * v.y + v.z * v.z + v.w * v.w;
  #pragma unroll
  for (int m = 1; m < 64; m <<= 1){ s += __shfl_xor(s, m); s2 += __shfl_xor(s2, m); }
  float mu = s * (1.f / 256.f);
  float var = s2 * (1.f / 256.f) - mu * mu;
  float rs = rsqrtf(var + 1e-5f);
  int c = lane * 4;
  u16* dst = aud_seq + (size_t)rid * 256 + c;
  dst[0] = f2b((v.x - mu) * rs * g[c + 0] + bb[c + 0]);
  dst[1] = f2b((v.y - mu) * rs * g[c + 1] + bb[c + 1]);
  dst[2] = f2b((v.z - mu) * rs * g[c + 2] + bb[c + 2]);
  dst[3] = f2b((v.w - mu) * rs * g[c + 3] + bb[c + 3]);
}

// ---------------- persistent decoder ----------------

struct DecArgs {
  const u16 *aud_seq, *lxm_b, *wd, *wih0, *whh0, *wih1, *whh1, *wp;
  u16 *emb, *pre_mo;
  u16 *h0a, *h0b, *h1a, *h1b;            // bf16 state (GEMM A operands), double buffered
  float *h0f0, *h0f1, *h1f0, *h1f1;      // fp32 state (recurrence carry), double buffered
  float *stats;                          // [0..31] sum, [32..63] sumsq
  const float *dib, *bih0, *bhh0, *bih1, *bhh1, *lng, *lnb, *pbias;
  float *out;
  int *cnt;
};

// monotonic grid barrier (device-scope fences handle cross-XCD L2)
__device__ __forceinline__ void gbar(int* cnt, int target){
  __syncthreads();
  if (threadIdx.x == 0){
    __threadfence();                     // release: flush this XCD's dirty L2
    atomicAdd(cnt, 1);
    while (__hip_atomic_load(cnt, __ATOMIC_RELAXED, __HIP_MEMORY_SCOPE_AGENT) < target)
      __builtin_amdgcn_s_sleep(1);
    __threadfence();                     // acquire: invalidate stale L1/L2
  }
  __syncthreads();
}

__device__ __forceinline__ short8 xcat_frag(const DecArgs& A, int row, int kk, int t, int b){
  if (kk < 256) return ld8(A.pre_mo + row * 256 + kk);
  if (kk < 512) return ld8(A.aud_seq + ((size_t)t * 32 + row) * 256 + (kk - 256));
  return ld8(A.lxm_b + ((size_t)b * 32 + row) * 128 + (kk - 512));
}
__device__ __forceinline__ short8 gin_frag(const DecArgs& A, int row, int kk, int t, int b){
  if (kk < 1024) return ld8(A.emb + row * 1024 + kk);
  return xcat_frag(A, row, kk - 1024, t, b);
}

template<int LAYER>
__device__ __forceinline__ void gru_stage(const DecArgs& A, int t, int b, int wave, int lane,
                                          const u16* giA, const u16* hs, u16* hd,
                                          const float* hsf, float* hdf,
                                          const u16* wih, const u16* whh,
                                          const float* bih, const float* bhh){
  const int r = lane & 15, g4 = lane >> 4;
  const int c0 = wave * 16;
  const int KIN = (LAYER == 0) ? 1664 : 1024;
  const f32x4 FZ = {0.f, 0.f, 0.f, 0.f};
  f32x4 gi[2][3], gh[2][3];
  #pragma unroll
  for (int m = 0; m < 2; ++m){
    #pragma unroll
    for (int j = 0; j < 3; ++j){ gi[m][j] = FZ; gh[m][j] = FZ; }
  }
  const u16* w0 = wih + (size_t)(c0 + r) * KIN + g4 * 8;
  const u16* w1 = wih + (size_t)(1024 + c0 + r) * KIN + g4 * 8;
  const u16* w2 = wih + (size_t)(2048 + c0 + r) * KIN + g4 * 8;
  for (int k = 0; k < KIN; k += 32){
    int kk = k + g4 * 8;
    short8 a0, a1;
    if (LAYER == 0){ a0 = gin_frag(A, r, kk, t, b); a1 = gin_frag(A, 16 + r, kk, t, b); }
    else           { a0 = ld8(giA + r * 1024 + kk); a1 = ld8(giA + (16 + r) * 1024 + kk); }
    short8 b0 = ld8(w0 + k), b1 = ld8(w1 + k), b2 = ld8(w2 + k);
    gi[0][0] = mfma16(a0, b0, gi[0][0]); gi[1][0] = mfma16(a1, b0, gi[1][0]);
    gi[0][1] = mfma16(a0, b1, gi[0][1]); gi[1][1] = mfma16(a1, b1, gi[1][1]);
    gi[0][2] = mfma16(a0, b2, gi[0][2]); gi[1][2] = mfma16(a1, b2, gi[1][2]);
  }
  const u16* u0 = whh + (size_t)(c0 + r) * 1024 + g4 * 8;
  const u16* u1 = whh + (size_t)(1024 + c0 + r) * 1024 + g4 * 8;
  const u16* u2 = whh + (size_t)(2048 + c0 + r) * 1024 + g4 * 8;
  for (int k = 0; k < 1024; k += 32){
    int kk = k + g4 * 8;
    short8 a0 = ld8(hs + r * 1024 + kk);
    short8 a1 = ld8(hs + (16 + r) * 1024 + kk);
    short8 b0 = ld8(u0 + k), b1 = ld8(u1 + k), b2 = ld8(u2 + k);
    gh[0][0] = mfma16(a0, b0, gh[0][0]); gh[1][0] = mfma16(a1, b0, gh[1][0]);
    gh[0][1] = mfma16(a0, b1, gh[0][1]); gh[1][1] = mfma16(a1, b1, gh[1][1]);
    gh[0][2] = mfma16(a0, b2, gh[0][2]); gh[1][2] = mfma16(a1, b2, gh[1][2]);
  }
  const int col = c0 + r;
  const float bir = bih[col], biz = bih[1024 + col], bin = bih[2048 + col];
  const float bhr = bhh[col], bhz = bhh[1024 + col], bhn = bhh[2048 + col];
  #pragma unroll
  for (int m = 0; m < 2; ++m){
    #pragma unroll
    for (int q = 0; q < 4; ++q){
      float ir = gi[m][0][q] + bir, iz = gi[m][1][q] + biz, inn = gi[m][2][q] + bin;
      float hr = gh[m][0][q] + bhr, hz = gh[m][1][q] + bhz, hn = gh[m][2][q] + bhn;
      float rg = 1.f / (1.f + expf(-(ir + hr)));
      float zg = 1.f / (1.f + expf(-(iz + hz)));
      float ng = tanhf(inn + rg * hn);
      int rowD = m * 16 + g4 * 4 + q;
      float hp = hsf[rowD * 1024 + col];           // fp32 carry
      float hv = (1.f - zg) * ng + zg * hp;
      hd[rowD * 1024 + col]  = f2b(hv);
      hdf[rowD * 1024 + col] = hv;
      if (LAYER == 1){
        float sv = hv, sq = hv * hv;
        #pragma unroll
        for (int msk = 1; msk < 16; msk <<= 1){ sv += __shfl_xor(sv, msk); sq += __shfl_xor(sq, msk); }
        if (r == 0){ atomicAdd(&A.stats[rowD], sv); atomicAdd(&A.stats[32 + rowD], sq); }
      }
    }
  }
}

__global__ void decode_k(DecArgs A){
  const int lane = threadIdx.x & 63;
  const int wave = blockIdx.x * 4 + (threadIdx.x >> 6);    // 0..63
  const int r = lane & 15, g4 = lane >> 4;
  int bt = 0;
  #pragma unroll 1
  for (int t = 0; t < 540; ++t){
    const int b = t / 30;
    const int p = t & 1;
    const u16*   h0s  = p ? A.h0b  : A.h0a;   u16*   h0d  = p ? A.h0a  : A.h0b;
    const u16*   h1s  = p ? A.h1b  : A.h1a;   u16*   h1d  = p ? A.h1a  : A.h1b;
    const float* h0sf = p ? A.h0f1 : A.h0f0;  float* h0df = p ? A.h0f0 : A.h0f1;
    const float* h1sf = p ? A.h1f1 : A.h1f0;  float* h1df = p ? A.h1f0 : A.h1f1;

    // ---- S1: zero LN stats + emb = gelu(dec_in_w @ [pre_mo|a_t|l_t] + b)
    if (blockIdx.x == 0 && threadIdx.x < 64) A.stats[threadIdx.x] = 0.f;
    {
      const int c0 = wave * 16;
      const u16* wrow = A.wd + (size_t)(c0 + r) * 640 + g4 * 8;
      f32x4 a0 = {0.f,0.f,0.f,0.f}, a1 = {0.f,0.f,0.f,0.f};
      for (int k = 0; k < 640; k += 32){
        int kk = k + g4 * 8;
        short8 x0 = xcat_frag(A, r, kk, t, b);
        short8 x1 = xcat_frag(A, 16 + r, kk, t, b);
        short8 bv = ld8(wrow + k);
        a0 = mfma16(x0, bv, a0); a1 = mfma16(x1, bv, a1);
      }
      int col = c0 + r;
      float bias = A.dib[col];
      #pragma unroll
      for (int m = 0; m < 2; ++m){
        #pragma unroll
        for (int q = 0; q < 4; ++q){
          float v = gelu_f((m ? a1[q] : a0[q]) + bias);
          A.emb[(m * 16 + g4 * 4 + q) * 1024 + col] = f2b(v);
        }
      }
    }
    gbar(A.cnt, (++bt) * DEC_BLOCKS);

    // ---- S2: GRU layer 0
    gru_stage<0>(A, t, b, wave, lane, nullptr, h0s, h0d, h0sf, h0df,
                 A.wih0, A.whh0, A.bih0, A.bhh0);
    gbar(A.cnt, (++bt) * DEC_BLOCKS);

    // ---- S3: GRU layer 1 (+ LN stats)
    gru_stage<1>(A, t, b, wave, lane, h0d, h1s, h1d, h1sf, h1df,
                 A.wih1, A.whh1, A.bih1, A.bhh1);
    gbar(A.cnt, (++bt) * DEC_BLOCKS);

    // ---- S4: pred = LN(h1n) @ pred_w^T + pred_b ; write out + pre_mo
    if (wave < 16){
      const int c0 = wave * 16;
      float mu[2], rs[2];
      #pragma unroll
      for (int m = 0; m < 2; ++m){
        int row = m * 16 + r;
        float s = A.stats[row], s2 = A.stats[32 + row];
        float mm = s * (1.f / 1024.f);
        float vv = s2 * (1.f / 1024.f) - mm * mm;
        mu[m] = mm; rs[m] = rsqrtf(vv + 1e-5f);
      }
      const u16* wrow = A.wp + (size_t)(c0 + r) * 1024 + g4 * 8;
      f32x4 a0 = {0.f,0.f,0.f,0.f}, a1 = {0.f,0.f,0.f,0.f};
      const float* hr0 = h1df + r * 1024;
      const float* hr1 = h1df + (16 + r) * 1024;
      for (int k = 0; k < 1024; k += 32){
        int kk = k + g4 * 8;
        short8 f0, f1;
        #pragma unroll
        for (int j = 0; j < 8; ++j){
          float gg = A.lng[kk + j], bb = A.lnb[kk + j];
          f0[j] = (short)f2b((hr0[kk + j] - mu[0]) * rs[0] * gg + bb);
          f1[j] = (short)f2b((hr1[kk + j] - mu[1]) * rs[1] * gg + bb);
        }
        short8 bv = ld8(wrow + k);
        a0 = mfma16(f0, bv, a0); a1 = mfma16(f1, bv, a1);
      }
      int col = c0 + r;
      float pb = A.pbias[col];
      #pragma unroll
      for (int m = 0; m < 2; ++m){
        #pragma unroll
        for (int q = 0; q < 4; ++q){
          int rowD = m * 16 + g4 * 4 + q;
          float v = (m ? a1[q] : a0[q]) + pb;
          A.out[(size_t)rowD * (256 * 540) + (size_t)col * 540 + t] = v;
          A.pre_mo[rowD * 256 + col] = f2b(v);
        }
      }
    }
    gbar(A.cnt, (++bt) * DEC_BLOCKS);
  }
}

// ---------------------------------------------------------------------------

extern "C" void kernel_launch(void* const* d_in, const int* in_sizes, int n_in,
                              void* d_out, int out_size, void* d_ws, size_t ws_size,
                              hipStream_t stream) {
  enum { I_AUD=0, I_MO=1, I_LXM=2, I_AEW0=3, I_AEB0=4, I_AEW1=5, I_AEB1=6, I_AEW2=7, I_AEB2=8,
         I_AEW3=9, I_AEB3=10, I_AELNG=11, I_AELNB=12, I_CIW0=13, I_CIB0=14, I_CIW1=15, I_CIB1=16,
         I_CIW2=17, I_CIB2=18, I_DECW=19, I_DECB=20, I_WIH0=21, I_WHH0=22, I_BIH0=23, I_BHH0=24,
         I_WIH1=25, I_WHH1=26, I_BIH1=27, I_BHH1=28, I_LNG=29, I_LNB=30, I_PREDW=31, I_PREDB=32 };

  char* base = (char*)d_ws;
  size_t off = 0;
  auto alloc = [&](size_t bytes)->void*{
    void* p = base + off;
    off += (bytes + 255) & ~(size_t)255;
    return p;
  };

  // bf16 weight blobs (all [out,in] == [N,K] B^T layout, direct convert)
  u16* wd    = (u16*)alloc((size_t)1024*640*2);
  u16* wih0  = (u16*)alloc((size_t)3072*1664*2);
  u16* whh0  = (u16*)alloc((size_t)3072*1024*2);
  u16* wih1  = (u16*)alloc((size_t)3072*1024*2);
  u16* whh1  = (u16*)alloc((size_t)3072*1024*2);
  u16* wp    = (u16*)alloc((size_t)256*1024*2);
  u16* wc0   = (u16*)alloc((size_t)1024*384*2);
  u16* wc1   = (u16*)alloc((size_t)1024*1024*2);
  u16* wc2   = (u16*)alloc((size_t)2048*1024*2);
  u16* w0k   = (u16*)alloc((size_t)256*896*2);
  u16* w1k   = (u16*)alloc((size_t)256*1280*2);
  u16* w2k   = (u16*)alloc((size_t)256*1024*2);
  u16* w3k   = (u16*)alloc((size_t)256*256*2);
  // sequences / state
  u16* aud_seq = (u16*)alloc((size_t)540*32*256*2);
  u16* lxm_b   = (u16*)alloc((size_t)18*32*128*2);
  u16* xc      = (u16*)alloc((size_t)32*384*2);
  u16* ci1     = (u16*)alloc((size_t)32*1024*2);
  u16* ci2     = (u16*)alloc((size_t)32*1024*2);
  float* hraw  = (float*)alloc((size_t)32*2048*4);
  u16* h0a = (u16*)alloc((size_t)32*1024*2);
  u16* h0b = (u16*)alloc((size_t)32*1024*2);
  u16* h1a = (u16*)alloc((size_t)32*1024*2);
  u16* h1b = (u16*)alloc((size_t)32*1024*2);
  float* h0f0 = (float*)alloc((size_t)32*1024*4);
  float* h0f1 = (float*)alloc((size_t)32*1024*4);
  float* h1f0 = (float*)alloc((size_t)32*1024*4);
  float* h1f1 = (float*)alloc((size_t)32*1024*4);
  u16* emb    = (u16*)alloc((size_t)32*1024*2);
  u16* pre_mo = (u16*)alloc((size_t)32*256*2);
  float* stats = (float*)alloc(64*4);
  int* cnt     = (int*)alloc(256);
  // encoder transients
  u16* O0   = (u16*)alloc((size_t)48384*256*2);
  u16* O1   = (u16*)alloc((size_t)46080*256*2);
  u16* O2   = (u16*)alloc((size_t)23040*256*2);
  float* O3 = (float*)alloc((size_t)23040*256*4);
  u16* Abuf = (u16*)alloc((size_t)23040*1280*2);  // max im2col chunk (59 MB)
  (void)ws_size; (void)in_sizes; (void)n_in; (void)out_size;

  const float* aud = (const float*)d_in[I_AUD];
  const float* mo  = (const float*)d_in[I_MO];
  const float* lxm = (const float*)d_in[I_LXM];
  float* out = (float*)d_out;

  auto cdiv = [](long long a, long long b)->int{ return (int)((a + b - 1) / b); };
  auto cvt = [&](int idx, u16* dst, int n){
    f2b_k<<<cdiv(n,256), 256, 0, stream>>>((const float*)d_in[idx], dst, n);
  };

  // ---- weight conversion ----
  cvt(I_DECW, wd,   1024*640);
  cvt(I_WIH0, wih0, 3072*1664);
  cvt(I_WHH0, whh0, 3072*1024);
  cvt(I_WIH1, wih1, 3072*1024);
  cvt(I_WHH1, whh1, 3072*1024);
  cvt(I_PREDW, wp,  256*1024);
  cvt(I_CIW0, wc0,  1024*384);
  cvt(I_CIW1, wc1,  1024*1024);
  cvt(I_CIW2, wc2,  2048*1024);
  cvt(I_AEW0, w0k,  256*896);
  cvt(I_AEW1, w1k,  256*1280);
  cvt(I_AEW2, w2k,  256*1024);
  cvt(I_AEW3, w3k,  256*256);

  // ---- encoder: conv0 (two row-chunks of 24192) ----
  for (int c = 0; c < 2; ++c){
    int row0 = c * 24192;
    long long tot = (long long)24192 * 896;
    im2col0_k<<<cdiv(tot,256), 256, 0, stream>>>(aud, Abuf, row0, tot);
    gemm_bt<<<dim3(24192/64, 4), 256, 0, stream>>>(Abuf, 896, w0k, (const float*)d_in[I_AEB0],
        O0 + (size_t)row0*256, 24192, 256, 896, GELU_FLG|BF16_FLG);
  }
  // ---- conv1 (two row-chunks of 23040) ----
  for (int c = 0; c < 2; ++c){
    int row0 = c * 23040;
    long long tot = (long long)23040 * 1280;
    im2col1_k<<<cdiv(tot,256), 256, 0, stream>>>(O0, Abuf, row0, tot);
    gemm_bt<<<dim3(23040/64, 4), 256, 0, stream>>>(Abuf, 1280, w1k, (const float*)d_in[I_AEB1],
        O1 + (size_t)row0*256, 23040, 256, 1280, GELU_FLG|BF16_FLG);
  }
  // ---- conv2 (stride 2, pad 1) ----
  {
    long long tot = (long long)23040 * 1024;
    im2col2_k<<<cdiv(tot,256), 256, 0, stream>>>(O1, Abuf, 0, tot);
    gemm_bt<<<dim3(23040/64, 4), 256, 0, stream>>>(Abuf, 1024, w2k, (const float*)d_in[I_AEB2],
        O2, 23040, 256, 1024, GELU_FLG|BF16_FLG);
  }
  // ---- fc + gelu (fp32 out), then LN -> aud_seq ----
  gemm_bt<<<dim3(23040/64, 4), 256, 0, stream>>>(O2, 256, w3k, (const float*)d_in[I_AEB3],
      O3, 23040, 256, 256, GELU_FLG);
  enc_ln_k<<<4320, 256, 0, stream>>>(O3, (const float*)d_in[I_AELNG], (const float*)d_in[I_AELNB], aud_seq);

  // ---- lxm sequence + cell-init chain ----
  lxm_g_k<<<cdiv(18*32*128,256), 256, 0, stream>>>(lxm, lxm_b);
  gather_xc_k<<<cdiv(32*384,256), 256, 0, stream>>>(mo, lxm, xc, pre_mo, cnt);
  gemm_bt<<<dim3(1,16), 256, 0, stream>>>(xc, 384, wc0, (const float*)d_in[I_CIB0],
      ci1, 32, 1024, 384, GELU_FLG|BF16_FLG);
  gemm_bt<<<dim3(1,16), 256, 0, stream>>>(ci1, 1024, wc1, (const float*)d_in[I_CIB1],
      ci2, 32, 1024, 1024, GELU_FLG|BF16_FLG);
  gemm_bt<<<dim3(1,32), 256, 0, stream>>>(ci2, 1024, wc2, (const float*)d_in[I_CIB2],
      hraw, 32, 2048, 1024, 0);
  split_h_k<<<cdiv(32*1024,256), 256, 0, stream>>>(hraw, h0a, h1a, h0f0, h1f0);

  // ---- persistent decoder ----
  DecArgs da;
  da.aud_seq = aud_seq; da.lxm_b = lxm_b;
  da.wd = wd; da.wih0 = wih0; da.whh0 = whh0; da.wih1 = wih1; da.whh1 = whh1; da.wp = wp;
  da.emb = emb; da.pre_mo = pre_mo;
  da.h0a = h0a; da.h0b = h0b; da.h1a = h1a; da.h1b = h1b;
  da.h0f0 = h0f0; da.h0f1 = h0f1; da.h1f0 = h1f0; da.h1f1 = h1f1;
  da.stats = stats;
  da.dib  = (const float*)d_in[I_DECB];
  da.bih0 = (const float*)d_in[I_BIH0]; da.bhh0 = (const float*)d_in[I_BHH0];
  da.bih1 = (const float*)d_in[I_BIH1]; da.bhh1 = (const float*)d_in[I_BHH1];
  da.lng  = (const float*)d_in[I_LNG];  da.lnb  = (const float*)d_in[I_LNB];
  da.pbias = (const float*)d_in[I_PREDB];
  da.out = out; da.cnt = cnt;
  decode_k<<<dim3(DEC_BLOCKS), dim3(256), 0, stream>>>(da);
}

// Round 2
// 84689.062 us; speedup vs baseline: 1.2397x; 1.2397x over previous
//
#include <hip/hip_runtime.h>

// ---------------------------------------------------------------------------
// MotionGenerator RNN for MI355X (gfx950).
//  - encoder: im2col + bf16 MFMA GEMM (weights are [out,in] == [N,K] B^T layout)
//  - decoder: persistent kernel, 64 blocks x 256 thr (256 waves), 4-phase
//    dataflow per step with hoisted recurrent GEMMs, custom grid barrier.
//    fp32 recurrence carry, bf16 GEMM operands.
// ---------------------------------------------------------------------------

typedef unsigned short u16;
typedef __attribute__((ext_vector_type(8))) short short8;
typedef __attribute__((ext_vector_type(4))) float f32x4;

#define GELU_FLG 1
#define BF16_FLG 2
#define NBLK 64

__device__ __forceinline__ float b2f(u16 h){
  union { unsigned u; float f; } c; c.u = ((unsigned)h) << 16; return c.f;
}
__device__ __forceinline__ u16 f2b(float f){
  union { float f; unsigned u; } c; c.f = f;
  return (u16)((c.u + 0x7fffu + ((c.u >> 16) & 1u)) >> 16);   // RNE
}
__device__ __forceinline__ short8 ld8(const u16* p){
  return *reinterpret_cast<const short8*>(p);
}
__device__ __forceinline__ f32x4 mfma16(short8 a, short8 b, f32x4 c){
  return __builtin_amdgcn_mfma_f32_16x16x32_bf16(a, b, c, 0, 0, 0);
}
__device__ __forceinline__ float gelu_f(float x){
  return 0.5f * x * (1.f + erff(x * 0.70710678118654752f));   // exact gelu
}
__device__ __forceinline__ float sigmoid_f(float x){
  return 1.f / (1.f + __expf(-x));
}
__device__ __forceinline__ float tanh_f(float x){
  float e = __expf(-2.f * x);
  return (1.f - e) / (1.f + e);
}

// ---------------- elementwise / gather kernels ----------------

__global__ void f2b_k(const float* __restrict__ s, u16* __restrict__ d, int n){
  int i = blockIdx.x * 256 + threadIdx.x;
  if (i < n) d[i] = f2b(s[i]);
}

__global__ void gather_xc_k(const float* __restrict__ mo, const float* __restrict__ lxm,
                            u16* __restrict__ xc, u16* __restrict__ pre_mo, int* __restrict__ cnt){
  int i = blockIdx.x * 256 + threadIdx.x;
  if (i == 0) *cnt = 0;                      // zero decoder barrier counter
  if (i >= 32 * 384) return;
  int n = i / 384, c = i - n * 384;
  float v = (c < 256) ? mo[(size_t)(n * 256 + c) * 600 + 29]
                      : lxm[(size_t)(n * 128 + (c - 256)) * 20];
  u16 h = f2b(v);
  xc[i] = h;
  if (c < 256) pre_mo[n * 256 + c] = h;
}

__global__ void lxm_g_k(const float* __restrict__ lxm, u16* __restrict__ o){
  int i = blockIdx.x * 256 + threadIdx.x;
  if (i >= 18 * 32 * 128) return;
  int c = i & 127, rest = i >> 7;
  int n = rest & 31, b = rest >> 5;
  o[i] = f2b(lxm[(size_t)(n * 128 + c) * 20 + 1 + b]);
}

__global__ void split_h_k(const float* __restrict__ hraw, u16* __restrict__ h0, u16* __restrict__ h1,
                          float* __restrict__ h0f, float* __restrict__ h1f){
  int i = blockIdx.x * 256 + threadIdx.x;
  if (i >= 32 * 1024) return;
  int n = i >> 10, c = i & 1023;
  float a = hraw[(size_t)n * 2048 + c];
  float b = hraw[(size_t)n * 2048 + 1024 + c];
  h0[i] = f2b(a); h1[i] = f2b(b);
  h0f[i] = a;     h1f[i] = b;
}

// ---------------- im2col kernels (chunked by output row) ----------------

__global__ void im2col0_k(const float* __restrict__ aud, u16* __restrict__ A, int row0, long long tot){
  long long i = (long long)blockIdx.x * 256 + threadIdx.x;
  if (i >= tot) return;
  int k = (int)(i % 896);
  int row = row0 + (int)(i / 896);
  int ci = k / 7, kk = k - ci * 7;
  int p = row % 84, bn = row / 84;
  int b = bn >> 5, n = bn & 31;
  A[i] = f2b(aud[(size_t)(n * 128 + ci) * 600 + b * 30 + p + kk]);
}

__global__ void im2col1_k(const u16* __restrict__ O0, u16* __restrict__ A, int row0, long long tot){
  long long i = (long long)blockIdx.x * 256 + threadIdx.x;
  if (i >= tot) return;
  int k = (int)(i % 1280);
  int row = row0 + (int)(i / 1280);
  int ci = k / 5, kk = k - ci * 5;
  int p = row % 80, bn = row / 80;
  A[i] = O0[(size_t)(bn * 84 + p + kk) * 256 + ci];
}

__global__ void im2col2_k(const u16* __restrict__ O1, u16* __restrict__ A, int row0, long long tot){
  long long i = (long long)blockIdx.x * 256 + threadIdx.x;
  if (i >= tot) return;
  int k = (int)(i & 1023);
  int row = row0 + (int)(i >> 10);
  int ci = k >> 2, kk = k & 3;
  int p = row % 40, bn = row / 40;
  int pos = 2 * p - 1 + kk;                      // stride 2, pad 1
  A[i] = (pos >= 0 && pos < 80) ? O1[(size_t)(bn * 80 + pos) * 256 + ci] : (u16)0;
}

// ---------------- GEMM: C[M,N] = A[M,K] @ W[N,K]^T  (bf16 MFMA) ----------------

__global__ void gemm_bt(const u16* __restrict__ A, int lda,
                        const u16* __restrict__ W, const float* __restrict__ bias,
                        void* __restrict__ outp, int M, int N, int K, int flags){
  const int lane = threadIdx.x & 63, widx = threadIdx.x >> 6;
  const int m0 = blockIdx.x * 64 + widx * 16;
  if (m0 >= M) return;
  const int n0 = blockIdx.y * 64;
  const int r = lane & 15, g4 = lane >> 4;
  const u16* arow = A + (size_t)(m0 + r) * lda + g4 * 8;
  const u16* wrow = W + (size_t)(n0 + r) * K + g4 * 8;
  f32x4 acc[4];
  const f32x4 FZ = {0.f, 0.f, 0.f, 0.f};
  acc[0] = FZ; acc[1] = FZ; acc[2] = FZ; acc[3] = FZ;
  for (int k = 0; k < K; k += 32){
    short8 a = ld8(arow + k);
    #pragma unroll
    for (int j = 0; j < 4; ++j)
      acc[j] = mfma16(a, ld8(wrow + (size_t)j * 16 * K + k), acc[j]);
  }
  #pragma unroll
  for (int j = 0; j < 4; ++j){
    int col = n0 + j * 16 + r;
    float bv = bias ? bias[col] : 0.f;
    #pragma unroll
    for (int q = 0; q < 4; ++q){
      int row = m0 + g4 * 4 + q;
      float v = acc[j][q] + bv;
      if (flags & GELU_FLG) v = gelu_f(v);
      if (flags & BF16_FLG) ((u16*)outp)[(size_t)row * N + col] = f2b(v);
      else                  ((float*)outp)[(size_t)row * N + col] = v;
    }
  }
}

// ---------------- encoder LayerNorm -> aud_seq (bf16) ----------------

__global__ void enc_ln_k(const float* __restrict__ O3, const float* __restrict__ g,
                         const float* __restrict__ bb, u16* __restrict__ aud_seq){
  int rid = blockIdx.x * 4 + (threadIdx.x >> 6);
  int lane = threadIdx.x & 63;
  int b = rid / 960, rem = rid - b * 960;
  int p2 = rem >> 5, n = rem & 31;
  int orow = (b * 32 + n) * 40 + p2;
  const float4 v = *reinterpret_cast<const float4*>(O3 + (size_t)orow * 256 + lane * 4);
  float s  = v.x + v.y + v.z + v.w;
  float s2 = v.x * v.x + v.y * v.y + v.z * v.z + v.w * v.w;
  #pragma unroll
  for (int m = 1; m < 64; m <<= 1){ s += __shfl_xor(s, m); s2 += __shfl_xor(s2, m); }
  float mu = s * (1.f / 256.f);
  float var = s2 * (1.f / 256.f) - mu * mu;
  float rs = rsqrtf(var + 1e-5f);
  int c = lane * 4;
  u16* dst = aud_seq + (size_t)rid * 256 + c;
  dst[0] = f2b((v.x - mu) * rs * g[c + 0] + bb[c + 0]);
  dst[1] = f2b((v.y - mu) * rs * g[c + 1] + bb[c + 1]);
  dst[2] = f2b((v.z - mu) * rs * g[c + 2] + bb[c + 2]);
  dst[3] = f2b((v.w - mu) * rs * g[c + 3] + bb[c + 3]);
}

// ---------------- persistent decoder ----------------

struct DecArgs {
  const u16 *aud_seq, *lxm_b, *wd, *wih0, *whh0, *wih1, *whh1, *wp;
  u16 *emb, *pre_mo;
  u16 *h0a, *h0b, *h1a, *h1b;            // bf16 state (GEMM A operands), double buffered
  float *h0f0, *h0f1, *h1f0, *h1f1;      // fp32 state (recurrence carry), double buffered
  float *gaccX, *gaccH0, *gaccH1;        // f32 partials [32][3072]
  float *stats;                          // [64 waves][64] LN partial sums/sumsq
  const float *dib, *bih0, *bhh0, *bih1, *bhh1, *lng, *lnb, *pbias;
  float *out;
  int *cnt;
};

// monotonic grid barrier (device-scope fences handle cross-XCD L2)
__device__ __forceinline__ void gbar(int* cnt, int target){
  __syncthreads();
  if (threadIdx.x == 0){
    __threadfence();                     // release
    atomicAdd(cnt, 1);
    while (__hip_atomic_load(cnt, __ATOMIC_RELAXED, __HIP_MEMORY_SCOPE_AGENT) < target)
      __builtin_amdgcn_s_sleep(1);
    __threadfence();                     // acquire
  }
  __syncthreads();
}

__device__ __forceinline__ short8 xcat_frag(const DecArgs& A, int row, int kk, int t, int b){
  if (kk < 256) return ld8(A.pre_mo + row * 256 + kk);
  if (kk < 512) return ld8(A.aud_seq + ((size_t)t * 32 + row) * 256 + (kk - 256));
  return ld8(A.lxm_b + ((size_t)b * 32 + row) * 128 + (kk - 512));
}

// emb = gelu(wd @ xcat + dib), 16 cols
__device__ __forceinline__ void emb_job(const DecArgs& A, int t, int b, int lane, int c0){
  const int r = lane & 15, g4 = lane >> 4;
  const u16* wrow = A.wd + (size_t)(c0 + r) * 640 + g4 * 8;
  f32x4 a0 = {0.f,0.f,0.f,0.f}, a1 = {0.f,0.f,0.f,0.f};
  for (int k = 0; k < 640; k += 32){
    int kk = k + g4 * 8;
    short8 x0 = xcat_frag(A, r, kk, t, b);
    short8 x1 = xcat_frag(A, 16 + r, kk, t, b);
    short8 bv = ld8(wrow + k);
    a0 = mfma16(x0, bv, a0); a1 = mfma16(x1, bv, a1);
  }
  int col = c0 + r;
  float bias = A.dib[col];
  #pragma unroll
  for (int m = 0; m < 2; ++m){
    #pragma unroll
    for (int q = 0; q < 4; ++q){
      float v = gelu_f((m ? a1[q] : a0[q]) + bias);
      A.emb[(m * 16 + g4 * 4 + q) * 1024 + col] = f2b(v);
    }
  }
}

// partial: 16 rows of wih0's xcat-columns (K=640) -> gaccX
__device__ __forceinline__ void gate_job_xcat(const DecArgs& A, int t, int b, int lane, int row0){
  const int r = lane & 15, g4 = lane >> 4;
  const u16* w = A.wih0 + (size_t)(row0 + r) * 1664 + 1024 + g4 * 8;
  f32x4 a0 = {0.f,0.f,0.f,0.f}, a1 = {0.f,0.f,0.f,0.f};
  for (int k = 0; k < 640; k += 32){
    int kk = k + g4 * 8;
    short8 bv = ld8(w + k);
    a0 = mfma16(xcat_frag(A, r, kk, t, b), bv, a0);
    a1 = mfma16(xcat_frag(A, 16 + r, kk, t, b), bv, a1);
  }
  const int col = row0 + r;
  #pragma unroll
  for (int q = 0; q < 4; ++q){
    A.gaccX[(size_t)(g4 * 4 + q) * 3072 + col]      = a0[q];
    A.gaccX[(size_t)(16 + g4 * 4 + q) * 3072 + col] = a1[q];
  }
}

// partial: 16 rows of a [3072,1024] recurrent weight on A [32,1024] -> dst
__device__ __forceinline__ void gate_job_mat(const u16* __restrict__ Am, const u16* __restrict__ W,
                                             int row0, int lane, float* __restrict__ dst){
  const int r = lane & 15, g4 = lane >> 4;
  const u16* w   = W + (size_t)(row0 + r) * 1024 + g4 * 8;
  const u16* a0p = Am + r * 1024 + g4 * 8;
  const u16* a1p = Am + (16 + r) * 1024 + g4 * 8;
  f32x4 acc0 = {0.f,0.f,0.f,0.f}, acc1 = {0.f,0.f,0.f,0.f};
  for (int k = 0; k < 1024; k += 32){
    short8 bv = ld8(w + k);
    acc0 = mfma16(ld8(a0p + k), bv, acc0);
    acc1 = mfma16(ld8(a1p + k), bv, acc1);
  }
  const int col = row0 + r;
  #pragma unroll
  for (int q = 0; q < 4; ++q){
    dst[(size_t)(g4 * 4 + q) * 3072 + col]      = acc0[q];
    dst[(size_t)(16 + g4 * 4 + q) * 3072 + col] = acc1[q];
  }
}

// GRU combine job: 16 output cols. gi = W_in(3 gates) @ Am (K=1024) [+ gaccX];
// gh from gacc partial buffer; pointwise -> h (bf16 + f32).
template<int LAYER>
__device__ __forceinline__ void col_job(const DecArgs& A, int lane, int wid, int c0,
                                        const u16* __restrict__ Am,
                                        const float* __restrict__ hsf,
                                        u16* __restrict__ hd, float* __restrict__ hdf){
  const int r = lane & 15, g4 = lane >> 4;
  const size_t LDW = (LAYER == 0) ? 1664 : 1024;
  const u16* wbase = (LAYER == 0) ? A.wih0 : A.wih1;
  const u16* w0 = wbase + (size_t)(c0 + r) * LDW + g4 * 8;
  const u16* w1 = wbase + (size_t)(1024 + c0 + r) * LDW + g4 * 8;
  const u16* w2 = wbase + (size_t)(2048 + c0 + r) * LDW + g4 * 8;
  const u16* a0p = Am + r * 1024 + g4 * 8;
  const u16* a1p = Am + (16 + r) * 1024 + g4 * 8;
  const f32x4 FZ = {0.f,0.f,0.f,0.f};
  f32x4 gi[2][3];
  #pragma unroll
  for (int m = 0; m < 2; ++m){ gi[m][0] = FZ; gi[m][1] = FZ; gi[m][2] = FZ; }
  for (int k = 0; k < 1024; k += 32){
    short8 a0 = ld8(a0p + k), a1 = ld8(a1p + k);
    short8 b0 = ld8(w0 + k), b1 = ld8(w1 + k), b2 = ld8(w2 + k);
    gi[0][0] = mfma16(a0, b0, gi[0][0]); gi[1][0] = mfma16(a1, b0, gi[1][0]);
    gi[0][1] = mfma16(a0, b1, gi[0][1]); gi[1][1] = mfma16(a1, b1, gi[1][1]);
    gi[0][2] = mfma16(a0, b2, gi[0][2]); gi[1][2] = mfma16(a1, b2, gi[1][2]);
  }
  const int col = c0 + r;
  const float* bih = (LAYER == 0) ? A.bih0 : A.bih1;
  const float* bhh = (LAYER == 0) ? A.bhh0 : A.bhh1;
  const float bir = bih[col], biz = bih[1024 + col], bin = bih[2048 + col];
  const float bhr = bhh[col], bhz = bhh[1024 + col], bhn = bhh[2048 + col];
  const float* gH = (LAYER == 0) ? A.gaccH0 : A.gaccH1;
  #pragma unroll
  for (int m = 0; m < 2; ++m){
    #pragma unroll
    for (int q = 0; q < 4; ++q){
      const int s = m * 16 + g4 * 4 + q;
      const float* gh = gH + (size_t)s * 3072;
      float ir = gi[m][0][q] + bir, iz = gi[m][1][q] + biz, inn = gi[m][2][q] + bin;
      if (LAYER == 0){
        const float* gx = A.gaccX + (size_t)s * 3072;
        ir += gx[col]; iz += gx[1024 + col]; inn += gx[2048 + col];
      }
      float hr = gh[col] + bhr, hz = gh[1024 + col] + bhz, hn = gh[2048 + col] + bhn;
      float rg = sigmoid_f(ir + hr);
      float zg = sigmoid_f(iz + hz);
      float ng = tanh_f(inn + rg * hn);
      float hp = hsf[s * 1024 + col];
      float hv = (1.f - zg) * ng + zg * hp;
      hd[s * 1024 + col]  = f2b(hv);
      hdf[s * 1024 + col] = hv;
      if (LAYER == 1){
        float sv = hv, sq = hv * hv;
        #pragma unroll
        for (int msk = 1; msk < 16; msk <<= 1){ sv += __shfl_xor(sv, msk); sq += __shfl_xor(sq, msk); }
        if (r == 0){
          A.stats[wid * 64 + s]      = sv;   // partial over this wave's 16 cols
          A.stats[wid * 64 + 32 + s] = sq;
        }
      }
    }
  }
}

// pred = LN(h1) @ wp^T + pb -> out[:, :, t], pre_mo
__device__ __forceinline__ void pred_job(const DecArgs& A, int lane, int c0,
                                         const float* __restrict__ h1df, int t){
  const int r = lane & 15, g4 = lane >> 4;
  // reduce LN partials: lane e accumulates entry e over 64 waves
  float acc = 0.f;
  {
    const float* sp = A.stats + lane;
    #pragma unroll
    for (int w = 0; w < 64; ++w) acc += sp[w * 64];
  }
  float sum0 = __shfl(acc, r),      sq0 = __shfl(acc, 32 + r);
  float sum1 = __shfl(acc, 16 + r), sq1 = __shfl(acc, 48 + r);
  float mu0 = sum0 * (1.f / 1024.f), mu1 = sum1 * (1.f / 1024.f);
  float rs0 = rsqrtf(sq0 * (1.f / 1024.f) - mu0 * mu0 + 1e-5f);
  float rs1 = rsqrtf(sq1 * (1.f / 1024.f) - mu1 * mu1 + 1e-5f);
  const u16* wrow = A.wp + (size_t)(c0 + r) * 1024 + g4 * 8;
  f32x4 a0 = {0.f,0.f,0.f,0.f}, a1 = {0.f,0.f,0.f,0.f};
  const float* hr0 = h1df + r * 1024;
  const float* hr1 = h1df + (16 + r) * 1024;
  for (int k = 0; k < 1024; k += 32){
    int kk = k + g4 * 8;
    short8 f0, f1;
    #pragma unroll
    for (int j = 0; j < 8; ++j){
      float gg = A.lng[kk + j], bb = A.lnb[kk + j];
      f0[j] = (short)f2b((hr0[kk + j] - mu0) * rs0 * gg + bb);
      f1[j] = (short)f2b((hr1[kk + j] - mu1) * rs1 * gg + bb);
    }
    short8 bv = ld8(wrow + k);
    a0 = mfma16(f0, bv, a0); a1 = mfma16(f1, bv, a1);
  }
  const int col = c0 + r;
  const float pb = A.pbias[col];
  #pragma unroll
  for (int m = 0; m < 2; ++m){
    #pragma unroll
    for (int q = 0; q < 4; ++q){
      int s = m * 16 + g4 * 4 + q;
      float v = (m ? a1[q] : a0[q]) + pb;
      A.out[(size_t)s * (256 * 540) + (size_t)col * 540 + t] = v;
      A.pre_mo[s * 256 + col] = f2b(v);
    }
  }
}

__global__ void decode_k(DecArgs A){
  const int lane = threadIdx.x & 63;
  const int wid = blockIdx.x * 4 + (threadIdx.x >> 6);    // 0..255
  int bt = 0;
  #pragma unroll 1
  for (int t = 0; t < 540; ++t){
    const int b = t / 30;
    const int p = t & 1;
    const u16*   h0s  = p ? A.h0b  : A.h0a;   u16*   h0d  = p ? A.h0a  : A.h0b;
    const u16*   h1s  = p ? A.h1b  : A.h1a;   u16*   h1d  = p ? A.h1a  : A.h1b;
    const float* h0sf = p ? A.h0f1 : A.h0f0;  float* h0df = p ? A.h0f0 : A.h0f1;
    const float* h1sf = p ? A.h1f1 : A.h1f0;  float* h1df = p ? A.h1f0 : A.h1f1;

    // ---- P1: emb (64) || wih0_x @ xcat partials (192); t==0: also gaccH0 seed
    if (wid < 64) emb_job(A, t, b, lane, wid * 16);
    else          gate_job_xcat(A, t, b, lane, (wid - 64) * 16);
    if (t == 0 && wid >= 64) gate_job_mat(h0s, A.whh0, (wid - 64) * 16, lane, A.gaccH0);
    gbar(A.cnt, (++bt) * NBLK);

    // ---- P2: h0 combine (64) || whh1 @ h1_{t-1} -> gaccH1 (192)
    if (wid < 64) col_job<0>(A, lane, wid, wid * 16, A.emb, h0sf, h0d, h0df);
    else          gate_job_mat(h1s, A.whh1, (wid - 64) * 16, lane, A.gaccH1);
    gbar(A.cnt, (++bt) * NBLK);

    // ---- P3: h1 combine + LN partials (64) || whh0 @ h0_t -> gaccH0 (192)
    if (wid < 64) col_job<1>(A, lane, wid, wid * 16, h0d, h1sf, h1d, h1df);
    else          gate_job_mat(h0d, A.whh0, (wid - 64) * 16, lane, A.gaccH0);
    gbar(A.cnt, (++bt) * NBLK);

    // ---- P4: pred (16)
    if (wid < 16) pred_job(A, lane, wid * 16, h1df, t);
    gbar(A.cnt, (++bt) * NBLK);
  }
}

// ---------------------------------------------------------------------------

extern "C" void kernel_launch(void* const* d_in, const int* in_sizes, int n_in,
                              void* d_out, int out_size, void* d_ws, size_t ws_size,
                              hipStream_t stream) {
  enum { I_AUD=0, I_MO=1, I_LXM=2, I_AEW0=3, I_AEB0=4, I_AEW1=5, I_AEB1=6, I_AEW2=7, I_AEB2=8,
         I_AEW3=9, I_AEB3=10, I_AELNG=11, I_AELNB=12, I_CIW0=13, I_CIB0=14, I_CIW1=15, I_CIB1=16,
         I_CIW2=17, I_CIB2=18, I_DECW=19, I_DECB=20, I_WIH0=21, I_WHH0=22, I_BIH0=23, I_BHH0=24,
         I_WIH1=25, I_WHH1=26, I_BIH1=27, I_BHH1=28, I_LNG=29, I_LNB=30, I_PREDW=31, I_PREDB=32 };

  char* base = (char*)d_ws;
  size_t off = 0;
  auto alloc = [&](size_t bytes)->void*{
    void* p = base + off;
    off += (bytes + 255) & ~(size_t)255;
    return p;
  };

  // bf16 weight blobs
  u16* wd    = (u16*)alloc((size_t)1024*640*2);
  u16* wih0  = (u16*)alloc((size_t)3072*1664*2);
  u16* whh0  = (u16*)alloc((size_t)3072*1024*2);
  u16* wih1  = (u16*)alloc((size_t)3072*1024*2);
  u16* whh1  = (u16*)alloc((size_t)3072*1024*2);
  u16* wp    = (u16*)alloc((size_t)256*1024*2);
  u16* wc0   = (u16*)alloc((size_t)1024*384*2);
  u16* wc1   = (u16*)alloc((size_t)1024*1024*2);
  u16* wc2   = (u16*)alloc((size_t)2048*1024*2);
  u16* w0k   = (u16*)alloc((size_t)256*896*2);
  u16* w1k   = (u16*)alloc((size_t)256*1280*2);
  u16* w2k   = (u16*)alloc((size_t)256*1024*2);
  u16* w3k   = (u16*)alloc((size_t)256*256*2);
  // sequences / state
  u16* aud_seq = (u16*)alloc((size_t)540*32*256*2);
  u16* lxm_b   = (u16*)alloc((size_t)18*32*128*2);
  u16* xc      = (u16*)alloc((size_t)32*384*2);
  u16* ci1     = (u16*)alloc((size_t)32*1024*2);
  u16* ci2     = (u16*)alloc((size_t)32*1024*2);
  float* hraw  = (float*)alloc((size_t)32*2048*4);
  u16* h0a = (u16*)alloc((size_t)32*1024*2);
  u16* h0b = (u16*)alloc((size_t)32*1024*2);
  u16* h1a = (u16*)alloc((size_t)32*1024*2);
  u16* h1b = (u16*)alloc((size_t)32*1024*2);
  float* h0f0 = (float*)alloc((size_t)32*1024*4);
  float* h0f1 = (float*)alloc((size_t)32*1024*4);
  float* h1f0 = (float*)alloc((size_t)32*1024*4);
  float* h1f1 = (float*)alloc((size_t)32*1024*4);
  u16* emb    = (u16*)alloc((size_t)32*1024*2);
  u16* pre_mo = (u16*)alloc((size_t)32*256*2);
  float* gaccX  = (float*)alloc((size_t)32*3072*4);
  float* gaccH0 = (float*)alloc((size_t)32*3072*4);
  float* gaccH1 = (float*)alloc((size_t)32*3072*4);
  float* stats  = (float*)alloc((size_t)64*64*4);
  int* cnt      = (int*)alloc(256);
  // encoder transients
  u16* O0   = (u16*)alloc((size_t)48384*256*2);
  u16* O1   = (u16*)alloc((size_t)46080*256*2);
  u16* O2   = (u16*)alloc((size_t)23040*256*2);
  float* O3 = (float*)alloc((size_t)23040*256*4);
  u16* Abuf = (u16*)alloc((size_t)23040*1280*2);  // max im2col chunk (59 MB)
  (void)ws_size; (void)in_sizes; (void)n_in; (void)out_size;

  const float* aud = (const float*)d_in[I_AUD];
  const float* mo  = (const float*)d_in[I_MO];
  const float* lxm = (const float*)d_in[I_LXM];
  float* out = (float*)d_out;

  auto cdiv = [](long long a, long long b)->int{ return (int)((a + b - 1) / b); };
  auto cvt = [&](int idx, u16* dst, int n){
    f2b_k<<<cdiv(n,256), 256, 0, stream>>>((const float*)d_in[idx], dst, n);
  };

  // ---- weight conversion ----
  cvt(I_DECW, wd,   1024*640);
  cvt(I_WIH0, wih0, 3072*1664);
  cvt(I_WHH0, whh0, 3072*1024);
  cvt(I_WIH1, wih1, 3072*1024);
  cvt(I_WHH1, whh1, 3072*1024);
  cvt(I_PREDW, wp,  256*1024);
  cvt(I_CIW0, wc0,  1024*384);
  cvt(I_CIW1, wc1,  1024*1024);
  cvt(I_CIW2, wc2,  2048*1024);
  cvt(I_AEW0, w0k,  256*896);
  cvt(I_AEW1, w1k,  256*1280);
  cvt(I_AEW2, w2k,  256*1024);
  cvt(I_AEW3, w3k,  256*256);

  // ---- encoder: conv0 (two row-chunks of 24192) ----
  for (int c = 0; c < 2; ++c){
    int row0 = c * 24192;
    long long tot = (long long)24192 * 896;
    im2col0_k<<<cdiv(tot,256), 256, 0, stream>>>(aud, Abuf, row0, tot);
    gemm_bt<<<dim3(24192/64, 4), 256, 0, stream>>>(Abuf, 896, w0k, (const float*)d_in[I_AEB0],
        O0 + (size_t)row0*256, 24192, 256, 896, GELU_FLG|BF16_FLG);
  }
  // ---- conv1 (two row-chunks of 23040) ----
  for (int c = 0; c < 2; ++c){
    int row0 = c * 23040;
    long long tot = (long long)23040 * 1280;
    im2col1_k<<<cdiv(tot,256), 256, 0, stream>>>(O0, Abuf, row0, tot);
    gemm_bt<<<dim3(23040/64, 4), 256, 0, stream>>>(Abuf, 1280, w1k, (const float*)d_in[I_AEB1],
        O1 + (size_t)row0*256, 23040, 256, 1280, GELU_FLG|BF16_FLG);
  }
  // ---- conv2 (stride 2, pad 1) ----
  {
    long long tot = (long long)23040 * 1024;
    im2col2_k<<<cdiv(tot,256), 256, 0, stream>>>(O1, Abuf, 0, tot);
    gemm_bt<<<dim3(23040/64, 4), 256, 0, stream>>>(Abuf, 1024, w2k, (const float*)d_in[I_AEB2],
        O2, 23040, 256, 1024, GELU_FLG|BF16_FLG);
  }
  // ---- fc + gelu (fp32 out), then LN -> aud_seq ----
  gemm_bt<<<dim3(23040/64, 4), 256, 0, stream>>>(O2, 256, w3k, (const float*)d_in[I_AEB3],
      O3, 23040, 256, 256, GELU_FLG);
  enc_ln_k<<<4320, 256, 0, stream>>>(O3, (const float*)d_in[I_AELNG], (const float*)d_in[I_AELNB], aud_seq);

  // ---- lxm sequence + cell-init chain ----
  lxm_g_k<<<cdiv(18*32*128,256), 256, 0, stream>>>(lxm, lxm_b);
  gather_xc_k<<<cdiv(32*384,256), 256, 0, stream>>>(mo, lxm, xc, pre_mo, cnt);
  gemm_bt<<<dim3(1,16), 256, 0, stream>>>(xc, 384, wc0, (const float*)d_in[I_CIB0],
      ci1, 32, 1024, 384, GELU_FLG|BF16_FLG);
  gemm_bt<<<dim3(1,16), 256, 0, stream>>>(ci1, 1024, wc1, (const float*)d_in[I_CIB1],
      ci2, 32, 1024, 1024, GELU_FLG|BF16_FLG);
  gemm_bt<<<dim3(1,32), 256, 0, stream>>>(ci2, 1024, wc2, (const float*)d_in[I_CIB2],
      hraw, 32, 2048, 1024, 0);
  split_h_k<<<cdiv(32*1024,256), 256, 0, stream>>>(hraw, h0a, h1a, h0f0, h1f0);

  // ---- persistent decoder ----
  DecArgs da;
  da.aud_seq = aud_seq; da.lxm_b = lxm_b;
  da.wd = wd; da.wih0 = wih0; da.whh0 = whh0; da.wih1 = wih1; da.whh1 = whh1; da.wp = wp;
  da.emb = emb; da.pre_mo = pre_mo;
  da.h0a = h0a; da.h0b = h0b; da.h1a = h1a; da.h1b = h1b;
  da.h0f0 = h0f0; da.h0f1 = h0f1; da.h1f0 = h1f0; da.h1f1 = h1f1;
  da.gaccX = gaccX; da.gaccH0 = gaccH0; da.gaccH1 = gaccH1;
  da.stats = stats;
  da.dib  = (const float*)d_in[I_DECB];
  da.bih0 = (const float*)d_in[I_BIH0]; da.bhh0 = (const float*)d_in[I_BHH0];
  da.bih1 = (const float*)d_in[I_BIH1]; da.bhh1 = (const float*)d_in[I_BHH1];
  da.lng  = (const float*)d_in[I_LNG];  da.lnb  = (const float*)d_in[I_LNB];
  da.pbias = (const float*)d_in[I_PREDB];
  da.out = out; da.cnt = cnt;
  decode_k<<<dim3(NBLK), dim3(256), 0, stream>>>(da);
}

// Round 3
// 27470.084 us; speedup vs baseline: 3.8219x; 3.0830x over previous
//
#include <hip/hip_runtime.h>

// ---------------------------------------------------------------------------
// MotionGenerator RNN for MI355X (gfx950).
//  - encoder: im2col + bf16 MFMA GEMM (weights are [out,in] == [N,K] B^T layout)
//  - decoder: weight-stationary persistent kernel, 212 blocks x 256 thr,
//    all decoder weights resident in VGPRs, 3 grid barriers per step.
//    pred->xcat dependency removed by composing through the linear LN/pred
//    layers (precomputed Wd_p@Wp, Wih0_p@Wp with LN gain/bias folded).
// ---------------------------------------------------------------------------

typedef unsigned short u16;
typedef __attribute__((ext_vector_type(8))) short short8;
typedef __attribute__((ext_vector_type(4))) float f32x4;

#define GELU_FLG 1
#define BF16_FLG 2
#define NBLK 212
#define DEC_STEPS 540

__device__ __forceinline__ u16 f2b(float f){
  union { float f; unsigned u; } c; c.f = f;
  return (u16)((c.u + 0x7fffu + ((c.u >> 16) & 1u)) >> 16);   // RNE
}
__device__ __forceinline__ short8 ld8(const u16* p){
  return *reinterpret_cast<const short8*>(p);
}
__device__ __forceinline__ f32x4 mfma16(short8 a, short8 b, f32x4 c){
  return __builtin_amdgcn_mfma_f32_16x16x32_bf16(a, b, c, 0, 0, 0);
}
__device__ __forceinline__ float gelu_f(float x){
  return 0.5f * x * (1.f + erff(x * 0.70710678118654752f));   // exact gelu
}
__device__ __forceinline__ float sigmoid_f(float x){
  return 1.f / (1.f + __expf(-x));
}
__device__ __forceinline__ float tanh_f(float x){
  float e = __expf(-2.f * x);
  return (1.f - e) / (1.f + e);
}

// ---------------- elementwise / gather kernels ----------------

__global__ void f2b_k(const float* __restrict__ s, u16* __restrict__ d, int n){
  int i = blockIdx.x * 256 + threadIdx.x;
  if (i < n) d[i] = f2b(s[i]);
}

__global__ void gather_xc_k(const float* __restrict__ mo, const float* __restrict__ lxm,
                            u16* __restrict__ xc, u16* __restrict__ pre_mo){
  int i = blockIdx.x * 256 + threadIdx.x;
  if (i >= 32 * 384) return;
  int n = i / 384, c = i - n * 384;
  float v = (c < 256) ? mo[(size_t)(n * 256 + c) * 600 + 29]
                      : lxm[(size_t)(n * 128 + (c - 256)) * 20];
  u16 h = f2b(v);
  xc[i] = h;
  if (c < 256) pre_mo[n * 256 + c] = h;
}

__global__ void lxm_g_k(const float* __restrict__ lxm, u16* __restrict__ o){
  int i = blockIdx.x * 256 + threadIdx.x;
  if (i >= 18 * 32 * 128) return;
  int c = i & 127, rest = i >> 7;
  int n = rest & 31, b = rest >> 5;
  o[i] = f2b(lxm[(size_t)(n * 128 + c) * 20 + 1 + b]);
}

__global__ void split_h_k(const float* __restrict__ hraw, u16* __restrict__ h0, u16* __restrict__ h1,
                          float* __restrict__ h0f, float* __restrict__ h1f){
  int i = blockIdx.x * 256 + threadIdx.x;
  if (i >= 32 * 1024) return;
  int n = i >> 10, c = i & 1023;
  float a = hraw[(size_t)n * 2048 + c];
  float b = hraw[(size_t)n * 2048 + 1024 + c];
  h0[i] = f2b(a); h1[i] = f2b(b);
  h0f[i] = a;     h1f[i] = b;
}

__global__ void build_xc0_k(const u16* __restrict__ pre_mo, const u16* __restrict__ aud_seq,
                            const u16* __restrict__ lxm_b, u16* __restrict__ xc0){
  int i = blockIdx.x * 256 + threadIdx.x;
  if (i >= 32 * 640) return;
  int n = i / 640, c = i - n * 640;
  u16 v;
  if (c < 256) v = pre_mo[n * 256 + c];
  else if (c < 512) v = aud_seq[n * 256 + (c - 256)];
  else v = lxm_b[n * 128 + (c - 512)];
  xc0[i] = v;
}

__global__ void t_wpT_k(const float* __restrict__ wp, u16* __restrict__ wpT){
  int i = blockIdx.x * 256 + threadIdx.x;
  if (i >= 1024 * 256) return;
  int h = i >> 8, j = i & 255;
  wpT[i] = f2b(wp[(size_t)j * 1024 + h]);
}

// fold LN gain/bias into a [R x 1024] matrix that acts on LN(h1):
// Wg = W * g (bf16), S[r] = sum_h W[r,h]*g[h], B[r] = sum_h W[r,h]*b[h] (+addb)
__global__ void foldW_k(const float* __restrict__ src, const float* __restrict__ g,
                        const float* __restrict__ b, const float* __restrict__ addb,
                        u16* __restrict__ Wg, float* __restrict__ S, float* __restrict__ B, int R){
  int row = blockIdx.x * 4 + (threadIdx.x >> 6);
  if (row >= R) return;
  int lane = threadIdx.x & 63;
  const float* sr = src + (size_t)row * 1024;
  float s = 0.f, bb = 0.f;
  #pragma unroll
  for (int k = 0; k < 16; ++k){
    int c = lane + k * 64;
    float w = sr[c], gw = w * g[c];
    Wg[(size_t)row * 1024 + c] = f2b(gw);
    s += gw; bb += w * b[c];
  }
  #pragma unroll
  for (int m = 1; m < 64; m <<= 1){ s += __shfl_xor(s, m); bb += __shfl_xor(bb, m); }
  if (lane == 0){ S[row] = s; B[row] = bb + (addb ? addb[row] : 0.f); }
}

// v[row] = base[row] + sum_{j<256} W[row*ldw + off + j] * pb[j]
__global__ void vfold_k(const float* __restrict__ W, int ldw, int off, const float* __restrict__ pb,
                        const float* __restrict__ base, float* __restrict__ v, int R){
  int row = blockIdx.x * 4 + (threadIdx.x >> 6);
  if (row >= R) return;
  int lane = threadIdx.x & 63;
  const float* wr = W + (size_t)row * ldw + off;
  float s = 0.f;
  #pragma unroll
  for (int k = 0; k < 4; ++k){ int j = lane + k * 64; s += wr[j] * pb[j]; }
  #pragma unroll
  for (int m = 1; m < 64; m <<= 1) s += __shfl_xor(s, m);
  if (lane == 0) v[row] = s + (base ? base[row] : 0.f);
}

// ---------------- im2col kernels ----------------

__global__ void im2col0_k(const float* __restrict__ aud, u16* __restrict__ A, int row0, long long tot){
  long long i = (long long)blockIdx.x * 256 + threadIdx.x;
  if (i >= tot) return;
  int k = (int)(i % 896);
  int row = row0 + (int)(i / 896);
  int ci = k / 7, kk = k - ci * 7;
  int p = row % 84, bn = row / 84;
  int b = bn >> 5, n = bn & 31;
  A[i] = f2b(aud[(size_t)(n * 128 + ci) * 600 + b * 30 + p + kk]);
}

__global__ void im2col1_k(const u16* __restrict__ O0, u16* __restrict__ A, int row0, long long tot){
  long long i = (long long)blockIdx.x * 256 + threadIdx.x;
  if (i >= tot) return;
  int k = (int)(i % 1280);
  int row = row0 + (int)(i / 1280);
  int ci = k / 5, kk = k - ci * 5;
  int p = row % 80, bn = row / 80;
  A[i] = O0[(size_t)(bn * 84 + p + kk) * 256 + ci];
}

__global__ void im2col2_k(const u16* __restrict__ O1, u16* __restrict__ A, int row0, long long tot){
  long long i = (long long)blockIdx.x * 256 + threadIdx.x;
  if (i >= tot) return;
  int k = (int)(i & 1023);
  int row = row0 + (int)(i >> 10);
  int ci = k >> 2, kk = k & 3;
  int p = row % 40, bn = row / 40;
  int pos = 2 * p - 1 + kk;                      // stride 2, pad 1
  A[i] = (pos >= 0 && pos < 80) ? O1[(size_t)(bn * 80 + pos) * 256 + ci] : (u16)0;
}

// ---------------- GEMM: C[M,N] = A[M,K] @ W[N,K]^T  (bf16 MFMA) ----------------

__global__ void gemm_bt(const u16* __restrict__ A, int lda,
                        const u16* __restrict__ W, int ldw, const float* __restrict__ bias,
                        void* __restrict__ outp, int M, int N, int K, int flags){
  const int lane = threadIdx.x & 63, widx = threadIdx.x >> 6;
  const int m0 = blockIdx.x * 64 + widx * 16;
  if (m0 >= M) return;
  const int n0 = blockIdx.y * 64;
  const int r = lane & 15, g4 = lane >> 4;
  const u16* arow = A + (size_t)(m0 + r) * lda + g4 * 8;
  const u16* wrow = W + (size_t)(n0 + r) * ldw + g4 * 8;
  f32x4 acc[4];
  const f32x4 FZ = {0.f, 0.f, 0.f, 0.f};
  acc[0] = FZ; acc[1] = FZ; acc[2] = FZ; acc[3] = FZ;
  for (int k = 0; k < K; k += 32){
    short8 a = ld8(arow + k);
    #pragma unroll
    for (int j = 0; j < 4; ++j)
      acc[j] = mfma16(a, ld8(wrow + (size_t)j * 16 * ldw + k), acc[j]);
  }
  #pragma unroll
  for (int j = 0; j < 4; ++j){
    int col = n0 + j * 16 + r;
    float bv = bias ? bias[col] : 0.f;
    #pragma unroll
    for (int q = 0; q < 4; ++q){
      int row = m0 + g4 * 4 + q;
      float v = acc[j][q] + bv;
      if (flags & GELU_FLG) v = gelu_f(v);
      if (flags & BF16_FLG) ((u16*)outp)[(size_t)row * N + col] = f2b(v);
      else                  ((float*)outp)[(size_t)row * N + col] = v;
    }
  }
}

// ---------------- encoder LayerNorm -> aud_seq (bf16) ----------------

__global__ void enc_ln_k(const float* __restrict__ O3, const float* __restrict__ g,
                         const float* __restrict__ bb, u16* __restrict__ aud_seq){
  int rid = blockIdx.x * 4 + (threadIdx.x >> 6);
  int lane = threadIdx.x & 63;
  int b = rid / 960, rem = rid - b * 960;
  int p2 = rem >> 5, n = rem & 31;
  int orow = (b * 32 + n) * 40 + p2;
  const float4 v = *reinterpret_cast<const float4*>(O3 + (size_t)orow * 256 + lane * 4);
  float s  = v.x + v.y + v.z + v.w;
  float s2 = v.x * v.x + v.y * v.y + v.z * v.z + v.w * v.w;
  #pragma unroll
  for (int m = 1; m < 64; m <<= 1){ s += __shfl_xor(s, m); s2 += __shfl_xor(s2, m); }
  float mu = s * (1.f / 256.f);
  float var = s2 * (1.f / 256.f) - mu * mu;
  float rs = rsqrtf(var + 1e-5f);
  int c = lane * 4;
  u16* dst = aud_seq + (size_t)rid * 256 + c;
  dst[0] = f2b((v.x - mu) * rs * g[c + 0] + bb[c + 0]);
  dst[1] = f2b((v.y - mu) * rs * g[c + 1] + bb[c + 1]);
  dst[2] = f2b((v.z - mu) * rs * g[c + 2] + bb[c + 2]);
  dst[3] = f2b((v.w - mu) * rs * g[c + 3] + bb[c + 3]);
}

// ---------------- persistent weight-stationary decoder ----------------

struct DecArgs {
  const u16 *aud_seq, *lxm_b;
  const u16 *wih0, *whh0, *wih1, *whh1, *wd;       // bf16 blobs
  const u16 *wpg, *Wdpg, *Wgpg;                    // LN-folded PE weights
  const float *Sp, *Bp, *S1, *B1, *S2, *B2, *vX, *vG;
  const float *bih0, *bhh0, *bih1, *bhh1;
  u16 *emb, *h0, *h1;
  float *h0f, *h1f, *Gx, *Xal, *Gal, *stats, *out;
  int *bar;
};

// grid barrier: 8 split counters + root release. Monotonic epochs.
__device__ __forceinline__ void gbar(int* bar, int ep){
  __syncthreads();
  if (threadIdx.x == 0){
    __threadfence();
    atomicAdd(bar + (blockIdx.x & 7) * 32, 1);
    if (blockIdx.x == 0){
      int s;
      do {
        s = 0;
        #pragma unroll
        for (int i = 0; i < 8; ++i)
          s += __hip_atomic_load(bar + i * 32, __ATOMIC_RELAXED, __HIP_MEMORY_SCOPE_AGENT);
      } while (s < ep * NBLK);
      __threadfence();
      atomicAdd(bar + 256, 1);
    }
    while (__hip_atomic_load(bar + 256, __ATOMIC_RELAXED, __HIP_MEMORY_SCOPE_AGENT) < ep)
      __builtin_amdgcn_s_sleep(1);
    __threadfence();
  }
  __syncthreads();
}

__global__ __launch_bounds__(256, 1) void decode_k(DecArgs A){
  const int tid = threadIdx.x;
  const int lane = tid & 63, q = tid >> 6;
  const int r = lane & 15, g4 = lane >> 4;
  const int blk = blockIdx.x;
  __shared__ float lds[4][4][32][16];
  const f32x4 FZ = {0.f, 0.f, 0.f, 0.f};

  if (blk < 64){
    // ---------------- L0: h0 producer (wih0_e + whh0 resident) ----------------
    const int c0 = blk * 16;
    const int kq = q * 256;
    short8 we[24], wh[24];
    #pragma unroll
    for (int g = 0; g < 3; ++g)
      #pragma unroll
      for (int ch = 0; ch < 8; ++ch){
        we[g * 8 + ch] = ld8(A.wih0 + (size_t)(g * 1024 + c0 + r) * 1664 + kq + ch * 32 + g4 * 8);
        wh[g * 8 + ch] = ld8(A.whh0 + (size_t)(g * 1024 + c0 + r) * 1024 + kq + ch * 32 + g4 * 8);
      }
    const int n_c = tid >> 3;
    const int cc0 = (tid & 7) * 2;
    const int colA = c0 + cc0, colB = colA + 1;
    const float bi_r[2] = {A.bih0[colA], A.bih0[colB]};
    const float bi_z[2] = {A.bih0[1024 + colA], A.bih0[1024 + colB]};
    const float bi_n[2] = {A.bih0[2048 + colA], A.bih0[2048 + colB]};
    const float bh_r[2] = {A.bhh0[colA], A.bhh0[colB]};
    const float bh_z[2] = {A.bhh0[1024 + colA], A.bhh0[1024 + colB]};
    const float bh_n[2] = {A.bhh0[2048 + colA], A.bhh0[2048 + colB]};
    f32x4 ar[2], az[2], ani[2], anh[2];
    // P0: gh0 on initial h0
    ar[0] = FZ; ar[1] = FZ; az[0] = FZ; az[1] = FZ; ani[0] = FZ; ani[1] = FZ; anh[0] = FZ; anh[1] = FZ;
    #pragma unroll
    for (int ch = 0; ch < 8; ++ch){
      short8 a0 = ld8(A.h0 + r * 1024 + kq + ch * 32 + g4 * 8);
      short8 a1 = ld8(A.h0 + (16 + r) * 1024 + kq + ch * 32 + g4 * 8);
      ar[0] = mfma16(a0, wh[ch], ar[0]);        ar[1] = mfma16(a1, wh[ch], ar[1]);
      az[0] = mfma16(a0, wh[8 + ch], az[0]);    az[1] = mfma16(a1, wh[8 + ch], az[1]);
      anh[0] = mfma16(a0, wh[16 + ch], anh[0]); anh[1] = mfma16(a1, wh[16 + ch], anh[1]);
    }
    int ep = 1; gbar(A.bar, ep);
    #pragma unroll 1
    for (int t = 0; t < DEC_STEPS; ++t){
      // PA: gi0e on emb (adds into resident gh0 accumulators)
      #pragma unroll
      for (int ch = 0; ch < 8; ++ch){
        short8 a0 = ld8(A.emb + r * 1024 + kq + ch * 32 + g4 * 8);
        short8 a1 = ld8(A.emb + (16 + r) * 1024 + kq + ch * 32 + g4 * 8);
        ar[0] = mfma16(a0, we[ch], ar[0]);        ar[1] = mfma16(a1, we[ch], ar[1]);
        az[0] = mfma16(a0, we[8 + ch], az[0]);    az[1] = mfma16(a1, we[8 + ch], az[1]);
        ani[0] = mfma16(a0, we[16 + ch], ani[0]); ani[1] = mfma16(a1, we[16 + ch], ani[1]);
      }
      #pragma unroll
      for (int m = 0; m < 2; ++m)
        #pragma unroll
        for (int j = 0; j < 4; ++j){
          int row = m * 16 + g4 * 4 + j;
          lds[q][0][row][r] = ar[m][j];
          lds[q][1][row][r] = az[m][j];
          lds[q][2][row][r] = ani[m][j];
          lds[q][3][row][r] = anh[m][j];
        }
      __syncthreads();
      #pragma unroll
      for (int e = 0; e < 2; ++e){
        int cc = cc0 + e, col = c0 + cc;
        float sr = bi_r[e] + bh_r[e] + A.Gx[n_c * 3072 + col];
        float sz = bi_z[e] + bh_z[e] + A.Gx[n_c * 3072 + 1024 + col];
        float si = bi_n[e] + A.Gx[n_c * 3072 + 2048 + col];
        float sh = bh_n[e];
        #pragma unroll
        for (int qq = 0; qq < 4; ++qq){
          sr += lds[qq][0][n_c][cc]; sz += lds[qq][1][n_c][cc];
          si += lds[qq][2][n_c][cc]; sh += lds[qq][3][n_c][cc];
        }
        float rg = sigmoid_f(sr), zg = sigmoid_f(sz);
        float ng = tanh_f(si + rg * sh);
        float hv = (1.f - zg) * ng + zg * A.h0f[n_c * 1024 + col];
        A.h0f[n_c * 1024 + col] = hv;
        A.h0[n_c * 1024 + col] = f2b(hv);
      }
      gbar(A.bar, ++ep);
      // PB: fresh gh0-next on h0_t
      ar[0] = FZ; ar[1] = FZ; az[0] = FZ; az[1] = FZ; ani[0] = FZ; ani[1] = FZ; anh[0] = FZ; anh[1] = FZ;
      #pragma unroll
      for (int ch = 0; ch < 8; ++ch){
        short8 a0 = ld8(A.h0 + r * 1024 + kq + ch * 32 + g4 * 8);
        short8 a1 = ld8(A.h0 + (16 + r) * 1024 + kq + ch * 32 + g4 * 8);
        ar[0] = mfma16(a0, wh[ch], ar[0]);        ar[1] = mfma16(a1, wh[ch], ar[1]);
        az[0] = mfma16(a0, wh[8 + ch], az[0]);    az[1] = mfma16(a1, wh[8 + ch], az[1]);
        anh[0] = mfma16(a0, wh[16 + ch], anh[0]); anh[1] = mfma16(a1, wh[16 + ch], anh[1]);
      }
      gbar(A.bar, ++ep);
      // PC: idle
      gbar(A.bar, ++ep);
    }
  } else if (blk < 128){
    // ---------------- L1: h1 producer (wih1 + whh1 resident) ----------------
    const int c0 = (blk - 64) * 16;
    const int kq = q * 256;
    short8 wi[24], wh[24];
    #pragma unroll
    for (int g = 0; g < 3; ++g)
      #pragma unroll
      for (int ch = 0; ch < 8; ++ch){
        wi[g * 8 + ch] = ld8(A.wih1 + (size_t)(g * 1024 + c0 + r) * 1024 + kq + ch * 32 + g4 * 8);
        wh[g * 8 + ch] = ld8(A.whh1 + (size_t)(g * 1024 + c0 + r) * 1024 + kq + ch * 32 + g4 * 8);
      }
    const int n_c = tid >> 3;
    const int cc0 = (tid & 7) * 2;
    const int colA = c0 + cc0, colB = colA + 1;
    const float bi_r[2] = {A.bih1[colA], A.bih1[colB]};
    const float bi_z[2] = {A.bih1[1024 + colA], A.bih1[1024 + colB]};
    const float bi_n[2] = {A.bih1[2048 + colA], A.bih1[2048 + colB]};
    const float bh_r[2] = {A.bhh1[colA], A.bhh1[colB]};
    const float bh_z[2] = {A.bhh1[1024 + colA], A.bhh1[1024 + colB]};
    const float bh_n[2] = {A.bhh1[2048 + colA], A.bhh1[2048 + colB]};
    f32x4 ar[2], az[2], ani[2], anh[2];
    int ep = 1; gbar(A.bar, ep);
    #pragma unroll 1
    for (int t = 0; t < DEC_STEPS; ++t){
      // PA: gh1 on h1_{t-1}
      ar[0] = FZ; ar[1] = FZ; az[0] = FZ; az[1] = FZ; ani[0] = FZ; ani[1] = FZ; anh[0] = FZ; anh[1] = FZ;
      #pragma unroll
      for (int ch = 0; ch < 8; ++ch){
        short8 a0 = ld8(A.h1 + r * 1024 + kq + ch * 32 + g4 * 8);
        short8 a1 = ld8(A.h1 + (16 + r) * 1024 + kq + ch * 32 + g4 * 8);
        ar[0] = mfma16(a0, wh[ch], ar[0]);        ar[1] = mfma16(a1, wh[ch], ar[1]);
        az[0] = mfma16(a0, wh[8 + ch], az[0]);    az[1] = mfma16(a1, wh[8 + ch], az[1]);
        anh[0] = mfma16(a0, wh[16 + ch], anh[0]); anh[1] = mfma16(a1, wh[16 + ch], anh[1]);
      }
      gbar(A.bar, ++ep);
      // PB: gi1 on h0_t, combine -> h1 + LN stats
      #pragma unroll
      for (int ch = 0; ch < 8; ++ch){
        short8 a0 = ld8(A.h0 + r * 1024 + kq + ch * 32 + g4 * 8);
        short8 a1 = ld8(A.h0 + (16 + r) * 1024 + kq + ch * 32 + g4 * 8);
        ar[0] = mfma16(a0, wi[ch], ar[0]);        ar[1] = mfma16(a1, wi[ch], ar[1]);
        az[0] = mfma16(a0, wi[8 + ch], az[0]);    az[1] = mfma16(a1, wi[8 + ch], az[1]);
        ani[0] = mfma16(a0, wi[16 + ch], ani[0]); ani[1] = mfma16(a1, wi[16 + ch], ani[1]);
      }
      #pragma unroll
      for (int m = 0; m < 2; ++m)
        #pragma unroll
        for (int j = 0; j < 4; ++j){
          int row = m * 16 + g4 * 4 + j;
          lds[q][0][row][r] = ar[m][j];
          lds[q][1][row][r] = az[m][j];
          lds[q][2][row][r] = ani[m][j];
          lds[q][3][row][r] = anh[m][j];
        }
      __syncthreads();
      float hv2[2];
      #pragma unroll
      for (int e = 0; e < 2; ++e){
        int cc = cc0 + e, col = c0 + cc;
        float sr = bi_r[e] + bh_r[e];
        float sz = bi_z[e] + bh_z[e];
        float si = bi_n[e];
        float sh = bh_n[e];
        #pragma unroll
        for (int qq = 0; qq < 4; ++qq){
          sr += lds[qq][0][n_c][cc]; sz += lds[qq][1][n_c][cc];
          si += lds[qq][2][n_c][cc]; sh += lds[qq][3][n_c][cc];
        }
        float rg = sigmoid_f(sr), zg = sigmoid_f(sz);
        float ng = tanh_f(si + rg * sh);
        float hv = (1.f - zg) * ng + zg * A.h1f[n_c * 1024 + col];
        A.h1f[n_c * 1024 + col] = hv;
        A.h1[n_c * 1024 + col] = f2b(hv);
        hv2[e] = hv;
      }
      float sv = hv2[0] + hv2[1], sq = hv2[0] * hv2[0] + hv2[1] * hv2[1];
      sv += __shfl_xor(sv, 1); sq += __shfl_xor(sq, 1);
      sv += __shfl_xor(sv, 2); sq += __shfl_xor(sq, 2);
      sv += __shfl_xor(sv, 4); sq += __shfl_xor(sq, 4);
      if ((tid & 7) == 0){
        A.stats[(blk - 64) * 64 + n_c] = sv;
        A.stats[(blk - 64) * 64 + 32 + n_c] = sq;
      }
      gbar(A.bar, ++ep);
      // PC: idle
      gbar(A.bar, ++ep);
    }
  } else if (blk < 196){
    // ---------------- PE: pred / emb_{t+1} / Gx_{t+1} on h1 (LN folded) ----------------
    const int tile = (blk - 128) * 4 + q;     // 0..271
    int jt, c0;
    const u16* wsrc; const float *Sv, *Bv;
    if (tile < 16)      { jt = 0; c0 = tile * 16;        wsrc = A.wpg;  Sv = A.Sp; Bv = A.Bp; }
    else if (tile < 80) { jt = 1; c0 = (tile - 16) * 16; wsrc = A.Wdpg; Sv = A.S1; Bv = A.B1; }
    else                { jt = 2; c0 = (tile - 80) * 16; wsrc = A.Wgpg; Sv = A.S2; Bv = A.B2; }
    short8 w[32];
    #pragma unroll
    for (int ch = 0; ch < 32; ++ch)
      w[ch] = ld8(wsrc + (size_t)(c0 + r) * 1024 + ch * 32 + g4 * 8);
    const float Sc = Sv[c0 + r], Bc = Bv[c0 + r];
    const int col = c0 + r;
    int ep = 1; gbar(A.bar, ep);
    #pragma unroll 1
    for (int t = 0; t < DEC_STEPS; ++t){
      gbar(A.bar, ++ep);   // PA idle
      gbar(A.bar, ++ep);   // PB idle
      // PC
      float sacc = 0.f;
      #pragma unroll
      for (int b2 = 0; b2 < 64; ++b2) sacc += A.stats[b2 * 64 + lane];
      float muA[2][4], rsA[2][4];
      #pragma unroll
      for (int m = 0; m < 2; ++m)
        #pragma unroll
        for (int j = 0; j < 4; ++j){
          int n = m * 16 + g4 * 4 + j;
          float sv = __shfl(sacc, n), sq = __shfl(sacc, 32 + n);
          float mu = sv * (1.f / 1024.f);
          muA[m][j] = mu;
          rsA[m][j] = rsqrtf(sq * (1.f / 1024.f) - mu * mu + 1e-5f);
        }
      f32x4 a0 = FZ, a1 = FZ;
      #pragma unroll
      for (int ch = 0; ch < 32; ++ch){
        short8 x0 = ld8(A.h1 + r * 1024 + ch * 32 + g4 * 8);
        short8 x1 = ld8(A.h1 + (16 + r) * 1024 + ch * 32 + g4 * 8);
        a0 = mfma16(x0, w[ch], a0);
        a1 = mfma16(x1, w[ch], a1);
      }
      #pragma unroll
      for (int m = 0; m < 2; ++m)
        #pragma unroll
        for (int j = 0; j < 4; ++j){
          int n = m * 16 + g4 * 4 + j;
          float acc = (m ? a1[j] : a0[j]);
          float v = rsA[m][j] * (acc - muA[m][j] * Sc) + Bc;
          if (jt == 0){
            A.out[(size_t)n * (256 * 540) + (size_t)col * 540 + t] = v;
          } else if (jt == 1){
            float pre = v + A.Xal[n * 1024 + col];
            A.emb[n * 1024 + col] = f2b(gelu_f(pre));
          } else {
            A.Gx[n * 3072 + col] = v + A.Gal[n * 3072 + col];
          }
        }
      gbar(A.bar, ++ep);
    }
  } else {
    // ---------------- AL: audio/lxm partials for step t+1 ----------------
    const int wg = (blk - 196) * 4 + q;       // 0..63
    const int at0 = wg * 4;
    short8 w[48];
    float vb[4];
    #pragma unroll
    for (int j = 0; j < 4; ++j){
      int at = at0 + j;
      if (at < 64){
        #pragma unroll
        for (int ch = 0; ch < 12; ++ch)
          w[j * 12 + ch] = ld8(A.wd + (size_t)(at * 16 + r) * 640 + 256 + ch * 32 + g4 * 8);
        vb[j] = A.vX[at * 16 + r];
      } else {
        #pragma unroll
        for (int ch = 0; ch < 12; ++ch)
          w[j * 12 + ch] = ld8(A.wih0 + (size_t)((at - 64) * 16 + r) * 1664 + 1280 + ch * 32 + g4 * 8);
        vb[j] = A.vG[(at - 64) * 16 + r];
      }
    }
    int ep = 1; gbar(A.bar, ep);
    #pragma unroll 1
    for (int t = 0; t < DEC_STEPS; ++t){
      gbar(A.bar, ++ep);   // PA idle
      // PB
      int tn = t + 1; if (tn > 539) tn = 539;
      int bn = tn / 30;
      short8 af0[12], af1[12];
      #pragma unroll
      for (int ch = 0; ch < 12; ++ch){
        int kk = ch * 32 + g4 * 8;
        if (ch < 8){
          af0[ch] = ld8(A.aud_seq + ((size_t)tn * 32 + r) * 256 + kk);
          af1[ch] = ld8(A.aud_seq + ((size_t)tn * 32 + 16 + r) * 256 + kk);
        } else {
          af0[ch] = ld8(A.lxm_b + ((size_t)bn * 32 + r) * 128 + kk - 256);
          af1[ch] = ld8(A.lxm_b + ((size_t)bn * 32 + 16 + r) * 128 + kk - 256);
        }
      }
      #pragma unroll
      for (int j = 0; j < 4; ++j){
        f32x4 c0a = FZ, c1a = FZ;
        #pragma unroll
        for (int ch = 0; ch < 12; ++ch){
          c0a = mfma16(af0[ch], w[j * 12 + ch], c0a);
          c1a = mfma16(af1[ch], w[j * 12 + ch], c1a);
        }
        int at = at0 + j;
        #pragma unroll
        for (int m = 0; m < 2; ++m)
          #pragma unroll
          for (int jj = 0; jj < 4; ++jj){
            int n = m * 16 + g4 * 4 + jj;
            float v = (m ? c1a[jj] : c0a[jj]) + vb[j];
            if (at < 64) A.Xal[n * 1024 + at * 16 + r] = v;
            else         A.Gal[n * 3072 + (at - 64) * 16 + r] = v;
          }
      }
      gbar(A.bar, ++ep);   // end PB
      gbar(A.bar, ++ep);   // PC idle
    }
  }
}

// ---------------------------------------------------------------------------

extern "C" void kernel_launch(void* const* d_in, const int* in_sizes, int n_in,
                              void* d_out, int out_size, void* d_ws, size_t ws_size,
                              hipStream_t stream) {
  enum { I_AUD=0, I_MO=1, I_LXM=2, I_AEW0=3, I_AEB0=4, I_AEW1=5, I_AEB1=6, I_AEW2=7, I_AEB2=8,
         I_AEW3=9, I_AEB3=10, I_AELNG=11, I_AELNB=12, I_CIW0=13, I_CIB0=14, I_CIW1=15, I_CIB1=16,
         I_CIW2=17, I_CIB2=18, I_DECW=19, I_DECB=20, I_WIH0=21, I_WHH0=22, I_BIH0=23, I_BHH0=24,
         I_WIH1=25, I_WHH1=26, I_BIH1=27, I_BHH1=28, I_LNG=29, I_LNB=30, I_PREDW=31, I_PREDB=32 };

  char* base = (char*)d_ws;
  size_t off = 0;
  auto alloc = [&](size_t bytes)->void*{
    void* p = base + off;
    off += (bytes + 255) & ~(size_t)255;
    return p;
  };

  // bf16 weight blobs
  u16* wd_b   = (u16*)alloc((size_t)1024*640*2);
  u16* wih0_b = (u16*)alloc((size_t)3072*1664*2);
  u16* whh0_b = (u16*)alloc((size_t)3072*1024*2);
  u16* wih1_b = (u16*)alloc((size_t)3072*1024*2);
  u16* whh1_b = (u16*)alloc((size_t)3072*1024*2);
  u16* wc0    = (u16*)alloc((size_t)1024*384*2);
  u16* wc1    = (u16*)alloc((size_t)1024*1024*2);
  u16* wc2    = (u16*)alloc((size_t)2048*1024*2);
  u16* w0k    = (u16*)alloc((size_t)256*896*2);
  u16* w1k    = (u16*)alloc((size_t)256*1280*2);
  u16* w2k    = (u16*)alloc((size_t)256*1024*2);
  u16* w3k    = (u16*)alloc((size_t)256*256*2);
  u16* wpT    = (u16*)alloc((size_t)1024*256*2);
  u16* wpg    = (u16*)alloc((size_t)256*1024*2);
  u16* Wdpg   = (u16*)alloc((size_t)1024*1024*2);
  u16* Wgpg   = (u16*)alloc((size_t)3072*1024*2);
  float* Sp = (float*)alloc(256*4);   float* Bp = (float*)alloc(256*4);
  float* S1 = (float*)alloc(1024*4);  float* B1 = (float*)alloc(1024*4);
  float* S2 = (float*)alloc(3072*4);  float* B2 = (float*)alloc(3072*4);
  float* vX = (float*)alloc(1024*4);  float* vG = (float*)alloc(3072*4);
  // sequences / state
  u16* aud_seq = (u16*)alloc((size_t)540*32*256*2);
  u16* lxm_b   = (u16*)alloc((size_t)18*32*128*2);
  u16* xc      = (u16*)alloc((size_t)32*384*2);
  u16* xc0     = (u16*)alloc((size_t)32*640*2);
  u16* ci1     = (u16*)alloc((size_t)32*1024*2);
  u16* ci2     = (u16*)alloc((size_t)32*1024*2);
  float* hraw  = (float*)alloc((size_t)32*2048*4);
  u16* h0      = (u16*)alloc((size_t)32*1024*2);
  u16* h1      = (u16*)alloc((size_t)32*1024*2);
  float* h0f   = (float*)alloc((size_t)32*1024*4);
  float* h1f   = (float*)alloc((size_t)32*1024*4);
  u16* emb     = (u16*)alloc((size_t)32*1024*2);
  u16* pre_mo  = (u16*)alloc((size_t)32*256*2);
  float* Gx    = (float*)alloc((size_t)32*3072*4);
  float* Xal   = (float*)alloc((size_t)32*1024*4);
  float* Gal   = (float*)alloc((size_t)32*3072*4);
  float* stats = (float*)alloc((size_t)64*64*4);
  int* bar     = (int*)alloc(4096);
  // encoder transients
  u16* O0   = (u16*)alloc((size_t)48384*256*2);
  u16* O1   = (u16*)alloc((size_t)46080*256*2);
  u16* O2   = (u16*)alloc((size_t)23040*256*2);
  float* O3 = (float*)alloc((size_t)23040*256*4);
  u16* Abuf = (u16*)alloc((size_t)23040*1280*2);
  // composition temps alias Abuf (free after conv GEMMs)
  float* Wdp_f = (float*)Abuf;                                  // 4 MB
  float* Wgp_f = (float*)((char*)Abuf + (size_t)1024*1024*4 + 256);  // 12.6 MB
  (void)ws_size; (void)in_sizes; (void)n_in; (void)out_size;

  const float* aud = (const float*)d_in[I_AUD];
  const float* mo  = (const float*)d_in[I_MO];
  const float* lxm = (const float*)d_in[I_LXM];
  float* out = (float*)d_out;

  auto cdiv = [](long long a, long long b)->int{ return (int)((a + b - 1) / b); };
  auto cvt = [&](int idx, u16* dst, int n){
    f2b_k<<<cdiv(n,256), 256, 0, stream>>>((const float*)d_in[idx], dst, n);
  };

  // ---- weight conversion ----
  cvt(I_DECW, wd_b,   1024*640);
  cvt(I_WIH0, wih0_b, 3072*1664);
  cvt(I_WHH0, whh0_b, 3072*1024);
  cvt(I_WIH1, wih1_b, 3072*1024);
  cvt(I_WHH1, whh1_b, 3072*1024);
  cvt(I_CIW0, wc0,    1024*384);
  cvt(I_CIW1, wc1,    1024*1024);
  cvt(I_CIW2, wc2,    2048*1024);
  cvt(I_AEW0, w0k,    256*896);
  cvt(I_AEW1, w1k,    256*1280);
  cvt(I_AEW2, w2k,    256*1024);
  cvt(I_AEW3, w3k,    256*256);

  // ---- encoder ----
  for (int c = 0; c < 2; ++c){
    int row0 = c * 24192;
    long long tot = (long long)24192 * 896;
    im2col0_k<<<cdiv(tot,256), 256, 0, stream>>>(aud, Abuf, row0, tot);
    gemm_bt<<<dim3(24192/64, 4), 256, 0, stream>>>(Abuf, 896, w0k, 896, (const float*)d_in[I_AEB0],
        O0 + (size_t)row0*256, 24192, 256, 896, GELU_FLG|BF16_FLG);
  }
  for (int c = 0; c < 2; ++c){
    int row0 = c * 23040;
    long long tot = (long long)23040 * 1280;
    im2col1_k<<<cdiv(tot,256), 256, 0, stream>>>(O0, Abuf, row0, tot);
    gemm_bt<<<dim3(23040/64, 4), 256, 0, stream>>>(Abuf, 1280, w1k, 1280, (const float*)d_in[I_AEB1],
        O1 + (size_t)row0*256, 23040, 256, 1280, GELU_FLG|BF16_FLG);
  }
  {
    long long tot = (long long)23040 * 1024;
    im2col2_k<<<cdiv(tot,256), 256, 0, stream>>>(O1, Abuf, 0, tot);
    gemm_bt<<<dim3(23040/64, 4), 256, 0, stream>>>(Abuf, 1024, w2k, 1024, (const float*)d_in[I_AEB2],
        O2, 23040, 256, 1024, GELU_FLG|BF16_FLG);
  }
  gemm_bt<<<dim3(23040/64, 4), 256, 0, stream>>>(O2, 256, w3k, 256, (const float*)d_in[I_AEB3],
      O3, 23040, 256, 256, GELU_FLG);
  enc_ln_k<<<4320, 256, 0, stream>>>(O3, (const float*)d_in[I_AELNG], (const float*)d_in[I_AELNB], aud_seq);

  // ---- lxm + cell-init chain ----
  lxm_g_k<<<cdiv(18*32*128,256), 256, 0, stream>>>(lxm, lxm_b);
  gather_xc_k<<<cdiv(32*384,256), 256, 0, stream>>>(mo, lxm, xc, pre_mo);
  gemm_bt<<<dim3(1,16), 256, 0, stream>>>(xc, 384, wc0, 384, (const float*)d_in[I_CIB0],
      ci1, 32, 1024, 384, GELU_FLG|BF16_FLG);
  gemm_bt<<<dim3(1,16), 256, 0, stream>>>(ci1, 1024, wc1, 1024, (const float*)d_in[I_CIB1],
      ci2, 32, 1024, 1024, GELU_FLG|BF16_FLG);
  gemm_bt<<<dim3(1,32), 256, 0, stream>>>(ci2, 1024, wc2, 1024, (const float*)d_in[I_CIB2],
      hraw, 32, 2048, 1024, 0);
  split_h_k<<<cdiv(32*1024,256), 256, 0, stream>>>(hraw, h0, h1, h0f, h1f);

  // ---- composition precompute ----
  t_wpT_k<<<cdiv(1024*256,256), 256, 0, stream>>>((const float*)d_in[I_PREDW], wpT);
  // Wdp = Wd_p @ Wp  (wd cols 0..255), Wgp = Wih0_p @ Wp (wih0 cols 1024..1279)
  gemm_bt<<<dim3(16,16), 256, 0, stream>>>(wd_b, 640, wpT, 256, nullptr, Wdp_f, 1024, 1024, 256, 0);
  gemm_bt<<<dim3(48,16), 256, 0, stream>>>(wih0_b + 1024, 1664, wpT, 256, nullptr, Wgp_f, 3072, 1024, 256, 0);
  foldW_k<<<cdiv(1024,4), 256, 0, stream>>>(Wdp_f, (const float*)d_in[I_LNG], (const float*)d_in[I_LNB],
      nullptr, Wdpg, S1, B1, 1024);
  foldW_k<<<cdiv(3072,4), 256, 0, stream>>>(Wgp_f, (const float*)d_in[I_LNG], (const float*)d_in[I_LNB],
      nullptr, Wgpg, S2, B2, 3072);
  foldW_k<<<cdiv(256,4), 256, 0, stream>>>((const float*)d_in[I_PREDW], (const float*)d_in[I_LNG],
      (const float*)d_in[I_LNB], (const float*)d_in[I_PREDB], wpg, Sp, Bp, 256);
  // vX = db + Wd_p @ pb ; vG = Wih0_p @ pb
  vfold_k<<<cdiv(1024,4), 256, 0, stream>>>((const float*)d_in[I_DECW], 640, 0,
      (const float*)d_in[I_PREDB], (const float*)d_in[I_DECB], vX, 1024);
  vfold_k<<<cdiv(3072,4), 256, 0, stream>>>((const float*)d_in[I_WIH0], 1664, 1024,
      (const float*)d_in[I_PREDB], nullptr, vG, 3072);

  // ---- t=0 boot values: emb_0 and Gx_0 from the real xcat_0 ----
  build_xc0_k<<<cdiv(32*640,256), 256, 0, stream>>>(pre_mo, aud_seq, lxm_b, xc0);
  gemm_bt<<<dim3(1,16), 256, 0, stream>>>(xc0, 640, wd_b, 640, (const float*)d_in[I_DECB],
      emb, 32, 1024, 640, GELU_FLG|BF16_FLG);
  gemm_bt<<<dim3(1,48), 256, 0, stream>>>(xc0, 640, wih0_b + 1024, 1664, nullptr,
      Gx, 32, 3072, 640, 0);

  hipMemsetAsync(bar, 0, 4096, stream);

  // ---- persistent decoder ----
  DecArgs da;
  da.aud_seq = aud_seq; da.lxm_b = lxm_b;
  da.wih0 = wih0_b; da.whh0 = whh0_b; da.wih1 = wih1_b; da.whh1 = whh1_b; da.wd = wd_b;
  da.wpg = wpg; da.Wdpg = Wdpg; da.Wgpg = Wgpg;
  da.Sp = Sp; da.Bp = Bp; da.S1 = S1; da.B1 = B1; da.S2 = S2; da.B2 = B2; da.vX = vX; da.vG = vG;
  da.bih0 = (const float*)d_in[I_BIH0]; da.bhh0 = (const float*)d_in[I_BHH0];
  da.bih1 = (const float*)d_in[I_BIH1]; da.bhh1 = (const float*)d_in[I_BHH1];
  da.emb = emb; da.h0 = h0; da.h1 = h1;
  da.h0f = h0f; da.h1f = h1f; da.Gx = Gx; da.Xal = Xal; da.Gal = Gal;
  da.stats = stats; da.out = out; da.bar = bar;
  decode_k<<<dim3(NBLK), dim3(256), 0, stream>>>(da);
}

// Round 4
// 27384.241 us; speedup vs baseline: 3.8338x; 1.0031x over previous
//
#include <hip/hip_runtime.h>

// ---------------------------------------------------------------------------
// MotionGenerator RNN for MI355X (gfx950).
//  - encoder: im2col + bf16 MFMA GEMM (weights are [out,in] == [N,K] B^T layout)
//  - decoder: weight-stationary persistent kernel, 212 blocks x 256 thr,
//    all decoder weights resident in VGPRs, 3 grid barriers per step.
//    Barrier = per-block arrival slots + all-blocks-parallel poll (no RMW).
//    pred->xcat dependency removed by composing through the linear LN/pred
//    layers (precomputed Wd_p@Wp, Wih0_p@Wp with LN gain/bias folded).
// ---------------------------------------------------------------------------

typedef unsigned short u16;
typedef __attribute__((ext_vector_type(8))) short short8;
typedef __attribute__((ext_vector_type(4))) float f32x4;

#define GELU_FLG 1
#define BF16_FLG 2
#define NBLK 212
#define DEC_STEPS 540

__device__ __forceinline__ u16 f2b(float f){
  union { float f; unsigned u; } c; c.f = f;
  return (u16)((c.u + 0x7fffu + ((c.u >> 16) & 1u)) >> 16);   // RNE
}
__device__ __forceinline__ short8 ld8(const u16* p){
  return *reinterpret_cast<const short8*>(p);
}
__device__ __forceinline__ f32x4 mfma16(short8 a, short8 b, f32x4 c){
  return __builtin_amdgcn_mfma_f32_16x16x32_bf16(a, b, c, 0, 0, 0);
}
__device__ __forceinline__ float gelu_f(float x){
  return 0.5f * x * (1.f + erff(x * 0.70710678118654752f));   // exact gelu
}
__device__ __forceinline__ float sigmoid_f(float x){
  return 1.f / (1.f + __expf(-x));
}
__device__ __forceinline__ float tanh_f(float x){
  float e = __expf(-2.f * x);
  return (1.f - e) / (1.f + e);
}

// ---------------- elementwise / gather kernels ----------------

__global__ void f2b_k(const float* __restrict__ s, u16* __restrict__ d, int n){
  int i = blockIdx.x * 256 + threadIdx.x;
  if (i < n) d[i] = f2b(s[i]);
}

__global__ void gather_xc_k(const float* __restrict__ mo, const float* __restrict__ lxm,
                            u16* __restrict__ xc, u16* __restrict__ pre_mo){
  int i = blockIdx.x * 256 + threadIdx.x;
  if (i >= 32 * 384) return;
  int n = i / 384, c = i - n * 384;
  float v = (c < 256) ? mo[(size_t)(n * 256 + c) * 600 + 29]
                      : lxm[(size_t)(n * 128 + (c - 256)) * 20];
  u16 h = f2b(v);
  xc[i] = h;
  if (c < 256) pre_mo[n * 256 + c] = h;
}

__global__ void lxm_g_k(const float* __restrict__ lxm, u16* __restrict__ o){
  int i = blockIdx.x * 256 + threadIdx.x;
  if (i >= 18 * 32 * 128) return;
  int c = i & 127, rest = i >> 7;
  int n = rest & 31, b = rest >> 5;
  o[i] = f2b(lxm[(size_t)(n * 128 + c) * 20 + 1 + b]);
}

__global__ void split_h_k(const float* __restrict__ hraw, u16* __restrict__ h0, u16* __restrict__ h1,
                          float* __restrict__ h0f, float* __restrict__ h1f){
  int i = blockIdx.x * 256 + threadIdx.x;
  if (i >= 32 * 1024) return;
  int n = i >> 10, c = i & 1023;
  float a = hraw[(size_t)n * 2048 + c];
  float b = hraw[(size_t)n * 2048 + 1024 + c];
  h0[i] = f2b(a); h1[i] = f2b(b);
  h0f[i] = a;     h1f[i] = b;
}

__global__ void build_xc0_k(const u16* __restrict__ pre_mo, const u16* __restrict__ aud_seq,
                            const u16* __restrict__ lxm_b, u16* __restrict__ xc0){
  int i = blockIdx.x * 256 + threadIdx.x;
  if (i >= 32 * 640) return;
  int n = i / 640, c = i - n * 640;
  u16 v;
  if (c < 256) v = pre_mo[n * 256 + c];
  else if (c < 512) v = aud_seq[n * 256 + (c - 256)];
  else v = lxm_b[n * 128 + (c - 512)];
  xc0[i] = v;
}

__global__ void t_wpT_k(const float* __restrict__ wp, u16* __restrict__ wpT){
  int i = blockIdx.x * 256 + threadIdx.x;
  if (i >= 1024 * 256) return;
  int h = i >> 8, j = i & 255;
  wpT[i] = f2b(wp[(size_t)j * 1024 + h]);
}

// fold LN gain/bias into a [R x 1024] matrix that acts on LN(h1):
// Wg = W * g (bf16), S[r] = sum_h W[r,h]*g[h], B[r] = sum_h W[r,h]*b[h] (+addb)
__global__ void foldW_k(const float* __restrict__ src, const float* __restrict__ g,
                        const float* __restrict__ b, const float* __restrict__ addb,
                        u16* __restrict__ Wg, float* __restrict__ S, float* __restrict__ B, int R){
  int row = blockIdx.x * 4 + (threadIdx.x >> 6);
  if (row >= R) return;
  int lane = threadIdx.x & 63;
  const float* sr = src + (size_t)row * 1024;
  float s = 0.f, bb = 0.f;
  #pragma unroll
  for (int k = 0; k < 16; ++k){
    int c = lane + k * 64;
    float w = sr[c], gw = w * g[c];
    Wg[(size_t)row * 1024 + c] = f2b(gw);
    s += gw; bb += w * b[c];
  }
  #pragma unroll
  for (int m = 1; m < 64; m <<= 1){ s += __shfl_xor(s, m); bb += __shfl_xor(bb, m); }
  if (lane == 0){ S[row] = s; B[row] = bb + (addb ? addb[row] : 0.f); }
}

// v[row] = base[row] + sum_{j<256} W[row*ldw + off + j] * pb[j]
__global__ void vfold_k(const float* __restrict__ W, int ldw, int off, const float* __restrict__ pb,
                        const float* __restrict__ base, float* __restrict__ v, int R){
  int row = blockIdx.x * 4 + (threadIdx.x >> 6);
  if (row >= R) return;
  int lane = threadIdx.x & 63;
  const float* wr = W + (size_t)row * ldw + off;
  float s = 0.f;
  #pragma unroll
  for (int k = 0; k < 4; ++k){ int j = lane + k * 64; s += wr[j] * pb[j]; }
  #pragma unroll
  for (int m = 1; m < 64; m <<= 1) s += __shfl_xor(s, m);
  if (lane == 0) v[row] = s + (base ? base[row] : 0.f);
}

// ---------------- im2col kernels ----------------

__global__ void im2col0_k(const float* __restrict__ aud, u16* __restrict__ A, int row0, long long tot){
  long long i = (long long)blockIdx.x * 256 + threadIdx.x;
  if (i >= tot) return;
  int k = (int)(i % 896);
  int row = row0 + (int)(i / 896);
  int ci = k / 7, kk = k - ci * 7;
  int p = row % 84, bn = row / 84;
  int b = bn >> 5, n = bn & 31;
  A[i] = f2b(aud[(size_t)(n * 128 + ci) * 600 + b * 30 + p + kk]);
}

__global__ void im2col1_k(const u16* __restrict__ O0, u16* __restrict__ A, int row0, long long tot){
  long long i = (long long)blockIdx.x * 256 + threadIdx.x;
  if (i >= tot) return;
  int k = (int)(i % 1280);
  int row = row0 + (int)(i / 1280);
  int ci = k / 5, kk = k - ci * 5;
  int p = row % 80, bn = row / 80;
  A[i] = O0[(size_t)(bn * 84 + p + kk) * 256 + ci];
}

__global__ void im2col2_k(const u16* __restrict__ O1, u16* __restrict__ A, int row0, long long tot){
  long long i = (long long)blockIdx.x * 256 + threadIdx.x;
  if (i >= tot) return;
  int k = (int)(i & 1023);
  int row = row0 + (int)(i >> 10);
  int ci = k >> 2, kk = k & 3;
  int p = row % 40, bn = row / 40;
  int pos = 2 * p - 1 + kk;                      // stride 2, pad 1
  A[i] = (pos >= 0 && pos < 80) ? O1[(size_t)(bn * 80 + pos) * 256 + ci] : (u16)0;
}

// ---------------- GEMM: C[M,N] = A[M,K] @ W[N,K]^T  (bf16 MFMA) ----------------

__global__ void gemm_bt(const u16* __restrict__ A, int lda,
                        const u16* __restrict__ W, int ldw, const float* __restrict__ bias,
                        void* __restrict__ outp, int M, int N, int K, int flags){
  const int lane = threadIdx.x & 63, widx = threadIdx.x >> 6;
  const int m0 = blockIdx.x * 64 + widx * 16;
  if (m0 >= M) return;
  const int n0 = blockIdx.y * 64;
  const int r = lane & 15, g4 = lane >> 4;
  const u16* arow = A + (size_t)(m0 + r) * lda + g4 * 8;
  const u16* wrow = W + (size_t)(n0 + r) * ldw + g4 * 8;
  f32x4 acc[4];
  const f32x4 FZ = {0.f, 0.f, 0.f, 0.f};
  acc[0] = FZ; acc[1] = FZ; acc[2] = FZ; acc[3] = FZ;
  for (int k = 0; k < K; k += 32){
    short8 a = ld8(arow + k);
    #pragma unroll
    for (int j = 0; j < 4; ++j)
      acc[j] = mfma16(a, ld8(wrow + (size_t)j * 16 * ldw + k), acc[j]);
  }
  #pragma unroll
  for (int j = 0; j < 4; ++j){
    int col = n0 + j * 16 + r;
    float bv = bias ? bias[col] : 0.f;
    #pragma unroll
    for (int q = 0; q < 4; ++q){
      int row = m0 + g4 * 4 + q;
      float v = acc[j][q] + bv;
      if (flags & GELU_FLG) v = gelu_f(v);
      if (flags & BF16_FLG) ((u16*)outp)[(size_t)row * N + col] = f2b(v);
      else                  ((float*)outp)[(size_t)row * N + col] = v;
    }
  }
}

// ---------------- encoder LayerNorm -> aud_seq (bf16) ----------------

__global__ void enc_ln_k(const float* __restrict__ O3, const float* __restrict__ g,
                         const float* __restrict__ bb, u16* __restrict__ aud_seq){
  int rid = blockIdx.x * 4 + (threadIdx.x >> 6);
  int lane = threadIdx.x & 63;
  int b = rid / 960, rem = rid - b * 960;
  int p2 = rem >> 5, n = rem & 31;
  int orow = (b * 32 + n) * 40 + p2;
  const float4 v = *reinterpret_cast<const float4*>(O3 + (size_t)orow * 256 + lane * 4);
  float s  = v.x + v.y + v.z + v.w;
  float s2 = v.x * v.x + v.y * v.y + v.z * v.z + v.w * v.w;
  #pragma unroll
  for (int m = 1; m < 64; m <<= 1){ s += __shfl_xor(s, m); s2 += __shfl_xor(s2, m); }
  float mu = s * (1.f / 256.f);
  float var = s2 * (1.f / 256.f) - mu * mu;
  float rs = rsqrtf(var + 1e-5f);
  int c = lane * 4;
  u16* dst = aud_seq + (size_t)rid * 256 + c;
  dst[0] = f2b((v.x - mu) * rs * g[c + 0] + bb[c + 0]);
  dst[1] = f2b((v.y - mu) * rs * g[c + 1] + bb[c + 1]);
  dst[2] = f2b((v.z - mu) * rs * g[c + 2] + bb[c + 2]);
  dst[3] = f2b((v.w - mu) * rs * g[c + 3] + bb[c + 3]);
}

// ---------------- persistent weight-stationary decoder ----------------

struct DecArgs {
  const u16 *aud_seq, *lxm_b;
  const u16 *wih0, *whh0, *wih1, *whh1, *wd;       // bf16 blobs
  const u16 *wpg, *Wdpg, *Wgpg;                    // LN-folded PE weights
  const float *Sp, *Bp, *S1, *B1, *S2, *B2, *vX, *vG;
  const float *bih0, *bhh0, *bih1, *bhh1;
  u16 *emb, *h0, *h1;
  float *h0f, *h1f, *Gx, *Xal, *Gal, *stats, *out;
  int *bar;
};

// grid barrier: per-block arrival slot (64B apart, plain store, no RMW) +
// every block's threads 0..NBLK-1 poll one slot each in parallel. 2 hops.
__device__ __forceinline__ void gbar(int* bar, int ep){
  __syncthreads();                               // block writes complete
  if (threadIdx.x == 0){
    __threadfence();                             // release (wbL2)
    __hip_atomic_store(bar + blockIdx.x * 16, ep, __ATOMIC_RELAXED, __HIP_MEMORY_SCOPE_AGENT);
  }
  if (threadIdx.x < NBLK){
    while (__hip_atomic_load(bar + threadIdx.x * 16, __ATOMIC_RELAXED, __HIP_MEMORY_SCOPE_AGENT) < ep)
      __builtin_amdgcn_s_sleep(1);
  }
  __syncthreads();                               // all slots seen
  if (threadIdx.x == 0) __threadfence();         // acquire (invL1/L2)
  __syncthreads();
}

__global__ __launch_bounds__(256, 1) void decode_k(DecArgs A){
  const int tid = threadIdx.x;
  const int lane = tid & 63, q = tid >> 6;
  const int r = lane & 15, g4 = lane >> 4;
  const int blk = blockIdx.x;
  __shared__ float lds[4][4][32][16];
  const f32x4 FZ = {0.f, 0.f, 0.f, 0.f};

  if (blk < 64){
    // ---------------- L0: h0 producer (wih0_e + whh0 resident) ----------------
    const int c0 = blk * 16;
    const int kq = q * 256;
    short8 we[24], wh[24];
    #pragma unroll
    for (int g = 0; g < 3; ++g)
      #pragma unroll
      for (int ch = 0; ch < 8; ++ch){
        we[g * 8 + ch] = ld8(A.wih0 + (size_t)(g * 1024 + c0 + r) * 1664 + kq + ch * 32 + g4 * 8);
        wh[g * 8 + ch] = ld8(A.whh0 + (size_t)(g * 1024 + c0 + r) * 1024 + kq + ch * 32 + g4 * 8);
      }
    const int n_c = tid >> 3;
    const int cc0 = (tid & 7) * 2;
    const int colA = c0 + cc0, colB = colA + 1;
    const float bi_r[2] = {A.bih0[colA], A.bih0[colB]};
    const float bi_z[2] = {A.bih0[1024 + colA], A.bih0[1024 + colB]};
    const float bi_n[2] = {A.bih0[2048 + colA], A.bih0[2048 + colB]};
    const float bh_r[2] = {A.bhh0[colA], A.bhh0[colB]};
    const float bh_z[2] = {A.bhh0[1024 + colA], A.bhh0[1024 + colB]};
    const float bh_n[2] = {A.bhh0[2048 + colA], A.bhh0[2048 + colB]};
    f32x4 ar[2], az[2], ani[2], anh[2];
    // P0: gh0 on initial h0
    ar[0] = FZ; ar[1] = FZ; az[0] = FZ; az[1] = FZ; ani[0] = FZ; ani[1] = FZ; anh[0] = FZ; anh[1] = FZ;
    #pragma unroll
    for (int ch = 0; ch < 8; ++ch){
      short8 a0 = ld8(A.h0 + r * 1024 + kq + ch * 32 + g4 * 8);
      short8 a1 = ld8(A.h0 + (16 + r) * 1024 + kq + ch * 32 + g4 * 8);
      ar[0] = mfma16(a0, wh[ch], ar[0]);        ar[1] = mfma16(a1, wh[ch], ar[1]);
      az[0] = mfma16(a0, wh[8 + ch], az[0]);    az[1] = mfma16(a1, wh[8 + ch], az[1]);
      anh[0] = mfma16(a0, wh[16 + ch], anh[0]); anh[1] = mfma16(a1, wh[16 + ch], anh[1]);
    }
    int ep = 1; gbar(A.bar, ep);
    #pragma unroll 1
    for (int t = 0; t < DEC_STEPS; ++t){
      // PA: prefetch Gx/h0f (ready since last barrier), gi0e on emb, combine
      float pgr[2], pgz[2], pgn[2], phf[2];
      #pragma unroll
      for (int e = 0; e < 2; ++e){
        int col = c0 + cc0 + e;
        pgr[e] = A.Gx[n_c * 3072 + col];
        pgz[e] = A.Gx[n_c * 3072 + 1024 + col];
        pgn[e] = A.Gx[n_c * 3072 + 2048 + col];
        phf[e] = A.h0f[n_c * 1024 + col];
      }
      #pragma unroll
      for (int ch = 0; ch < 8; ++ch){
        short8 a0 = ld8(A.emb + r * 1024 + kq + ch * 32 + g4 * 8);
        short8 a1 = ld8(A.emb + (16 + r) * 1024 + kq + ch * 32 + g4 * 8);
        ar[0] = mfma16(a0, we[ch], ar[0]);        ar[1] = mfma16(a1, we[ch], ar[1]);
        az[0] = mfma16(a0, we[8 + ch], az[0]);    az[1] = mfma16(a1, we[8 + ch], az[1]);
        ani[0] = mfma16(a0, we[16 + ch], ani[0]); ani[1] = mfma16(a1, we[16 + ch], ani[1]);
      }
      #pragma unroll
      for (int m = 0; m < 2; ++m)
        #pragma unroll
        for (int j = 0; j < 4; ++j){
          int row = m * 16 + g4 * 4 + j;
          lds[q][0][row][r] = ar[m][j];
          lds[q][1][row][r] = az[m][j];
          lds[q][2][row][r] = ani[m][j];
          lds[q][3][row][r] = anh[m][j];
        }
      __syncthreads();
      #pragma unroll
      for (int e = 0; e < 2; ++e){
        int cc = cc0 + e, col = c0 + cc;
        float sr = bi_r[e] + bh_r[e] + pgr[e];
        float sz = bi_z[e] + bh_z[e] + pgz[e];
        float si = bi_n[e] + pgn[e];
        float sh = bh_n[e];
        #pragma unroll
        for (int qq = 0; qq < 4; ++qq){
          sr += lds[qq][0][n_c][cc]; sz += lds[qq][1][n_c][cc];
          si += lds[qq][2][n_c][cc]; sh += lds[qq][3][n_c][cc];
        }
        float rg = sigmoid_f(sr), zg = sigmoid_f(sz);
        float ng = tanh_f(si + rg * sh);
        float hv = (1.f - zg) * ng + zg * phf[e];
        A.h0f[n_c * 1024 + col] = hv;
        A.h0[n_c * 1024 + col] = f2b(hv);
      }
      gbar(A.bar, ++ep);
      // PB: fresh gh0-next on h0_t
      ar[0] = FZ; ar[1] = FZ; az[0] = FZ; az[1] = FZ; ani[0] = FZ; ani[1] = FZ; anh[0] = FZ; anh[1] = FZ;
      #pragma unroll
      for (int ch = 0; ch < 8; ++ch){
        short8 a0 = ld8(A.h0 + r * 1024 + kq + ch * 32 + g4 * 8);
        short8 a1 = ld8(A.h0 + (16 + r) * 1024 + kq + ch * 32 + g4 * 8);
        ar[0] = mfma16(a0, wh[ch], ar[0]);        ar[1] = mfma16(a1, wh[ch], ar[1]);
        az[0] = mfma16(a0, wh[8 + ch], az[0]);    az[1] = mfma16(a1, wh[8 + ch], az[1]);
        anh[0] = mfma16(a0, wh[16 + ch], anh[0]); anh[1] = mfma16(a1, wh[16 + ch], anh[1]);
      }
      gbar(A.bar, ++ep);
      // PC: idle
      gbar(A.bar, ++ep);
    }
  } else if (blk < 128){
    // ---------------- L1: h1 producer (wih1 + whh1 resident) ----------------
    const int c0 = (blk - 64) * 16;
    const int kq = q * 256;
    short8 wi[24], wh[24];
    #pragma unroll
    for (int g = 0; g < 3; ++g)
      #pragma unroll
      for (int ch = 0; ch < 8; ++ch){
        wi[g * 8 + ch] = ld8(A.wih1 + (size_t)(g * 1024 + c0 + r) * 1024 + kq + ch * 32 + g4 * 8);
        wh[g * 8 + ch] = ld8(A.whh1 + (size_t)(g * 1024 + c0 + r) * 1024 + kq + ch * 32 + g4 * 8);
      }
    const int n_c = tid >> 3;
    const int cc0 = (tid & 7) * 2;
    const int colA = c0 + cc0, colB = colA + 1;
    const float bi_r[2] = {A.bih1[colA], A.bih1[colB]};
    const float bi_z[2] = {A.bih1[1024 + colA], A.bih1[1024 + colB]};
    const float bi_n[2] = {A.bih1[2048 + colA], A.bih1[2048 + colB]};
    const float bh_r[2] = {A.bhh1[colA], A.bhh1[colB]};
    const float bh_z[2] = {A.bhh1[1024 + colA], A.bhh1[1024 + colB]};
    const float bh_n[2] = {A.bhh1[2048 + colA], A.bhh1[2048 + colB]};
    f32x4 ar[2], az[2], ani[2], anh[2];
    // pre-loop: gh1 on initial h1
    ar[0] = FZ; ar[1] = FZ; az[0] = FZ; az[1] = FZ; ani[0] = FZ; ani[1] = FZ; anh[0] = FZ; anh[1] = FZ;
    #pragma unroll
    for (int ch = 0; ch < 8; ++ch){
      short8 a0 = ld8(A.h1 + r * 1024 + kq + ch * 32 + g4 * 8);
      short8 a1 = ld8(A.h1 + (16 + r) * 1024 + kq + ch * 32 + g4 * 8);
      ar[0] = mfma16(a0, wh[ch], ar[0]);        ar[1] = mfma16(a1, wh[ch], ar[1]);
      az[0] = mfma16(a0, wh[8 + ch], az[0]);    az[1] = mfma16(a1, wh[8 + ch], az[1]);
      anh[0] = mfma16(a0, wh[16 + ch], anh[0]); anh[1] = mfma16(a1, wh[16 + ch], anh[1]);
    }
    int ep = 1; gbar(A.bar, ep);
    #pragma unroll 1
    for (int t = 0; t < DEC_STEPS; ++t){
      // PA: idle (gh1 already computed in previous PC / pre-loop)
      gbar(A.bar, ++ep);
      // PB: gi1 on h0_t, combine -> h1 + LN stats
      float phf[2];
      phf[0] = A.h1f[n_c * 1024 + colA];
      phf[1] = A.h1f[n_c * 1024 + colB];
      #pragma unroll
      for (int ch = 0; ch < 8; ++ch){
        short8 a0 = ld8(A.h0 + r * 1024 + kq + ch * 32 + g4 * 8);
        short8 a1 = ld8(A.h0 + (16 + r) * 1024 + kq + ch * 32 + g4 * 8);
        ar[0] = mfma16(a0, wi[ch], ar[0]);        ar[1] = mfma16(a1, wi[ch], ar[1]);
        az[0] = mfma16(a0, wi[8 + ch], az[0]);    az[1] = mfma16(a1, wi[8 + ch], az[1]);
        ani[0] = mfma16(a0, wi[16 + ch], ani[0]); ani[1] = mfma16(a1, wi[16 + ch], ani[1]);
      }
      #pragma unroll
      for (int m = 0; m < 2; ++m)
        #pragma unroll
        for (int j = 0; j < 4; ++j){
          int row = m * 16 + g4 * 4 + j;
          lds[q][0][row][r] = ar[m][j];
          lds[q][1][row][r] = az[m][j];
          lds[q][2][row][r] = ani[m][j];
          lds[q][3][row][r] = anh[m][j];
        }
      __syncthreads();
      float hv2[2];
      #pragma unroll
      for (int e = 0; e < 2; ++e){
        int cc = cc0 + e, col = c0 + cc;
        float sr = bi_r[e] + bh_r[e];
        float sz = bi_z[e] + bh_z[e];
        float si = bi_n[e];
        float sh = bh_n[e];
        #pragma unroll
        for (int qq = 0; qq < 4; ++qq){
          sr += lds[qq][0][n_c][cc]; sz += lds[qq][1][n_c][cc];
          si += lds[qq][2][n_c][cc]; sh += lds[qq][3][n_c][cc];
        }
        float rg = sigmoid_f(sr), zg = sigmoid_f(sz);
        float ng = tanh_f(si + rg * sh);
        float hv = (1.f - zg) * ng + zg * phf[e];
        A.h1f[n_c * 1024 + col] = hv;
        A.h1[n_c * 1024 + col] = f2b(hv);
        hv2[e] = hv;
      }
      float sv = hv2[0] + hv2[1], sq = hv2[0] * hv2[0] + hv2[1] * hv2[1];
      sv += __shfl_xor(sv, 1); sq += __shfl_xor(sq, 1);
      sv += __shfl_xor(sv, 2); sq += __shfl_xor(sq, 2);
      sv += __shfl_xor(sv, 4); sq += __shfl_xor(sq, 4);
      if ((tid & 7) == 0){
        A.stats[(blk - 64) * 64 + n_c] = sv;
        A.stats[(blk - 64) * 64 + 32 + n_c] = sq;
      }
      gbar(A.bar, ++ep);
      // PC: gh1 on h1_t (for next step's PB), overlaps PE
      ar[0] = FZ; ar[1] = FZ; az[0] = FZ; az[1] = FZ; ani[0] = FZ; ani[1] = FZ; anh[0] = FZ; anh[1] = FZ;
      #pragma unroll
      for (int ch = 0; ch < 8; ++ch){
        short8 a0 = ld8(A.h1 + r * 1024 + kq + ch * 32 + g4 * 8);
        short8 a1 = ld8(A.h1 + (16 + r) * 1024 + kq + ch * 32 + g4 * 8);
        ar[0] = mfma16(a0, wh[ch], ar[0]);        ar[1] = mfma16(a1, wh[ch], ar[1]);
        az[0] = mfma16(a0, wh[8 + ch], az[0]);    az[1] = mfma16(a1, wh[8 + ch], az[1]);
        anh[0] = mfma16(a0, wh[16 + ch], anh[0]); anh[1] = mfma16(a1, wh[16 + ch], anh[1]);
      }
      gbar(A.bar, ++ep);
    }
  } else if (blk < 196){
    // ---------------- PE: pred / emb_{t+1} / Gx_{t+1} on h1 (LN folded) ----------------
    const int tile = (blk - 128) * 4 + q;     // 0..271
    int jt, c0;
    const u16* wsrc; const float *Sv, *Bv;
    if (tile < 16)      { jt = 0; c0 = tile * 16;        wsrc = A.wpg;  Sv = A.Sp; Bv = A.Bp; }
    else if (tile < 80) { jt = 1; c0 = (tile - 16) * 16; wsrc = A.Wdpg; Sv = A.S1; Bv = A.B1; }
    else                { jt = 2; c0 = (tile - 80) * 16; wsrc = A.Wgpg; Sv = A.S2; Bv = A.B2; }
    short8 w[32];
    #pragma unroll
    for (int ch = 0; ch < 32; ++ch)
      w[ch] = ld8(wsrc + (size_t)(c0 + r) * 1024 + ch * 32 + g4 * 8);
    const float Sc = Sv[c0 + r], Bc = Bv[c0 + r];
    const int col = c0 + r;
    int ep = 1; gbar(A.bar, ep);
    #pragma unroll 1
    for (int t = 0; t < DEC_STEPS; ++t){
      gbar(A.bar, ++ep);   // PA idle
      gbar(A.bar, ++ep);   // PB idle
      // PC
      float sacc = 0.f;
      #pragma unroll
      for (int b2 = 0; b2 < 64; ++b2) sacc += A.stats[b2 * 64 + lane];
      float muA[2][4], rsA[2][4];
      #pragma unroll
      for (int m = 0; m < 2; ++m)
        #pragma unroll
        for (int j = 0; j < 4; ++j){
          int n = m * 16 + g4 * 4 + j;
          float sv = __shfl(sacc, n), sq = __shfl(sacc, 32 + n);
          float mu = sv * (1.f / 1024.f);
          muA[m][j] = mu;
          rsA[m][j] = rsqrtf(sq * (1.f / 1024.f) - mu * mu + 1e-5f);
        }
      f32x4 a0 = FZ, a1 = FZ;
      #pragma unroll
      for (int ch = 0; ch < 32; ++ch){
        short8 x0 = ld8(A.h1 + r * 1024 + ch * 32 + g4 * 8);
        short8 x1 = ld8(A.h1 + (16 + r) * 1024 + ch * 32 + g4 * 8);
        a0 = mfma16(x0, w[ch], a0);
        a1 = mfma16(x1, w[ch], a1);
      }
      #pragma unroll
      for (int m = 0; m < 2; ++m)
        #pragma unroll
        for (int j = 0; j < 4; ++j){
          int n = m * 16 + g4 * 4 + j;
          float acc = (m ? a1[j] : a0[j]);
          float v = rsA[m][j] * (acc - muA[m][j] * Sc) + Bc;
          if (jt == 0){
            A.out[(size_t)n * (256 * 540) + (size_t)col * 540 + t] = v;
          } else if (jt == 1){
            float pre = v + A.Xal[n * 1024 + col];
            A.emb[n * 1024 + col] = f2b(gelu_f(pre));
          } else {
            A.Gx[n * 3072 + col] = v + A.Gal[n * 3072 + col];
          }
        }
      gbar(A.bar, ++ep);
    }
  } else {
    // ---------------- AL: audio/lxm partials for step t+1 ----------------
    const int wg = (blk - 196) * 4 + q;       // 0..63
    const int at0 = wg * 4;
    short8 w[48];
    float vb[4];
    #pragma unroll
    for (int j = 0; j < 4; ++j){
      int at = at0 + j;
      if (at < 64){
        #pragma unroll
        for (int ch = 0; ch < 12; ++ch)
          w[j * 12 + ch] = ld8(A.wd + (size_t)(at * 16 + r) * 640 + 256 + ch * 32 + g4 * 8);
        vb[j] = A.vX[at * 16 + r];
      } else {
        #pragma unroll
        for (int ch = 0; ch < 12; ++ch)
          w[j * 12 + ch] = ld8(A.wih0 + (size_t)((at - 64) * 16 + r) * 1664 + 1280 + ch * 32 + g4 * 8);
        vb[j] = A.vG[(at - 64) * 16 + r];
      }
    }
    int ep = 1; gbar(A.bar, ep);
    #pragma unroll 1
    for (int t = 0; t < DEC_STEPS; ++t){
      gbar(A.bar, ++ep);   // PA idle
      // PB
      int tn = t + 1; if (tn > 539) tn = 539;
      int bn = tn / 30;
      short8 af0[12], af1[12];
      #pragma unroll
      for (int ch = 0; ch < 12; ++ch){
        int kk = ch * 32 + g4 * 8;
        if (ch < 8){
          af0[ch] = ld8(A.aud_seq + ((size_t)tn * 32 + r) * 256 + kk);
          af1[ch] = ld8(A.aud_seq + ((size_t)tn * 32 + 16 + r) * 256 + kk);
        } else {
          af0[ch] = ld8(A.lxm_b + ((size_t)bn * 32 + r) * 128 + kk - 256);
          af1[ch] = ld8(A.lxm_b + ((size_t)bn * 32 + 16 + r) * 128 + kk - 256);
        }
      }
      #pragma unroll
      for (int j = 0; j < 4; ++j){
        f32x4 c0a = FZ, c1a = FZ;
        #pragma unroll
        for (int ch = 0; ch < 12; ++ch){
          c0a = mfma16(af0[ch], w[j * 12 + ch], c0a);
          c1a = mfma16(af1[ch], w[j * 12 + ch], c1a);
        }
        int at = at0 + j;
        #pragma unroll
        for (int m = 0; m < 2; ++m)
          #pragma unroll
          for (int jj = 0; jj < 4; ++jj){
            int n = m * 16 + g4 * 4 + jj;
            float v = (m ? c1a[jj] : c0a[jj]) + vb[j];
            if (at < 64) A.Xal[n * 1024 + at * 16 + r] = v;
            else         A.Gal[n * 3072 + (at - 64) * 16 + r] = v;
          }
      }
      gbar(A.bar, ++ep);   // end PB
      gbar(A.bar, ++ep);   // PC idle
    }
  }
}

// ---------------------------------------------------------------------------

extern "C" void kernel_launch(void* const* d_in, const int* in_sizes, int n_in,
                              void* d_out, int out_size, void* d_ws, size_t ws_size,
                              hipStream_t stream) {
  enum { I_AUD=0, I_MO=1, I_LXM=2, I_AEW0=3, I_AEB0=4, I_AEW1=5, I_AEB1=6, I_AEW2=7, I_AEB2=8,
         I_AEW3=9, I_AEB3=10, I_AELNG=11, I_AELNB=12, I_CIW0=13, I_CIB0=14, I_CIW1=15, I_CIB1=16,
         I_CIW2=17, I_CIB2=18, I_DECW=19, I_DECB=20, I_WIH0=21, I_WHH0=22, I_BIH0=23, I_BHH0=24,
         I_WIH1=25, I_WHH1=26, I_BIH1=27, I_BHH1=28, I_LNG=29, I_LNB=30, I_PREDW=31, I_PREDB=32 };

  char* base = (char*)d_ws;
  size_t off = 0;
  auto alloc = [&](size_t bytes)->void*{
    void* p = base + off;
    off += (bytes + 255) & ~(size_t)255;
    return p;
  };

  // bf16 weight blobs
  u16* wd_b   = (u16*)alloc((size_t)1024*640*2);
  u16* wih0_b = (u16*)alloc((size_t)3072*1664*2);
  u16* whh0_b = (u16*)alloc((size_t)3072*1024*2);
  u16* wih1_b = (u16*)alloc((size_t)3072*1024*2);
  u16* whh1_b = (u16*)alloc((size_t)3072*1024*2);
  u16* wc0    = (u16*)alloc((size_t)1024*384*2);
  u16* wc1    = (u16*)alloc((size_t)1024*1024*2);
  u16* wc2    = (u16*)alloc((size_t)2048*1024*2);
  u16* w0k    = (u16*)alloc((size_t)256*896*2);
  u16* w1k    = (u16*)alloc((size_t)256*1280*2);
  u16* w2k    = (u16*)alloc((size_t)256*1024*2);
  u16* w3k    = (u16*)alloc((size_t)256*256*2);
  u16* wpT    = (u16*)alloc((size_t)1024*256*2);
  u16* wpg    = (u16*)alloc((size_t)256*1024*2);
  u16* Wdpg   = (u16*)alloc((size_t)1024*1024*2);
  u16* Wgpg   = (u16*)alloc((size_t)3072*1024*2);
  float* Sp = (float*)alloc(256*4);   float* Bp = (float*)alloc(256*4);
  float* S1 = (float*)alloc(1024*4);  float* B1 = (float*)alloc(1024*4);
  float* S2 = (float*)alloc(3072*4);  float* B2 = (float*)alloc(3072*4);
  float* vX = (float*)alloc(1024*4);  float* vG = (float*)alloc(3072*4);
  // sequences / state
  u16* aud_seq = (u16*)alloc((size_t)540*32*256*2);
  u16* lxm_b   = (u16*)alloc((size_t)18*32*128*2);
  u16* xc      = (u16*)alloc((size_t)32*384*2);
  u16* xc0     = (u16*)alloc((size_t)32*640*2);
  u16* ci1     = (u16*)alloc((size_t)32*1024*2);
  u16* ci2     = (u16*)alloc((size_t)32*1024*2);
  float* hraw  = (float*)alloc((size_t)32*2048*4);
  u16* h0      = (u16*)alloc((size_t)32*1024*2);
  u16* h1      = (u16*)alloc((size_t)32*1024*2);
  float* h0f   = (float*)alloc((size_t)32*1024*4);
  float* h1f   = (float*)alloc((size_t)32*1024*4);
  u16* emb     = (u16*)alloc((size_t)32*1024*2);
  u16* pre_mo  = (u16*)alloc((size_t)32*256*2);
  float* Gx    = (float*)alloc((size_t)32*3072*4);
  float* Xal   = (float*)alloc((size_t)32*1024*4);
  float* Gal   = (float*)alloc((size_t)32*3072*4);
  float* stats = (float*)alloc((size_t)64*64*4);
  int* bar     = (int*)alloc(16384);
  // encoder transients
  u16* O0   = (u16*)alloc((size_t)48384*256*2);
  u16* O1   = (u16*)alloc((size_t)46080*256*2);
  u16* O2   = (u16*)alloc((size_t)23040*256*2);
  float* O3 = (float*)alloc((size_t)23040*256*4);
  u16* Abuf = (u16*)alloc((size_t)23040*1280*2);
  // composition temps alias Abuf (free after conv GEMMs)
  float* Wdp_f = (float*)Abuf;                                  // 4 MB
  float* Wgp_f = (float*)((char*)Abuf + (size_t)1024*1024*4 + 256);  // 12.6 MB
  (void)ws_size; (void)in_sizes; (void)n_in; (void)out_size;

  const float* aud = (const float*)d_in[I_AUD];
  const float* mo  = (const float*)d_in[I_MO];
  const float* lxm = (const float*)d_in[I_LXM];
  float* out = (float*)d_out;

  auto cdiv = [](long long a, long long b)->int{ return (int)((a + b - 1) / b); };
  auto cvt = [&](int idx, u16* dst, int n){
    f2b_k<<<cdiv(n,256), 256, 0, stream>>>((const float*)d_in[idx], dst, n);
  };

  // ---- weight conversion ----
  cvt(I_DECW, wd_b,   1024*640);
  cvt(I_WIH0, wih0_b, 3072*1664);
  cvt(I_WHH0, whh0_b, 3072*1024);
  cvt(I_WIH1, wih1_b, 3072*1024);
  cvt(I_WHH1, whh1_b, 3072*1024);
  cvt(I_CIW0, wc0,    1024*384);
  cvt(I_CIW1, wc1,    1024*1024);
  cvt(I_CIW2, wc2,    2048*1024);
  cvt(I_AEW0, w0k,    256*896);
  cvt(I_AEW1, w1k,    256*1280);
  cvt(I_AEW2, w2k,    256*1024);
  cvt(I_AEW3, w3k,    256*256);

  // ---- encoder ----
  for (int c = 0; c < 2; ++c){
    int row0 = c * 24192;
    long long tot = (long long)24192 * 896;
    im2col0_k<<<cdiv(tot,256), 256, 0, stream>>>(aud, Abuf, row0, tot);
    gemm_bt<<<dim3(24192/64, 4), 256, 0, stream>>>(Abuf, 896, w0k, 896, (const float*)d_in[I_AEB0],
        O0 + (size_t)row0*256, 24192, 256, 896, GELU_FLG|BF16_FLG);
  }
  for (int c = 0; c < 2; ++c){
    int row0 = c * 23040;
    long long tot = (long long)23040 * 1280;
    im2col1_k<<<cdiv(tot,256), 256, 0, stream>>>(O0, Abuf, row0, tot);
    gemm_bt<<<dim3(23040/64, 4), 256, 0, stream>>>(Abuf, 1280, w1k, 1280, (const float*)d_in[I_AEB1],
        O1 + (size_t)row0*256, 23040, 256, 1280, GELU_FLG|BF16_FLG);
  }
  {
    long long tot = (long long)23040 * 1024;
    im2col2_k<<<cdiv(tot,256), 256, 0, stream>>>(O1, Abuf, 0, tot);
    gemm_bt<<<dim3(23040/64, 4), 256, 0, stream>>>(Abuf, 1024, w2k, 1024, (const float*)d_in[I_AEB2],
        O2, 23040, 256, 1024, GELU_FLG|BF16_FLG);
  }
  gemm_bt<<<dim3(23040/64, 4), 256, 0, stream>>>(O2, 256, w3k, 256, (const float*)d_in[I_AEB3],
      O3, 23040, 256, 256, GELU_FLG);
  enc_ln_k<<<4320, 256, 0, stream>>>(O3, (const float*)d_in[I_AELNG], (const float*)d_in[I_AELNB], aud_seq);

  // ---- lxm + cell-init chain ----
  lxm_g_k<<<cdiv(18*32*128,256), 256, 0, stream>>>(lxm, lxm_b);
  gather_xc_k<<<cdiv(32*384,256), 256, 0, stream>>>(mo, lxm, xc, pre_mo);
  gemm_bt<<<dim3(1,16), 256, 0, stream>>>(xc, 384, wc0, 384, (const float*)d_in[I_CIB0],
      ci1, 32, 1024, 384, GELU_FLG|BF16_FLG);
  gemm_bt<<<dim3(1,16), 256, 0, stream>>>(ci1, 1024, wc1, 1024, (const float*)d_in[I_CIB1],
      ci2, 32, 1024, 1024, GELU_FLG|BF16_FLG);
  gemm_bt<<<dim3(1,32), 256, 0, stream>>>(ci2, 1024, wc2, 1024, (const float*)d_in[I_CIB2],
      hraw, 32, 2048, 1024, 0);
  split_h_k<<<cdiv(32*1024,256), 256, 0, stream>>>(hraw, h0, h1, h0f, h1f);

  // ---- composition precompute ----
  t_wpT_k<<<cdiv(1024*256,256), 256, 0, stream>>>((const float*)d_in[I_PREDW], wpT);
  // Wdp = Wd_p @ Wp  (wd cols 0..255), Wgp = Wih0_p @ Wp (wih0 cols 1024..1279)
  gemm_bt<<<dim3(16,16), 256, 0, stream>>>(wd_b, 640, wpT, 256, nullptr, Wdp_f, 1024, 1024, 256, 0);
  gemm_bt<<<dim3(48,16), 256, 0, stream>>>(wih0_b + 1024, 1664, wpT, 256, nullptr, Wgp_f, 3072, 1024, 256, 0);
  foldW_k<<<cdiv(1024,4), 256, 0, stream>>>(Wdp_f, (const float*)d_in[I_LNG], (const float*)d_in[I_LNB],
      nullptr, Wdpg, S1, B1, 1024);
  foldW_k<<<cdiv(3072,4), 256, 0, stream>>>(Wgp_f, (const float*)d_in[I_LNG], (const float*)d_in[I_LNB],
      nullptr, Wgpg, S2, B2, 3072);
  foldW_k<<<cdiv(256,4), 256, 0, stream>>>((const float*)d_in[I_PREDW], (const float*)d_in[I_LNG],
      (const float*)d_in[I_LNB], (const float*)d_in[I_PREDB], wpg, Sp, Bp, 256);
  // vX = db + Wd_p @ pb ; vG = Wih0_p @ pb
  vfold_k<<<cdiv(1024,4), 256, 0, stream>>>((const float*)d_in[I_DECW], 640, 0,
      (const float*)d_in[I_PREDB], (const float*)d_in[I_DECB], vX, 1024);
  vfold_k<<<cdiv(3072,4), 256, 0, stream>>>((const float*)d_in[I_WIH0], 1664, 1024,
      (const float*)d_in[I_PREDB], nullptr, vG, 3072);

  // ---- t=0 boot values: emb_0 and Gx_0 from the real xcat_0 ----
  build_xc0_k<<<cdiv(32*640,256), 256, 0, stream>>>(pre_mo, aud_seq, lxm_b, xc0);
  gemm_bt<<<dim3(1,16), 256, 0, stream>>>(xc0, 640, wd_b, 640, (const float*)d_in[I_DECB],
      emb, 32, 1024, 640, GELU_FLG|BF16_FLG);
  gemm_bt<<<dim3(1,48), 256, 0, stream>>>(xc0, 640, wih0_b + 1024, 1664, nullptr,
      Gx, 32, 3072, 640, 0);

  hipMemsetAsync(bar, 0, 16384, stream);

  // ---- persistent decoder ----
  DecArgs da;
  da.aud_seq = aud_seq; da.lxm_b = lxm_b;
  da.wih0 = wih0_b; da.whh0 = whh0_b; da.wih1 = wih1_b; da.whh1 = whh1_b; da.wd = wd_b;
  da.wpg = wpg; da.Wdpg = Wdpg; da.Wgpg = Wgpg;
  da.Sp = Sp; da.Bp = Bp; da.S1 = S1; da.B1 = B1; da.S2 = S2; da.B2 = B2; da.vX = vX; da.vG = vG;
  da.bih0 = (const float*)d_in[I_BIH0]; da.bhh0 = (const float*)d_in[I_BHH0];
  da.bih1 = (const float*)d_in[I_BIH1]; da.bhh1 = (const float*)d_in[I_BHH1];
  da.emb = emb; da.h0 = h0; da.h1 = h1;
  da.h0f = h0f; da.h1f = h1f; da.Gx = Gx; da.Xal = Xal; da.Gal = Gal;
  da.stats = stats; da.out = out; da.bar = bar;
  decode_k<<<dim3(NBLK), dim3(256), 0, stream>>>(da);
}

// Round 5
// 26067.508 us; speedup vs baseline: 4.0275x; 1.0505x over previous
//
#include <hip/hip_runtime.h>

// ---------------------------------------------------------------------------
// MotionGenerator RNN for MI355X (gfx950).
//  - encoder: im2col + bf16 MFMA GEMM (weights are [out,in] == [N,K] B^T layout)
//  - decoder: weight-stationary persistent kernel, 212 blocks x 256 thr,
//    all decoder weights resident in VGPRs, 3 grid barriers per step.
//    NO threadfence: cross-block data uses agent-scope (sc0 sc1) coherent
//    loads/stores that bypass the non-coherent L1/L2; private data stays
//    cached. Barrier = vmcnt drain + slot store + parallel poll.
// ---------------------------------------------------------------------------

typedef unsigned short u16;
typedef __attribute__((ext_vector_type(8))) short short8;
typedef __attribute__((ext_vector_type(4))) float f32x4;

#define GELU_FLG 1
#define BF16_FLG 2
#define NBLK 212
#define DEC_STEPS 540

__device__ __forceinline__ u16 f2b(float f){
  union { float f; unsigned u; } c; c.f = f;
  return (u16)((c.u + 0x7fffu + ((c.u >> 16) & 1u)) >> 16);   // RNE
}
__device__ __forceinline__ short8 ld8(const u16* p){
  return *reinterpret_cast<const short8*>(p);
}
// coherent (agent-scope, L1/L2-bypass) accessors for cross-block data
__device__ __forceinline__ short8 ld8c(const u16* p){
  union { unsigned long long q[2]; short8 v; } u;
  u.q[0] = __hip_atomic_load((const unsigned long long*)p,     __ATOMIC_RELAXED, __HIP_MEMORY_SCOPE_AGENT);
  u.q[1] = __hip_atomic_load((const unsigned long long*)p + 1, __ATOMIC_RELAXED, __HIP_MEMORY_SCOPE_AGENT);
  return u.v;
}
__device__ __forceinline__ float ldfc(const float* p){
  return __hip_atomic_load(p, __ATOMIC_RELAXED, __HIP_MEMORY_SCOPE_AGENT);
}
__device__ __forceinline__ void stfc(float* p, float v){
  __hip_atomic_store(p, v, __ATOMIC_RELAXED, __HIP_MEMORY_SCOPE_AGENT);
}
__device__ __forceinline__ void stu32c(u16* p, unsigned v){
  __hip_atomic_store((unsigned*)p, v, __ATOMIC_RELAXED, __HIP_MEMORY_SCOPE_AGENT);
}
__device__ __forceinline__ void st16c(u16* p, unsigned v){
  asm volatile("global_store_short %0, %1, off sc0 sc1" :: "v"(p), "v"(v) : "memory");
}
__device__ __forceinline__ f32x4 mfma16(short8 a, short8 b, f32x4 c){
  return __builtin_amdgcn_mfma_f32_16x16x32_bf16(a, b, c, 0, 0, 0);
}
__device__ __forceinline__ float gelu_f(float x){
  return 0.5f * x * (1.f + erff(x * 0.70710678118654752f));   // exact gelu
}
__device__ __forceinline__ float sigmoid_f(float x){
  return 1.f / (1.f + __expf(-x));
}
__device__ __forceinline__ float tanh_f(float x){
  float e = __expf(-2.f * x);
  return (1.f - e) / (1.f + e);
}

// ---------------- elementwise / gather kernels ----------------

__global__ void f2b_k(const float* __restrict__ s, u16* __restrict__ d, int n){
  int i = blockIdx.x * 256 + threadIdx.x;
  if (i < n) d[i] = f2b(s[i]);
}

__global__ void gather_xc_k(const float* __restrict__ mo, const float* __restrict__ lxm,
                            u16* __restrict__ xc, u16* __restrict__ pre_mo){
  int i = blockIdx.x * 256 + threadIdx.x;
  if (i >= 32 * 384) return;
  int n = i / 384, c = i - n * 384;
  float v = (c < 256) ? mo[(size_t)(n * 256 + c) * 600 + 29]
                      : lxm[(size_t)(n * 128 + (c - 256)) * 20];
  u16 h = f2b(v);
  xc[i] = h;
  if (c < 256) pre_mo[n * 256 + c] = h;
}

__global__ void lxm_g_k(const float* __restrict__ lxm, u16* __restrict__ o){
  int i = blockIdx.x * 256 + threadIdx.x;
  if (i >= 18 * 32 * 128) return;
  int c = i & 127, rest = i >> 7;
  int n = rest & 31, b = rest >> 5;
  o[i] = f2b(lxm[(size_t)(n * 128 + c) * 20 + 1 + b]);
}

__global__ void split_h_k(const float* __restrict__ hraw, u16* __restrict__ h0, u16* __restrict__ h1,
                          float* __restrict__ h0f, float* __restrict__ h1f){
  int i = blockIdx.x * 256 + threadIdx.x;
  if (i >= 32 * 1024) return;
  int n = i >> 10, c = i & 1023;
  float a = hraw[(size_t)n * 2048 + c];
  float b = hraw[(size_t)n * 2048 + 1024 + c];
  h0[i] = f2b(a); h1[i] = f2b(b);
  h0f[i] = a;     h1f[i] = b;
}

__global__ void build_xc0_k(const u16* __restrict__ pre_mo, const u16* __restrict__ aud_seq,
                            const u16* __restrict__ lxm_b, u16* __restrict__ xc0){
  int i = blockIdx.x * 256 + threadIdx.x;
  if (i >= 32 * 640) return;
  int n = i / 640, c = i - n * 640;
  u16 v;
  if (c < 256) v = pre_mo[n * 256 + c];
  else if (c < 512) v = aud_seq[n * 256 + (c - 256)];
  else v = lxm_b[n * 128 + (c - 512)];
  xc0[i] = v;
}

__global__ void t_wpT_k(const float* __restrict__ wp, u16* __restrict__ wpT){
  int i = blockIdx.x * 256 + threadIdx.x;
  if (i >= 1024 * 256) return;
  int h = i >> 8, j = i & 255;
  wpT[i] = f2b(wp[(size_t)j * 1024 + h]);
}

// fold LN gain/bias into a [R x 1024] matrix that acts on LN(h1):
// Wg = W * g (bf16), S[r] = sum_h W[r,h]*g[h], B[r] = sum_h W[r,h]*b[h] (+addb)
__global__ void foldW_k(const float* __restrict__ src, const float* __restrict__ g,
                        const float* __restrict__ b, const float* __restrict__ addb,
                        u16* __restrict__ Wg, float* __restrict__ S, float* __restrict__ B, int R){
  int row = blockIdx.x * 4 + (threadIdx.x >> 6);
  if (row >= R) return;
  int lane = threadIdx.x & 63;
  const float* sr = src + (size_t)row * 1024;
  float s = 0.f, bb = 0.f;
  #pragma unroll
  for (int k = 0; k < 16; ++k){
    int c = lane + k * 64;
    float w = sr[c], gw = w * g[c];
    Wg[(size_t)row * 1024 + c] = f2b(gw);
    s += gw; bb += w * b[c];
  }
  #pragma unroll
  for (int m = 1; m < 64; m <<= 1){ s += __shfl_xor(s, m); bb += __shfl_xor(bb, m); }
  if (lane == 0){ S[row] = s; B[row] = bb + (addb ? addb[row] : 0.f); }
}

// v[row] = base[row] + sum_{j<256} W[row*ldw + off + j] * pb[j]
__global__ void vfold_k(const float* __restrict__ W, int ldw, int off, const float* __restrict__ pb,
                        const float* __restrict__ base, float* __restrict__ v, int R){
  int row = blockIdx.x * 4 + (threadIdx.x >> 6);
  if (row >= R) return;
  int lane = threadIdx.x & 63;
  const float* wr = W + (size_t)row * ldw + off;
  float s = 0.f;
  #pragma unroll
  for (int k = 0; k < 4; ++k){ int j = lane + k * 64; s += wr[j] * pb[j]; }
  #pragma unroll
  for (int m = 1; m < 64; m <<= 1) s += __shfl_xor(s, m);
  if (lane == 0) v[row] = s + (base ? base[row] : 0.f);
}

// ---------------- im2col kernels ----------------

__global__ void im2col0_k(const float* __restrict__ aud, u16* __restrict__ A, int row0, long long tot){
  long long i = (long long)blockIdx.x * 256 + threadIdx.x;
  if (i >= tot) return;
  int k = (int)(i % 896);
  int row = row0 + (int)(i / 896);
  int ci = k / 7, kk = k - ci * 7;
  int p = row % 84, bn = row / 84;
  int b = bn >> 5, n = bn & 31;
  A[i] = f2b(aud[(size_t)(n * 128 + ci) * 600 + b * 30 + p + kk]);
}

__global__ void im2col1_k(const u16* __restrict__ O0, u16* __restrict__ A, int row0, long long tot){
  long long i = (long long)blockIdx.x * 256 + threadIdx.x;
  if (i >= tot) return;
  int k = (int)(i % 1280);
  int row = row0 + (int)(i / 1280);
  int ci = k / 5, kk = k - ci * 5;
  int p = row % 80, bn = row / 80;
  A[i] = O0[(size_t)(bn * 84 + p + kk) * 256 + ci];
}

__global__ void im2col2_k(const u16* __restrict__ O1, u16* __restrict__ A, int row0, long long tot){
  long long i = (long long)blockIdx.x * 256 + threadIdx.x;
  if (i >= tot) return;
  int k = (int)(i & 1023);
  int row = row0 + (int)(i >> 10);
  int ci = k >> 2, kk = k & 3;
  int p = row % 40, bn = row / 40;
  int pos = 2 * p - 1 + kk;                      // stride 2, pad 1
  A[i] = (pos >= 0 && pos < 80) ? O1[(size_t)(bn * 80 + pos) * 256 + ci] : (u16)0;
}

// ---------------- GEMM: C[M,N] = A[M,K] @ W[N,K]^T  (bf16 MFMA) ----------------

__global__ void gemm_bt(const u16* __restrict__ A, int lda,
                        const u16* __restrict__ W, int ldw, const float* __restrict__ bias,
                        void* __restrict__ outp, int M, int N, int K, int flags){
  const int lane = threadIdx.x & 63, widx = threadIdx.x >> 6;
  const int m0 = blockIdx.x * 64 + widx * 16;
  if (m0 >= M) return;
  const int n0 = blockIdx.y * 64;
  const int r = lane & 15, g4 = lane >> 4;
  const u16* arow = A + (size_t)(m0 + r) * lda + g4 * 8;
  const u16* wrow = W + (size_t)(n0 + r) * ldw + g4 * 8;
  f32x4 acc[4];
  const f32x4 FZ = {0.f, 0.f, 0.f, 0.f};
  acc[0] = FZ; acc[1] = FZ; acc[2] = FZ; acc[3] = FZ;
  for (int k = 0; k < K; k += 32){
    short8 a = ld8(arow + k);
    #pragma unroll
    for (int j = 0; j < 4; ++j)
      acc[j] = mfma16(a, ld8(wrow + (size_t)j * 16 * ldw + k), acc[j]);
  }
  #pragma unroll
  for (int j = 0; j < 4; ++j){
    int col = n0 + j * 16 + r;
    float bv = bias ? bias[col] : 0.f;
    #pragma unroll
    for (int q = 0; q < 4; ++q){
      int row = m0 + g4 * 4 + q;
      float v = acc[j][q] + bv;
      if (flags & GELU_FLG) v = gelu_f(v);
      if (flags & BF16_FLG) ((u16*)outp)[(size_t)row * N + col] = f2b(v);
      else                  ((float*)outp)[(size_t)row * N + col] = v;
    }
  }
}

// ---------------- encoder LayerNorm -> aud_seq (bf16) ----------------

__global__ void enc_ln_k(const float* __restrict__ O3, const float* __restrict__ g,
                         const float* __restrict__ bb, u16* __restrict__ aud_seq){
  int rid = blockIdx.x * 4 + (threadIdx.x >> 6);
  int lane = threadIdx.x & 63;
  int b = rid / 960, rem = rid - b * 960;
  int p2 = rem >> 5, n = rem & 31;
  int orow = (b * 32 + n) * 40 + p2;
  const float4 v = *reinterpret_cast<const float4*>(O3 + (size_t)orow * 256 + lane * 4);
  float s  = v.x + v.y + v.z + v.w;
  float s2 = v.x * v.x + v.y * v.y + v.z * v.z + v.w * v.w;
  #pragma unroll
  for (int m = 1; m < 64; m <<= 1){ s += __shfl_xor(s, m); s2 += __shfl_xor(s2, m); }
  float mu = s * (1.f / 256.f);
  float var = s2 * (1.f / 256.f) - mu * mu;
  float rs = rsqrtf(var + 1e-5f);
  int c = lane * 4;
  u16* dst = aud_seq + (size_t)rid * 256 + c;
  dst[0] = f2b((v.x - mu) * rs * g[c + 0] + bb[c + 0]);
  dst[1] = f2b((v.y - mu) * rs * g[c + 1] + bb[c + 1]);
  dst[2] = f2b((v.z - mu) * rs * g[c + 2] + bb[c + 2]);
  dst[3] = f2b((v.w - mu) * rs * g[c + 3] + bb[c + 3]);
}

// ---------------- persistent weight-stationary decoder ----------------

struct DecArgs {
  const u16 *aud_seq, *lxm_b;
  const u16 *wih0, *whh0, *wih1, *whh1, *wd;       // bf16 blobs
  const u16 *wpg, *Wdpg, *Wgpg;                    // LN-folded PE weights
  const float *Sp, *Bp, *S1, *B1, *S2, *B2, *vX, *vG;
  const float *bih0, *bhh0, *bih1, *bhh1;
  u16 *emb, *h0, *h1;
  float *h0f, *h1f, *Gx, *Xal, *Gal, *stats, *out;
  int *bar;
};

// grid barrier, fence-free: drain own vmem (coherent stores are write-through,
// so vmcnt(0) == globally visible), store own slot, poll all slots in parallel.
__device__ __forceinline__ void gbar(int* bar, int ep){
  asm volatile("s_waitcnt vmcnt(0)" ::: "memory");
  __syncthreads();
  if (threadIdx.x == 0)
    __hip_atomic_store(bar + blockIdx.x * 16, ep, __ATOMIC_RELAXED, __HIP_MEMORY_SCOPE_AGENT);
  if (threadIdx.x < NBLK){
    while (__hip_atomic_load(bar + threadIdx.x * 16, __ATOMIC_RELAXED, __HIP_MEMORY_SCOPE_AGENT) < ep)
      __builtin_amdgcn_s_sleep(1);
  }
  __syncthreads();
}

__global__ __launch_bounds__(256, 1) void decode_k(DecArgs A){
  const int tid = threadIdx.x;
  const int lane = tid & 63, q = tid >> 6;
  const int r = lane & 15, g4 = lane >> 4;
  const int blk = blockIdx.x;
  __shared__ float lds[4][4][32][16];
  const f32x4 FZ = {0.f, 0.f, 0.f, 0.f};

  if (blk < 64){
    // ---------------- L0: h0 producer (wih0_e + whh0 resident) ----------------
    const int c0 = blk * 16;
    const int kq = q * 256;
    short8 we[24], wh[24];
    #pragma unroll
    for (int g = 0; g < 3; ++g)
      #pragma unroll
      for (int ch = 0; ch < 8; ++ch){
        we[g * 8 + ch] = ld8(A.wih0 + (size_t)(g * 1024 + c0 + r) * 1664 + kq + ch * 32 + g4 * 8);
        wh[g * 8 + ch] = ld8(A.whh0 + (size_t)(g * 1024 + c0 + r) * 1024 + kq + ch * 32 + g4 * 8);
      }
    const int n_c = tid >> 3;
    const int cc0 = (tid & 7) * 2;
    const int colA = c0 + cc0, colB = colA + 1;
    const float bi_r[2] = {A.bih0[colA], A.bih0[colB]};
    const float bi_z[2] = {A.bih0[1024 + colA], A.bih0[1024 + colB]};
    const float bi_n[2] = {A.bih0[2048 + colA], A.bih0[2048 + colB]};
    const float bh_r[2] = {A.bhh0[colA], A.bhh0[colB]};
    const float bh_z[2] = {A.bhh0[1024 + colA], A.bhh0[1024 + colB]};
    const float bh_n[2] = {A.bhh0[2048 + colA], A.bhh0[2048 + colB]};
    f32x4 ar[2], az[2], ani[2], anh[2];
    // P0: gh0 on initial h0
    ar[0] = FZ; ar[1] = FZ; az[0] = FZ; az[1] = FZ; ani[0] = FZ; ani[1] = FZ; anh[0] = FZ; anh[1] = FZ;
    #pragma unroll
    for (int ch = 0; ch < 8; ++ch){
      short8 a0 = ld8c(A.h0 + r * 1024 + kq + ch * 32 + g4 * 8);
      short8 a1 = ld8c(A.h0 + (16 + r) * 1024 + kq + ch * 32 + g4 * 8);
      ar[0] = mfma16(a0, wh[ch], ar[0]);        ar[1] = mfma16(a1, wh[ch], ar[1]);
      az[0] = mfma16(a0, wh[8 + ch], az[0]);    az[1] = mfma16(a1, wh[8 + ch], az[1]);
      anh[0] = mfma16(a0, wh[16 + ch], anh[0]); anh[1] = mfma16(a1, wh[16 + ch], anh[1]);
    }
    int ep = 1; gbar(A.bar, ep);
    #pragma unroll 1
    for (int t = 0; t < DEC_STEPS; ++t){
      // PA: prefetch Gx (coherent) + h0f (private), gi0e on emb, combine
      float pgr[2], pgz[2], pgn[2], phf[2];
      #pragma unroll
      for (int e = 0; e < 2; ++e){
        int col = c0 + cc0 + e;
        pgr[e] = ldfc(A.Gx + n_c * 3072 + col);
        pgz[e] = ldfc(A.Gx + n_c * 3072 + 1024 + col);
        pgn[e] = ldfc(A.Gx + n_c * 3072 + 2048 + col);
        phf[e] = A.h0f[n_c * 1024 + col];
      }
      #pragma unroll
      for (int ch = 0; ch < 8; ++ch){
        short8 a0 = ld8c(A.emb + r * 1024 + kq + ch * 32 + g4 * 8);
        short8 a1 = ld8c(A.emb + (16 + r) * 1024 + kq + ch * 32 + g4 * 8);
        ar[0] = mfma16(a0, we[ch], ar[0]);        ar[1] = mfma16(a1, we[ch], ar[1]);
        az[0] = mfma16(a0, we[8 + ch], az[0]);    az[1] = mfma16(a1, we[8 + ch], az[1]);
        ani[0] = mfma16(a0, we[16 + ch], ani[0]); ani[1] = mfma16(a1, we[16 + ch], ani[1]);
      }
      #pragma unroll
      for (int m = 0; m < 2; ++m)
        #pragma unroll
        for (int j = 0; j < 4; ++j){
          int row = m * 16 + g4 * 4 + j;
          lds[q][0][row][r] = ar[m][j];
          lds[q][1][row][r] = az[m][j];
          lds[q][2][row][r] = ani[m][j];
          lds[q][3][row][r] = anh[m][j];
        }
      __syncthreads();
      float hv2[2];
      #pragma unroll
      for (int e = 0; e < 2; ++e){
        int cc = cc0 + e, col = c0 + cc;
        float sr = bi_r[e] + bh_r[e] + pgr[e];
        float sz = bi_z[e] + bh_z[e] + pgz[e];
        float si = bi_n[e] + pgn[e];
        float sh = bh_n[e];
        #pragma unroll
        for (int qq = 0; qq < 4; ++qq){
          sr += lds[qq][0][n_c][cc]; sz += lds[qq][1][n_c][cc];
          si += lds[qq][2][n_c][cc]; sh += lds[qq][3][n_c][cc];
        }
        float rg = sigmoid_f(sr), zg = sigmoid_f(sz);
        float ng = tanh_f(si + rg * sh);
        float hv = (1.f - zg) * ng + zg * phf[e];
        A.h0f[n_c * 1024 + col] = hv;            // private, cached
        hv2[e] = hv;
      }
      stu32c(A.h0 + n_c * 1024 + colA,
             (unsigned)f2b(hv2[0]) | ((unsigned)f2b(hv2[1]) << 16));
      gbar(A.bar, ++ep);
      // PB: fresh gh0-next on h0_t
      ar[0] = FZ; ar[1] = FZ; az[0] = FZ; az[1] = FZ; ani[0] = FZ; ani[1] = FZ; anh[0] = FZ; anh[1] = FZ;
      #pragma unroll
      for (int ch = 0; ch < 8; ++ch){
        short8 a0 = ld8c(A.h0 + r * 1024 + kq + ch * 32 + g4 * 8);
        short8 a1 = ld8c(A.h0 + (16 + r) * 1024 + kq + ch * 32 + g4 * 8);
        ar[0] = mfma16(a0, wh[ch], ar[0]);        ar[1] = mfma16(a1, wh[ch], ar[1]);
        az[0] = mfma16(a0, wh[8 + ch], az[0]);    az[1] = mfma16(a1, wh[8 + ch], az[1]);
        anh[0] = mfma16(a0, wh[16 + ch], anh[0]); anh[1] = mfma16(a1, wh[16 + ch], anh[1]);
      }
      gbar(A.bar, ++ep);
      // PC: idle
      gbar(A.bar, ++ep);
    }
  } else if (blk < 128){
    // ---------------- L1: h1 producer (wih1 + whh1 resident) ----------------
    const int c0 = (blk - 64) * 16;
    const int kq = q * 256;
    short8 wi[24], wh[24];
    #pragma unroll
    for (int g = 0; g < 3; ++g)
      #pragma unroll
      for (int ch = 0; ch < 8; ++ch){
        wi[g * 8 + ch] = ld8(A.wih1 + (size_t)(g * 1024 + c0 + r) * 1024 + kq + ch * 32 + g4 * 8);
        wh[g * 8 + ch] = ld8(A.whh1 + (size_t)(g * 1024 + c0 + r) * 1024 + kq + ch * 32 + g4 * 8);
      }
    const int n_c = tid >> 3;
    const int cc0 = (tid & 7) * 2;
    const int colA = c0 + cc0, colB = colA + 1;
    const float bi_r[2] = {A.bih1[colA], A.bih1[colB]};
    const float bi_z[2] = {A.bih1[1024 + colA], A.bih1[1024 + colB]};
    const float bi_n[2] = {A.bih1[2048 + colA], A.bih1[2048 + colB]};
    const float bh_r[2] = {A.bhh1[colA], A.bhh1[colB]};
    const float bh_z[2] = {A.bhh1[1024 + colA], A.bhh1[1024 + colB]};
    const float bh_n[2] = {A.bhh1[2048 + colA], A.bhh1[2048 + colB]};
    f32x4 ar[2], az[2], ani[2], anh[2];
    // pre-loop: gh1 on initial h1
    ar[0] = FZ; ar[1] = FZ; az[0] = FZ; az[1] = FZ; ani[0] = FZ; ani[1] = FZ; anh[0] = FZ; anh[1] = FZ;
    #pragma unroll
    for (int ch = 0; ch < 8; ++ch){
      short8 a0 = ld8c(A.h1 + r * 1024 + kq + ch * 32 + g4 * 8);
      short8 a1 = ld8c(A.h1 + (16 + r) * 1024 + kq + ch * 32 + g4 * 8);
      ar[0] = mfma16(a0, wh[ch], ar[0]);        ar[1] = mfma16(a1, wh[ch], ar[1]);
      az[0] = mfma16(a0, wh[8 + ch], az[0]);    az[1] = mfma16(a1, wh[8 + ch], az[1]);
      anh[0] = mfma16(a0, wh[16 + ch], anh[0]); anh[1] = mfma16(a1, wh[16 + ch], anh[1]);
    }
    int ep = 1; gbar(A.bar, ep);
    #pragma unroll 1
    for (int t = 0; t < DEC_STEPS; ++t){
      // PA: idle (gh1 already computed in previous PC / pre-loop)
      gbar(A.bar, ++ep);
      // PB: gi1 on h0_t, combine -> h1 + LN stats
      float phf[2];
      phf[0] = A.h1f[n_c * 1024 + colA];
      phf[1] = A.h1f[n_c * 1024 + colB];
      #pragma unroll
      for (int ch = 0; ch < 8; ++ch){
        short8 a0 = ld8c(A.h0 + r * 1024 + kq + ch * 32 + g4 * 8);
        short8 a1 = ld8c(A.h0 + (16 + r) * 1024 + kq + ch * 32 + g4 * 8);
        ar[0] = mfma16(a0, wi[ch], ar[0]);        ar[1] = mfma16(a1, wi[ch], ar[1]);
        az[0] = mfma16(a0, wi[8 + ch], az[0]);    az[1] = mfma16(a1, wi[8 + ch], az[1]);
        ani[0] = mfma16(a0, wi[16 + ch], ani[0]); ani[1] = mfma16(a1, wi[16 + ch], ani[1]);
      }
      #pragma unroll
      for (int m = 0; m < 2; ++m)
        #pragma unroll
        for (int j = 0; j < 4; ++j){
          int row = m * 16 + g4 * 4 + j;
          lds[q][0][row][r] = ar[m][j];
          lds[q][1][row][r] = az[m][j];
          lds[q][2][row][r] = ani[m][j];
          lds[q][3][row][r] = anh[m][j];
        }
      __syncthreads();
      float hv2[2];
      #pragma unroll
      for (int e = 0; e < 2; ++e){
        int cc = cc0 + e, col = c0 + cc;
        float sr = bi_r[e] + bh_r[e];
        float sz = bi_z[e] + bh_z[e];
        float si = bi_n[e];
        float sh = bh_n[e];
        #pragma unroll
        for (int qq = 0; qq < 4; ++qq){
          sr += lds[qq][0][n_c][cc]; sz += lds[qq][1][n_c][cc];
          si += lds[qq][2][n_c][cc]; sh += lds[qq][3][n_c][cc];
        }
        float rg = sigmoid_f(sr), zg = sigmoid_f(sz);
        float ng = tanh_f(si + rg * sh);
        float hv = (1.f - zg) * ng + zg * phf[e];
        A.h1f[n_c * 1024 + col] = hv;            // private, cached
        hv2[e] = hv;
      }
      stu32c(A.h1 + n_c * 1024 + colA,
             (unsigned)f2b(hv2[0]) | ((unsigned)f2b(hv2[1]) << 16));
      float sv = hv2[0] + hv2[1], sq = hv2[0] * hv2[0] + hv2[1] * hv2[1];
      sv += __shfl_xor(sv, 1); sq += __shfl_xor(sq, 1);
      sv += __shfl_xor(sv, 2); sq += __shfl_xor(sq, 2);
      sv += __shfl_xor(sv, 4); sq += __shfl_xor(sq, 4);
      if ((tid & 7) == 0){
        stfc(A.stats + (blk - 64) * 64 + n_c, sv);
        stfc(A.stats + (blk - 64) * 64 + 32 + n_c, sq);
      }
      gbar(A.bar, ++ep);
      // PC: gh1 on h1_t (for next step's PB), overlaps PE
      ar[0] = FZ; ar[1] = FZ; az[0] = FZ; az[1] = FZ; ani[0] = FZ; ani[1] = FZ; anh[0] = FZ; anh[1] = FZ;
      #pragma unroll
      for (int ch = 0; ch < 8; ++ch){
        short8 a0 = ld8c(A.h1 + r * 1024 + kq + ch * 32 + g4 * 8);
        short8 a1 = ld8c(A.h1 + (16 + r) * 1024 + kq + ch * 32 + g4 * 8);
        ar[0] = mfma16(a0, wh[ch], ar[0]);        ar[1] = mfma16(a1, wh[ch], ar[1]);
        az[0] = mfma16(a0, wh[8 + ch], az[0]);    az[1] = mfma16(a1, wh[8 + ch], az[1]);
        anh[0] = mfma16(a0, wh[16 + ch], anh[0]); anh[1] = mfma16(a1, wh[16 + ch], anh[1]);
      }
      gbar(A.bar, ++ep);
    }
  } else if (blk < 196){
    // ---------------- PE: pred / emb_{t+1} / Gx_{t+1} on h1 (LN folded) ----------------
    const int tile = (blk - 128) * 4 + q;     // 0..271
    int jt, c0;
    const u16* wsrc; const float *Sv, *Bv;
    if (tile < 16)      { jt = 0; c0 = tile * 16;        wsrc = A.wpg;  Sv = A.Sp; Bv = A.Bp; }
    else if (tile < 80) { jt = 1; c0 = (tile - 16) * 16; wsrc = A.Wdpg; Sv = A.S1; Bv = A.B1; }
    else                { jt = 2; c0 = (tile - 80) * 16; wsrc = A.Wgpg; Sv = A.S2; Bv = A.B2; }
    short8 w[32];
    #pragma unroll
    for (int ch = 0; ch < 32; ++ch)
      w[ch] = ld8(wsrc + (size_t)(c0 + r) * 1024 + ch * 32 + g4 * 8);
    const float Sc = Sv[c0 + r], Bc = Bv[c0 + r];
    const int col = c0 + r;
    int ep = 1; gbar(A.bar, ep);
    #pragma unroll 1
    for (int t = 0; t < DEC_STEPS; ++t){
      gbar(A.bar, ++ep);   // PA idle
      gbar(A.bar, ++ep);   // PB idle
      // PC
      float sacc = 0.f;
      #pragma unroll
      for (int b2 = 0; b2 < 64; ++b2) sacc += ldfc(A.stats + b2 * 64 + lane);
      float muA[2][4], rsA[2][4];
      #pragma unroll
      for (int m = 0; m < 2; ++m)
        #pragma unroll
        for (int j = 0; j < 4; ++j){
          int n = m * 16 + g4 * 4 + j;
          float sv = __shfl(sacc, n), sq = __shfl(sacc, 32 + n);
          float mu = sv * (1.f / 1024.f);
          muA[m][j] = mu;
          rsA[m][j] = rsqrtf(sq * (1.f / 1024.f) - mu * mu + 1e-5f);
        }
      f32x4 a0 = FZ, a1 = FZ;
      #pragma unroll
      for (int ch = 0; ch < 32; ++ch){
        short8 x0 = ld8c(A.h1 + r * 1024 + ch * 32 + g4 * 8);
        short8 x1 = ld8c(A.h1 + (16 + r) * 1024 + ch * 32 + g4 * 8);
        a0 = mfma16(x0, w[ch], a0);
        a1 = mfma16(x1, w[ch], a1);
      }
      #pragma unroll
      for (int m = 0; m < 2; ++m)
        #pragma unroll
        for (int j = 0; j < 4; ++j){
          int n = m * 16 + g4 * 4 + j;
          float acc = (m ? a1[j] : a0[j]);
          float v = rsA[m][j] * (acc - muA[m][j] * Sc) + Bc;
          if (jt == 0){
            A.out[(size_t)n * (256 * 540) + (size_t)col * 540 + t] = v;   // cached; flushed at kernel end
          } else if (jt == 1){
            float pre = v + ldfc(A.Xal + n * 1024 + col);
            st16c(A.emb + n * 1024 + col, (unsigned)f2b(gelu_f(pre)));
          } else {
            stfc(A.Gx + n * 3072 + col, v + ldfc(A.Gal + n * 3072 + col));
          }
        }
      gbar(A.bar, ++ep);
    }
  } else {
    // ---------------- AL: audio/lxm partials for step t+1 ----------------
    const int wg = (blk - 196) * 4 + q;       // 0..63
    const int at0 = wg * 4;
    short8 w[48];
    float vb[4];
    #pragma unroll
    for (int j = 0; j < 4; ++j){
      int at = at0 + j;
      if (at < 64){
        #pragma unroll
        for (int ch = 0; ch < 12; ++ch)
          w[j * 12 + ch] = ld8(A.wd + (size_t)(at * 16 + r) * 640 + 256 + ch * 32 + g4 * 8);
        vb[j] = A.vX[at * 16 + r];
      } else {
        #pragma unroll
        for (int ch = 0; ch < 12; ++ch)
          w[j * 12 + ch] = ld8(A.wih0 + (size_t)((at - 64) * 16 + r) * 1664 + 1280 + ch * 32 + g4 * 8);
        vb[j] = A.vG[(at - 64) * 16 + r];
      }
    }
    int ep = 1; gbar(A.bar, ep);
    #pragma unroll 1
    for (int t = 0; t < DEC_STEPS; ++t){
      gbar(A.bar, ++ep);   // PA idle
      // PB: aud_seq/lxm_b are read-only -> normal cached loads (L2 persists now)
      int tn = t + 1; if (tn > 539) tn = 539;
      int bn = tn / 30;
      short8 af0[12], af1[12];
      #pragma unroll
      for (int ch = 0; ch < 12; ++ch){
        int kk = ch * 32 + g4 * 8;
        if (ch < 8){
          af0[ch] = ld8(A.aud_seq + ((size_t)tn * 32 + r) * 256 + kk);
          af1[ch] = ld8(A.aud_seq + ((size_t)tn * 32 + 16 + r) * 256 + kk);
        } else {
          af0[ch] = ld8(A.lxm_b + ((size_t)bn * 32 + r) * 128 + kk - 256);
          af1[ch] = ld8(A.lxm_b + ((size_t)bn * 32 + 16 + r) * 128 + kk - 256);
        }
      }
      #pragma unroll
      for (int j = 0; j < 4; ++j){
        f32x4 c0a = FZ, c1a = FZ;
        #pragma unroll
        for (int ch = 0; ch < 12; ++ch){
          c0a = mfma16(af0[ch], w[j * 12 + ch], c0a);
          c1a = mfma16(af1[ch], w[j * 12 + ch], c1a);
        }
        int at = at0 + j;
        #pragma unroll
        for (int m = 0; m < 2; ++m)
          #pragma unroll
          for (int jj = 0; jj < 4; ++jj){
            int n = m * 16 + g4 * 4 + jj;
            float v = (m ? c1a[jj] : c0a[jj]) + vb[j];
            if (at < 64) stfc(A.Xal + n * 1024 + at * 16 + r, v);
            else         stfc(A.Gal + n * 3072 + (at - 64) * 16 + r, v);
          }
      }
      gbar(A.bar, ++ep);   // end PB
      gbar(A.bar, ++ep);   // PC idle
    }
  }
}

// ---------------------------------------------------------------------------

extern "C" void kernel_launch(void* const* d_in, const int* in_sizes, int n_in,
                              void* d_out, int out_size, void* d_ws, size_t ws_size,
                              hipStream_t stream) {
  enum { I_AUD=0, I_MO=1, I_LXM=2, I_AEW0=3, I_AEB0=4, I_AEW1=5, I_AEB1=6, I_AEW2=7, I_AEB2=8,
         I_AEW3=9, I_AEB3=10, I_AELNG=11, I_AELNB=12, I_CIW0=13, I_CIB0=14, I_CIW1=15, I_CIB1=16,
         I_CIW2=17, I_CIB2=18, I_DECW=19, I_DECB=20, I_WIH0=21, I_WHH0=22, I_BIH0=23, I_BHH0=24,
         I_WIH1=25, I_WHH1=26, I_BIH1=27, I_BHH1=28, I_LNG=29, I_LNB=30, I_PREDW=31, I_PREDB=32 };

  char* base = (char*)d_ws;
  size_t off = 0;
  auto alloc = [&](size_t bytes)->void*{
    void* p = base + off;
    off += (bytes + 255) & ~(size_t)255;
    return p;
  };

  // bf16 weight blobs
  u16* wd_b   = (u16*)alloc((size_t)1024*640*2);
  u16* wih0_b = (u16*)alloc((size_t)3072*1664*2);
  u16* whh0_b = (u16*)alloc((size_t)3072*1024*2);
  u16* wih1_b = (u16*)alloc((size_t)3072*1024*2);
  u16* whh1_b = (u16*)alloc((size_t)3072*1024*2);
  u16* wc0    = (u16*)alloc((size_t)1024*384*2);
  u16* wc1    = (u16*)alloc((size_t)1024*1024*2);
  u16* wc2    = (u16*)alloc((size_t)2048*1024*2);
  u16* w0k    = (u16*)alloc((size_t)256*896*2);
  u16* w1k    = (u16*)alloc((size_t)256*1280*2);
  u16* w2k    = (u16*)alloc((size_t)256*1024*2);
  u16* w3k    = (u16*)alloc((size_t)256*256*2);
  u16* wpT    = (u16*)alloc((size_t)1024*256*2);
  u16* wpg    = (u16*)alloc((size_t)256*1024*2);
  u16* Wdpg   = (u16*)alloc((size_t)1024*1024*2);
  u16* Wgpg   = (u16*)alloc((size_t)3072*1024*2);
  float* Sp = (float*)alloc(256*4);   float* Bp = (float*)alloc(256*4);
  float* S1 = (float*)alloc(1024*4);  float* B1 = (float*)alloc(1024*4);
  float* S2 = (float*)alloc(3072*4);  float* B2 = (float*)alloc(3072*4);
  float* vX = (float*)alloc(1024*4);  float* vG = (float*)alloc(3072*4);
  // sequences / state
  u16* aud_seq = (u16*)alloc((size_t)540*32*256*2);
  u16* lxm_b   = (u16*)alloc((size_t)18*32*128*2);
  u16* xc      = (u16*)alloc((size_t)32*384*2);
  u16* xc0     = (u16*)alloc((size_t)32*640*2);
  u16* ci1     = (u16*)alloc((size_t)32*1024*2);
  u16* ci2     = (u16*)alloc((size_t)32*1024*2);
  float* hraw  = (float*)alloc((size_t)32*2048*4);
  u16* h0      = (u16*)alloc((size_t)32*1024*2);
  u16* h1      = (u16*)alloc((size_t)32*1024*2);
  float* h0f   = (float*)alloc((size_t)32*1024*4);
  float* h1f   = (float*)alloc((size_t)32*1024*4);
  u16* emb     = (u16*)alloc((size_t)32*1024*2);
  u16* pre_mo  = (u16*)alloc((size_t)32*256*2);
  float* Gx    = (float*)alloc((size_t)32*3072*4);
  float* Xal   = (float*)alloc((size_t)32*1024*4);
  float* Gal   = (float*)alloc((size_t)32*3072*4);
  float* stats = (float*)alloc((size_t)64*64*4);
  int* bar     = (int*)alloc(16384);
  // encoder transients
  u16* O0   = (u16*)alloc((size_t)48384*256*2);
  u16* O1   = (u16*)alloc((size_t)46080*256*2);
  u16* O2   = (u16*)alloc((size_t)23040*256*2);
  float* O3 = (float*)alloc((size_t)23040*256*4);
  u16* Abuf = (u16*)alloc((size_t)23040*1280*2);
  // composition temps alias Abuf (free after conv GEMMs)
  float* Wdp_f = (float*)Abuf;                                  // 4 MB
  float* Wgp_f = (float*)((char*)Abuf + (size_t)1024*1024*4 + 256);  // 12.6 MB
  (void)ws_size; (void)in_sizes; (void)n_in; (void)out_size;

  const float* aud = (const float*)d_in[I_AUD];
  const float* mo  = (const float*)d_in[I_MO];
  const float* lxm = (const float*)d_in[I_LXM];
  float* out = (float*)d_out;

  auto cdiv = [](long long a, long long b)->int{ return (int)((a + b - 1) / b); };
  auto cvt = [&](int idx, u16* dst, int n){
    f2b_k<<<cdiv(n,256), 256, 0, stream>>>((const float*)d_in[idx], dst, n);
  };

  // ---- weight conversion ----
  cvt(I_DECW, wd_b,   1024*640);
  cvt(I_WIH0, wih0_b, 3072*1664);
  cvt(I_WHH0, whh0_b, 3072*1024);
  cvt(I_WIH1, wih1_b, 3072*1024);
  cvt(I_WHH1, whh1_b, 3072*1024);
  cvt(I_CIW0, wc0,    1024*384);
  cvt(I_CIW1, wc1,    1024*1024);
  cvt(I_CIW2, wc2,    2048*1024);
  cvt(I_AEW0, w0k,    256*896);
  cvt(I_AEW1, w1k,    256*1280);
  cvt(I_AEW2, w2k,    256*1024);
  cvt(I_AEW3, w3k,    256*256);

  // ---- encoder ----
  for (int c = 0; c < 2; ++c){
    int row0 = c * 24192;
    long long tot = (long long)24192 * 896;
    im2col0_k<<<cdiv(tot,256), 256, 0, stream>>>(aud, Abuf, row0, tot);
    gemm_bt<<<dim3(24192/64, 4), 256, 0, stream>>>(Abuf, 896, w0k, 896, (const float*)d_in[I_AEB0],
        O0 + (size_t)row0*256, 24192, 256, 896, GELU_FLG|BF16_FLG);
  }
  for (int c = 0; c < 2; ++c){
    int row0 = c * 23040;
    long long tot = (long long)23040 * 1280;
    im2col1_k<<<cdiv(tot,256), 256, 0, stream>>>(O0, Abuf, row0, tot);
    gemm_bt<<<dim3(23040/64, 4), 256, 0, stream>>>(Abuf, 1280, w1k, 1280, (const float*)d_in[I_AEB1],
        O1 + (size_t)row0*256, 23040, 256, 1280, GELU_FLG|BF16_FLG);
  }
  {
    long long tot = (long long)23040 * 1024;
    im2col2_k<<<cdiv(tot,256), 256, 0, stream>>>(O1, Abuf, 0, tot);
    gemm_bt<<<dim3(23040/64, 4), 256, 0, stream>>>(Abuf, 1024, w2k, 1024, (const float*)d_in[I_AEB2],
        O2, 23040, 256, 1024, GELU_FLG|BF16_FLG);
  }
  gemm_bt<<<dim3(23040/64, 4), 256, 0, stream>>>(O2, 256, w3k, 256, (const float*)d_in[I_AEB3],
      O3, 23040, 256, 256, GELU_FLG);
  enc_ln_k<<<4320, 256, 0, stream>>>(O3, (const float*)d_in[I_AELNG], (const float*)d_in[I_AELNB], aud_seq);

  // ---- lxm + cell-init chain ----
  lxm_g_k<<<cdiv(18*32*128,256), 256, 0, stream>>>(lxm, lxm_b);
  gather_xc_k<<<cdiv(32*384,256), 256, 0, stream>>>(mo, lxm, xc, pre_mo);
  gemm_bt<<<dim3(1,16), 256, 0, stream>>>(xc, 384, wc0, 384, (const float*)d_in[I_CIB0],
      ci1, 32, 1024, 384, GELU_FLG|BF16_FLG);
  gemm_bt<<<dim3(1,16), 256, 0, stream>>>(ci1, 1024, wc1, 1024, (const float*)d_in[I_CIB1],
      ci2, 32, 1024, 1024, GELU_FLG|BF16_FLG);
  gemm_bt<<<dim3(1,32), 256, 0, stream>>>(ci2, 1024, wc2, 1024, (const float*)d_in[I_CIB2],
      hraw, 32, 2048, 1024, 0);
  split_h_k<<<cdiv(32*1024,256), 256, 0, stream>>>(hraw, h0, h1, h0f, h1f);

  // ---- composition precompute ----
  t_wpT_k<<<cdiv(1024*256,256), 256, 0, stream>>>((const float*)d_in[I_PREDW], wpT);
  // Wdp = Wd_p @ Wp  (wd cols 0..255), Wgp = Wih0_p @ Wp (wih0 cols 1024..1279)
  gemm_bt<<<dim3(16,16), 256, 0, stream>>>(wd_b, 640, wpT, 256, nullptr, Wdp_f, 1024, 1024, 256, 0);
  gemm_bt<<<dim3(48,16), 256, 0, stream>>>(wih0_b + 1024, 1664, wpT, 256, nullptr, Wgp_f, 3072, 1024, 256, 0);
  foldW_k<<<cdiv(1024,4), 256, 0, stream>>>(Wdp_f, (const float*)d_in[I_LNG], (const float*)d_in[I_LNB],
      nullptr, Wdpg, S1, B1, 1024);
  foldW_k<<<cdiv(3072,4), 256, 0, stream>>>(Wgp_f, (const float*)d_in[I_LNG], (const float*)d_in[I_LNB],
      nullptr, Wgpg, S2, B2, 3072);
  foldW_k<<<cdiv(256,4), 256, 0, stream>>>((const float*)d_in[I_PREDW], (const float*)d_in[I_LNG],
      (const float*)d_in[I_LNB], (const float*)d_in[I_PREDB], wpg, Sp, Bp, 256);
  // vX = db + Wd_p @ pb ; vG = Wih0_p @ pb
  vfold_k<<<cdiv(1024,4), 256, 0, stream>>>((const float*)d_in[I_DECW], 640, 0,
      (const float*)d_in[I_PREDB], (const float*)d_in[I_DECB], vX, 1024);
  vfold_k<<<cdiv(3072,4), 256, 0, stream>>>((const float*)d_in[I_WIH0], 1664, 1024,
      (const float*)d_in[I_PREDB], nullptr, vG, 3072);

  // ---- t=0 boot values: emb_0 and Gx_0 from the real xcat_0 ----
  build_xc0_k<<<cdiv(32*640,256), 256, 0, stream>>>(pre_mo, aud_seq, lxm_b, xc0);
  gemm_bt<<<dim3(1,16), 256, 0, stream>>>(xc0, 640, wd_b, 640, (const float*)d_in[I_DECB],
      emb, 32, 1024, 640, GELU_FLG|BF16_FLG);
  gemm_bt<<<dim3(1,48), 256, 0, stream>>>(xc0, 640, wih0_b + 1024, 1664, nullptr,
      Gx, 32, 3072, 640, 0);

  hipMemsetAsync(bar, 0, 16384, stream);

  // ---- persistent decoder ----
  DecArgs da;
  da.aud_seq = aud_seq; da.lxm_b = lxm_b;
  da.wih0 = wih0_b; da.whh0 = whh0_b; da.wih1 = wih1_b; da.whh1 = whh1_b; da.wd = wd_b;
  da.wpg = wpg; da.Wdpg = Wdpg; da.Wgpg = Wgpg;
  da.Sp = Sp; da.Bp = Bp; da.S1 = S1; da.B1 = B1; da.S2 = S2; da.B2 = B2; da.vX = vX; da.vG = vG;
  da.bih0 = (const float*)d_in[I_BIH0]; da.bhh0 = (const float*)d_in[I_BHH0];
  da.bih1 = (const float*)d_in[I_BIH1]; da.bhh1 = (const float*)d_in[I_BHH1];
  da.emb = emb; da.h0 = h0; da.h1 = h1;
  da.h0f = h0f; da.h1f = h1f; da.Gx = Gx; da.Xal = Xal; da.Gal = Gal;
  da.stats = stats; da.out = out; da.bar = bar;
  decode_k<<<dim3(NBLK), dim3(256), 0, stream>>>(da);
}

// Round 6
// 20903.279 us; speedup vs baseline: 5.0225x; 1.2471x over previous
//
#include <hip/hip_runtime.h>

// ---------------------------------------------------------------------------
// MotionGenerator RNN for MI355X (gfx950).
//  - encoder: im2col + bf16 MFMA GEMM (weights are [out,in] == [N,K] B^T layout)
//  - decoder: weight-stationary persistent kernel, 212 blocks x 256 thr,
//    all decoder weights resident in VGPRs, 3 grid barriers per step.
//    Cross-block activations ride a NEVER-REUSED ring (ring[t]): producers
//    store uncached (sc0 sc1, write-through past L2); consumers use plain
//    CACHED loads -- fresh addresses can't be stale, and the per-XCD L2
//    multicasts each line to its ~26 blocks (kills the 20 MB/step uncached
//    fan-out that capped rounds 3-5 at ~46 us/step).
// ---------------------------------------------------------------------------

typedef unsigned short u16;
typedef __attribute__((ext_vector_type(8))) short short8;
typedef __attribute__((ext_vector_type(4))) float f32x4;

#define GELU_FLG 1
#define BF16_FLG 2
#define NBLK 212
#define DEC_STEPS 540

__device__ __forceinline__ u16 f2b(float f){
  union { float f; unsigned u; } c; c.f = f;
  return (u16)((c.u + 0x7fffu + ((c.u >> 16) & 1u)) >> 16);   // RNE
}
__device__ __forceinline__ short8 ld8(const u16* p){
  return *reinterpret_cast<const short8*>(p);
}
// coherent (agent-scope, cache-bypass) accessors for small cross-block data
__device__ __forceinline__ float ldfc(const float* p){
  return __hip_atomic_load(p, __ATOMIC_RELAXED, __HIP_MEMORY_SCOPE_AGENT);
}
__device__ __forceinline__ void stfc(float* p, float v){
  __hip_atomic_store(p, v, __ATOMIC_RELAXED, __HIP_MEMORY_SCOPE_AGENT);
}
__device__ __forceinline__ void stu32c(u16* p, unsigned v){
  __hip_atomic_store((unsigned*)p, v, __ATOMIC_RELAXED, __HIP_MEMORY_SCOPE_AGENT);
}
__device__ __forceinline__ void st16c(u16* p, unsigned v){
  asm volatile("global_store_short %0, %1, off sc0 sc1" :: "v"(p), "v"(v) : "memory");
}
__device__ __forceinline__ f32x4 mfma16(short8 a, short8 b, f32x4 c){
  return __builtin_amdgcn_mfma_f32_16x16x32_bf16(a, b, c, 0, 0, 0);
}
__device__ __forceinline__ float gelu_f(float x){
  return 0.5f * x * (1.f + erff(x * 0.70710678118654752f));   // exact gelu
}
__device__ __forceinline__ float sigmoid_f(float x){
  return 1.f / (1.f + __expf(-x));
}
__device__ __forceinline__ float tanh_f(float x){
  float e = __expf(-2.f * x);
  return (1.f - e) / (1.f + e);
}

// ---------------- elementwise / gather kernels ----------------

__global__ void f2b_k(const float* __restrict__ s, u16* __restrict__ d, int n){
  int i = blockIdx.x * 256 + threadIdx.x;
  if (i < n) d[i] = f2b(s[i]);
}

__global__ void gather_xc_k(const float* __restrict__ mo, const float* __restrict__ lxm,
                            u16* __restrict__ xc, u16* __restrict__ pre_mo){
  int i = blockIdx.x * 256 + threadIdx.x;
  if (i >= 32 * 384) return;
  int n = i / 384, c = i - n * 384;
  float v = (c < 256) ? mo[(size_t)(n * 256 + c) * 600 + 29]
                      : lxm[(size_t)(n * 128 + (c - 256)) * 20];
  u16 h = f2b(v);
  xc[i] = h;
  if (c < 256) pre_mo[n * 256 + c] = h;
}

__global__ void lxm_g_k(const float* __restrict__ lxm, u16* __restrict__ o){
  int i = blockIdx.x * 256 + threadIdx.x;
  if (i >= 18 * 32 * 128) return;
  int c = i & 127, rest = i >> 7;
  int n = rest & 31, b = rest >> 5;
  o[i] = f2b(lxm[(size_t)(n * 128 + c) * 20 + 1 + b]);
}

__global__ void split_h_k(const float* __restrict__ hraw, u16* __restrict__ h0, u16* __restrict__ h1,
                          float* __restrict__ h0f, float* __restrict__ h1f){
  int i = blockIdx.x * 256 + threadIdx.x;
  if (i >= 32 * 1024) return;
  int n = i >> 10, c = i & 1023;
  float a = hraw[(size_t)n * 2048 + c];
  float b = hraw[(size_t)n * 2048 + 1024 + c];
  h0[i] = f2b(a); h1[i] = f2b(b);
  h0f[i] = a;     h1f[i] = b;
}

__global__ void build_xc0_k(const u16* __restrict__ pre_mo, const u16* __restrict__ aud_seq,
                            const u16* __restrict__ lxm_b, u16* __restrict__ xc0){
  int i = blockIdx.x * 256 + threadIdx.x;
  if (i >= 32 * 640) return;
  int n = i / 640, c = i - n * 640;
  u16 v;
  if (c < 256) v = pre_mo[n * 256 + c];
  else if (c < 512) v = aud_seq[n * 256 + (c - 256)];
  else v = lxm_b[n * 128 + (c - 512)];
  xc0[i] = v;
}

__global__ void t_wpT_k(const float* __restrict__ wp, u16* __restrict__ wpT){
  int i = blockIdx.x * 256 + threadIdx.x;
  if (i >= 1024 * 256) return;
  int h = i >> 8, j = i & 255;
  wpT[i] = f2b(wp[(size_t)j * 1024 + h]);
}

// fold LN gain/bias into a [R x 1024] matrix that acts on LN(h1):
// Wg = W * g (bf16), S[r] = sum_h W[r,h]*g[h], B[r] = sum_h W[r,h]*b[h] (+addb)
__global__ void foldW_k(const float* __restrict__ src, const float* __restrict__ g,
                        const float* __restrict__ b, const float* __restrict__ addb,
                        u16* __restrict__ Wg, float* __restrict__ S, float* __restrict__ B, int R){
  int row = blockIdx.x * 4 + (threadIdx.x >> 6);
  if (row >= R) return;
  int lane = threadIdx.x & 63;
  const float* sr = src + (size_t)row * 1024;
  float s = 0.f, bb = 0.f;
  #pragma unroll
  for (int k = 0; k < 16; ++k){
    int c = lane + k * 64;
    float w = sr[c], gw = w * g[c];
    Wg[(size_t)row * 1024 + c] = f2b(gw);
    s += gw; bb += w * b[c];
  }
  #pragma unroll
  for (int m = 1; m < 64; m <<= 1){ s += __shfl_xor(s, m); bb += __shfl_xor(bb, m); }
  if (lane == 0){ S[row] = s; B[row] = bb + (addb ? addb[row] : 0.f); }
}

// v[row] = base[row] + sum_{j<256} W[row*ldw + off + j] * pb[j]
__global__ void vfold_k(const float* __restrict__ W, int ldw, int off, const float* __restrict__ pb,
                        const float* __restrict__ base, float* __restrict__ v, int R){
  int row = blockIdx.x * 4 + (threadIdx.x >> 6);
  if (row >= R) return;
  int lane = threadIdx.x & 63;
  const float* wr = W + (size_t)row * ldw + off;
  float s = 0.f;
  #pragma unroll
  for (int k = 0; k < 4; ++k){ int j = lane + k * 64; s += wr[j] * pb[j]; }
  #pragma unroll
  for (int m = 1; m < 64; m <<= 1) s += __shfl_xor(s, m);
  if (lane == 0) v[row] = s + (base ? base[row] : 0.f);
}

// ---------------- im2col kernels ----------------

__global__ void im2col0_k(const float* __restrict__ aud, u16* __restrict__ A, int row0, long long tot){
  long long i = (long long)blockIdx.x * 256 + threadIdx.x;
  if (i >= tot) return;
  int k = (int)(i % 896);
  int row = row0 + (int)(i / 896);
  int ci = k / 7, kk = k - ci * 7;
  int p = row % 84, bn = row / 84;
  int b = bn >> 5, n = bn & 31;
  A[i] = f2b(aud[(size_t)(n * 128 + ci) * 600 + b * 30 + p + kk]);
}

__global__ void im2col1_k(const u16* __restrict__ O0, u16* __restrict__ A, int row0, long long tot){
  long long i = (long long)blockIdx.x * 256 + threadIdx.x;
  if (i >= tot) return;
  int k = (int)(i % 1280);
  int row = row0 + (int)(i / 1280);
  int ci = k / 5, kk = k - ci * 5;
  int p = row % 80, bn = row / 80;
  A[i] = O0[(size_t)(bn * 84 + p + kk) * 256 + ci];
}

__global__ void im2col2_k(const u16* __restrict__ O1, u16* __restrict__ A, int row0, long long tot){
  long long i = (long long)blockIdx.x * 256 + threadIdx.x;
  if (i >= tot) return;
  int k = (int)(i & 1023);
  int row = row0 + (int)(i >> 10);
  int ci = k >> 2, kk = k & 3;
  int p = row % 40, bn = row / 40;
  int pos = 2 * p - 1 + kk;                      // stride 2, pad 1
  A[i] = (pos >= 0 && pos < 80) ? O1[(size_t)(bn * 80 + pos) * 256 + ci] : (u16)0;
}

// ---------------- GEMM: C[M,N] = A[M,K] @ W[N,K]^T  (bf16 MFMA) ----------------

__global__ void gemm_bt(const u16* __restrict__ A, int lda,
                        const u16* __restrict__ W, int ldw, const float* __restrict__ bias,
                        void* __restrict__ outp, int M, int N, int K, int flags){
  const int lane = threadIdx.x & 63, widx = threadIdx.x >> 6;
  const int m0 = blockIdx.x * 64 + widx * 16;
  if (m0 >= M) return;
  const int n0 = blockIdx.y * 64;
  const int r = lane & 15, g4 = lane >> 4;
  const u16* arow = A + (size_t)(m0 + r) * lda + g4 * 8;
  const u16* wrow = W + (size_t)(n0 + r) * ldw + g4 * 8;
  f32x4 acc[4];
  const f32x4 FZ = {0.f, 0.f, 0.f, 0.f};
  acc[0] = FZ; acc[1] = FZ; acc[2] = FZ; acc[3] = FZ;
  for (int k = 0; k < K; k += 32){
    short8 a = ld8(arow + k);
    #pragma unroll
    for (int j = 0; j < 4; ++j)
      acc[j] = mfma16(a, ld8(wrow + (size_t)j * 16 * ldw + k), acc[j]);
  }
  #pragma unroll
  for (int j = 0; j < 4; ++j){
    int col = n0 + j * 16 + r;
    float bv = bias ? bias[col] : 0.f;
    #pragma unroll
    for (int q = 0; q < 4; ++q){
      int row = m0 + g4 * 4 + q;
      float v = acc[j][q] + bv;
      if (flags & GELU_FLG) v = gelu_f(v);
      if (flags & BF16_FLG) ((u16*)outp)[(size_t)row * N + col] = f2b(v);
      else                  ((float*)outp)[(size_t)row * N + col] = v;
    }
  }
}

// ---------------- encoder LayerNorm -> aud_seq (bf16) ----------------

__global__ void enc_ln_k(const float* __restrict__ O3, const float* __restrict__ g,
                         const float* __restrict__ bb, u16* __restrict__ aud_seq){
  int rid = blockIdx.x * 4 + (threadIdx.x >> 6);
  int lane = threadIdx.x & 63;
  int b = rid / 960, rem = rid - b * 960;
  int p2 = rem >> 5, n = rem & 31;
  int orow = (b * 32 + n) * 40 + p2;
  const float4 v = *reinterpret_cast<const float4*>(O3 + (size_t)orow * 256 + lane * 4);
  float s  = v.x + v.y + v.z + v.w;
  float s2 = v.x * v.x + v.y * v.y + v.z * v.z + v.w * v.w;
  #pragma unroll
  for (int m = 1; m < 64; m <<= 1){ s += __shfl_xor(s, m); s2 += __shfl_xor(s2, m); }
  float mu = s * (1.f / 256.f);
  float var = s2 * (1.f / 256.f) - mu * mu;
  float rs = rsqrtf(var + 1e-5f);
  int c = lane * 4;
  u16* dst = aud_seq + (size_t)rid * 256 + c;
  dst[0] = f2b((v.x - mu) * rs * g[c + 0] + bb[c + 0]);
  dst[1] = f2b((v.y - mu) * rs * g[c + 1] + bb[c + 1]);
  dst[2] = f2b((v.z - mu) * rs * g[c + 2] + bb[c + 2]);
  dst[3] = f2b((v.w - mu) * rs * g[c + 3] + bb[c + 3]);
}

// ---------------- persistent weight-stationary decoder ----------------

struct DecArgs {
  const u16 *aud_seq, *lxm_b;
  const u16 *wih0, *whh0, *wih1, *whh1, *wd;       // bf16 blobs
  const u16 *wpg, *Wdpg, *Wgpg;                    // LN-folded PE weights
  const float *Sp, *Bp, *S1, *B1, *S2, *B2, *vX, *vG;
  const float *bih0, *bhh0, *bih1, *bhh1;
  const u16 *h0init, *h1init;
  u16 *embR, *h0R, *h1R;                 // rings: slot t = 32x1024 bf16 (64 KB)
  float *statsR;                         // ring:  slot t = [64 blk][64] f32
  float *h0f, *h1f, *Gx, *Xal, *Gal, *out;
  int *bar;
};

// grid barrier, fence-free: drain own vmem (uncached stores are write-through,
// so vmcnt(0) == globally visible), store own slot, poll all slots in parallel.
__device__ __forceinline__ void gbar(int* bar, int ep){
  asm volatile("s_waitcnt vmcnt(0)" ::: "memory");
  __syncthreads();
  if (threadIdx.x == 0)
    __hip_atomic_store(bar + blockIdx.x * 16, ep, __ATOMIC_RELAXED, __HIP_MEMORY_SCOPE_AGENT);
  if (threadIdx.x < NBLK){
    while (__hip_atomic_load(bar + threadIdx.x * 16, __ATOMIC_RELAXED, __HIP_MEMORY_SCOPE_AGENT) < ep)
      __builtin_amdgcn_s_sleep(1);
  }
  __syncthreads();
}

__global__ __launch_bounds__(256, 1) void decode_k(DecArgs A){
  const int tid = threadIdx.x;
  const int lane = tid & 63, q = tid >> 6;
  const int r = lane & 15, g4 = lane >> 4;
  const int blk = blockIdx.x;
  __shared__ float lds[4][4][32][16];
  const f32x4 FZ = {0.f, 0.f, 0.f, 0.f};

  if (blk < 64){
    // ---------------- L0: h0 producer (wih0_e + whh0 resident) ----------------
    const int c0 = blk * 16;
    const int kq = q * 256;
    short8 we[24], wh[24];
    #pragma unroll
    for (int g = 0; g < 3; ++g)
      #pragma unroll
      for (int ch = 0; ch < 8; ++ch){
        we[g * 8 + ch] = ld8(A.wih0 + (size_t)(g * 1024 + c0 + r) * 1664 + kq + ch * 32 + g4 * 8);
        wh[g * 8 + ch] = ld8(A.whh0 + (size_t)(g * 1024 + c0 + r) * 1024 + kq + ch * 32 + g4 * 8);
      }
    const int n_c = tid >> 3;
    const int cc0 = (tid & 7) * 2;
    const int colA = c0 + cc0, colB = colA + 1;
    const float bi_r[2] = {A.bih0[colA], A.bih0[colB]};
    const float bi_z[2] = {A.bih0[1024 + colA], A.bih0[1024 + colB]};
    const float bi_n[2] = {A.bih0[2048 + colA], A.bih0[2048 + colB]};
    const float bh_r[2] = {A.bhh0[colA], A.bhh0[colB]};
    const float bh_z[2] = {A.bhh0[1024 + colA], A.bhh0[1024 + colB]};
    const float bh_n[2] = {A.bhh0[2048 + colA], A.bhh0[2048 + colB]};
    f32x4 ar[2], az[2], ani[2], anh[2];
    // P0: gh0 on initial h0 (prior-kernel data: dispatch acquire made it safe)
    ar[0] = FZ; ar[1] = FZ; az[0] = FZ; az[1] = FZ; ani[0] = FZ; ani[1] = FZ; anh[0] = FZ; anh[1] = FZ;
    #pragma unroll
    for (int ch = 0; ch < 8; ++ch){
      short8 a0 = ld8(A.h0init + r * 1024 + kq + ch * 32 + g4 * 8);
      short8 a1 = ld8(A.h0init + (16 + r) * 1024 + kq + ch * 32 + g4 * 8);
      ar[0] = mfma16(a0, wh[ch], ar[0]);        ar[1] = mfma16(a1, wh[ch], ar[1]);
      az[0] = mfma16(a0, wh[8 + ch], az[0]);    az[1] = mfma16(a1, wh[8 + ch], az[1]);
      anh[0] = mfma16(a0, wh[16 + ch], anh[0]); anh[1] = mfma16(a1, wh[16 + ch], anh[1]);
    }
    int ep = 1; gbar(A.bar, ep);
    #pragma unroll 1
    for (int t = 0; t < DEC_STEPS; ++t){
      const u16* embT = A.embR + (size_t)t * 32768;
      u16*       h0T  = A.h0R  + (size_t)t * 32768;
      // PA: prefetch Gx (uncached) + h0f (private), gi0e on emb (cached ring), combine
      float pgr[2], pgz[2], pgn[2], phf[2];
      #pragma unroll
      for (int e = 0; e < 2; ++e){
        int col = c0 + cc0 + e;
        pgr[e] = ldfc(A.Gx + n_c * 3072 + col);
        pgz[e] = ldfc(A.Gx + n_c * 3072 + 1024 + col);
        pgn[e] = ldfc(A.Gx + n_c * 3072 + 2048 + col);
        phf[e] = A.h0f[n_c * 1024 + col];
      }
      #pragma unroll
      for (int ch = 0; ch < 8; ++ch){
        short8 a0 = ld8(embT + r * 1024 + kq + ch * 32 + g4 * 8);
        short8 a1 = ld8(embT + (16 + r) * 1024 + kq + ch * 32 + g4 * 8);
        ar[0] = mfma16(a0, we[ch], ar[0]);        ar[1] = mfma16(a1, we[ch], ar[1]);
        az[0] = mfma16(a0, we[8 + ch], az[0]);    az[1] = mfma16(a1, we[8 + ch], az[1]);
        ani[0] = mfma16(a0, we[16 + ch], ani[0]); ani[1] = mfma16(a1, we[16 + ch], ani[1]);
      }
      #pragma unroll
      for (int m = 0; m < 2; ++m)
        #pragma unroll
        for (int j = 0; j < 4; ++j){
          int row = m * 16 + g4 * 4 + j;
          lds[q][0][row][r] = ar[m][j];
          lds[q][1][row][r] = az[m][j];
          lds[q][2][row][r] = ani[m][j];
          lds[q][3][row][r] = anh[m][j];
        }
      __syncthreads();
      float hv2[2];
      #pragma unroll
      for (int e = 0; e < 2; ++e){
        int cc = cc0 + e, col = c0 + cc;
        float sr = bi_r[e] + bh_r[e] + pgr[e];
        float sz = bi_z[e] + bh_z[e] + pgz[e];
        float si = bi_n[e] + pgn[e];
        float sh = bh_n[e];
        #pragma unroll
        for (int qq = 0; qq < 4; ++qq){
          sr += lds[qq][0][n_c][cc]; sz += lds[qq][1][n_c][cc];
          si += lds[qq][2][n_c][cc]; sh += lds[qq][3][n_c][cc];
        }
        float rg = sigmoid_f(sr), zg = sigmoid_f(sz);
        float ng = tanh_f(si + rg * sh);
        float hv = (1.f - zg) * ng + zg * phf[e];
        A.h0f[n_c * 1024 + col] = hv;            // private, cached
        hv2[e] = hv;
      }
      stu32c(h0T + n_c * 1024 + colA,
             (unsigned)f2b(hv2[0]) | ((unsigned)f2b(hv2[1]) << 16));
      gbar(A.bar, ++ep);
      // PB: fresh gh0-next on h0_t (cached ring read)
      ar[0] = FZ; ar[1] = FZ; az[0] = FZ; az[1] = FZ; ani[0] = FZ; ani[1] = FZ; anh[0] = FZ; anh[1] = FZ;
      #pragma unroll
      for (int ch = 0; ch < 8; ++ch){
        short8 a0 = ld8(h0T + r * 1024 + kq + ch * 32 + g4 * 8);
        short8 a1 = ld8(h0T + (16 + r) * 1024 + kq + ch * 32 + g4 * 8);
        ar[0] = mfma16(a0, wh[ch], ar[0]);        ar[1] = mfma16(a1, wh[ch], ar[1]);
        az[0] = mfma16(a0, wh[8 + ch], az[0]);    az[1] = mfma16(a1, wh[8 + ch], az[1]);
        anh[0] = mfma16(a0, wh[16 + ch], anh[0]); anh[1] = mfma16(a1, wh[16 + ch], anh[1]);
      }
      gbar(A.bar, ++ep);
      // PC: idle
      gbar(A.bar, ++ep);
    }
  } else if (blk < 128){
    // ---------------- L1: h1 producer (wih1 + whh1 resident) ----------------
    const int c0 = (blk - 64) * 16;
    const int kq = q * 256;
    short8 wi[24], wh[24];
    #pragma unroll
    for (int g = 0; g < 3; ++g)
      #pragma unroll
      for (int ch = 0; ch < 8; ++ch){
        wi[g * 8 + ch] = ld8(A.wih1 + (size_t)(g * 1024 + c0 + r) * 1024 + kq + ch * 32 + g4 * 8);
        wh[g * 8 + ch] = ld8(A.whh1 + (size_t)(g * 1024 + c0 + r) * 1024 + kq + ch * 32 + g4 * 8);
      }
    const int n_c = tid >> 3;
    const int cc0 = (tid & 7) * 2;
    const int colA = c0 + cc0, colB = colA + 1;
    const float bi_r[2] = {A.bih1[colA], A.bih1[colB]};
    const float bi_z[2] = {A.bih1[1024 + colA], A.bih1[1024 + colB]};
    const float bi_n[2] = {A.bih1[2048 + colA], A.bih1[2048 + colB]};
    const float bh_r[2] = {A.bhh1[colA], A.bhh1[colB]};
    const float bh_z[2] = {A.bhh1[1024 + colA], A.bhh1[1024 + colB]};
    const float bh_n[2] = {A.bhh1[2048 + colA], A.bhh1[2048 + colB]};
    f32x4 ar[2], az[2], ani[2], anh[2];
    // pre-loop: gh1 on initial h1
    ar[0] = FZ; ar[1] = FZ; az[0] = FZ; az[1] = FZ; ani[0] = FZ; ani[1] = FZ; anh[0] = FZ; anh[1] = FZ;
    #pragma unroll
    for (int ch = 0; ch < 8; ++ch){
      short8 a0 = ld8(A.h1init + r * 1024 + kq + ch * 32 + g4 * 8);
      short8 a1 = ld8(A.h1init + (16 + r) * 1024 + kq + ch * 32 + g4 * 8);
      ar[0] = mfma16(a0, wh[ch], ar[0]);        ar[1] = mfma16(a1, wh[ch], ar[1]);
      az[0] = mfma16(a0, wh[8 + ch], az[0]);    az[1] = mfma16(a1, wh[8 + ch], az[1]);
      anh[0] = mfma16(a0, wh[16 + ch], anh[0]); anh[1] = mfma16(a1, wh[16 + ch], anh[1]);
    }
    int ep = 1; gbar(A.bar, ep);
    #pragma unroll 1
    for (int t = 0; t < DEC_STEPS; ++t){
      const u16* h0T = A.h0R + (size_t)t * 32768;
      u16*       h1T = A.h1R + (size_t)t * 32768;
      // PA: idle (gh1 already computed in previous PC / pre-loop)
      gbar(A.bar, ++ep);
      // PB: gi1 on h0_t (cached ring), combine -> h1 ring + LN stats ring
      float phf[2];
      phf[0] = A.h1f[n_c * 1024 + colA];
      phf[1] = A.h1f[n_c * 1024 + colB];
      #pragma unroll
      for (int ch = 0; ch < 8; ++ch){
        short8 a0 = ld8(h0T + r * 1024 + kq + ch * 32 + g4 * 8);
        short8 a1 = ld8(h0T + (16 + r) * 1024 + kq + ch * 32 + g4 * 8);
        ar[0] = mfma16(a0, wi[ch], ar[0]);        ar[1] = mfma16(a1, wi[ch], ar[1]);
        az[0] = mfma16(a0, wi[8 + ch], az[0]);    az[1] = mfma16(a1, wi[8 + ch], az[1]);
        ani[0] = mfma16(a0, wi[16 + ch], ani[0]); ani[1] = mfma16(a1, wi[16 + ch], ani[1]);
      }
      #pragma unroll
      for (int m = 0; m < 2; ++m)
        #pragma unroll
        for (int j = 0; j < 4; ++j){
          int row = m * 16 + g4 * 4 + j;
          lds[q][0][row][r] = ar[m][j];
          lds[q][1][row][r] = az[m][j];
          lds[q][2][row][r] = ani[m][j];
          lds[q][3][row][r] = anh[m][j];
        }
      __syncthreads();
      float hv2[2];
      #pragma unroll
      for (int e = 0; e < 2; ++e){
        int cc = cc0 + e, col = c0 + cc;
        float sr = bi_r[e] + bh_r[e];
        float sz = bi_z[e] + bh_z[e];
        float si = bi_n[e];
        float sh = bh_n[e];
        #pragma unroll
        for (int qq = 0; qq < 4; ++qq){
          sr += lds[qq][0][n_c][cc]; sz += lds[qq][1][n_c][cc];
          si += lds[qq][2][n_c][cc]; sh += lds[qq][3][n_c][cc];
        }
        float rg = sigmoid_f(sr), zg = sigmoid_f(sz);
        float ng = tanh_f(si + rg * sh);
        float hv = (1.f - zg) * ng + zg * phf[e];
        A.h1f[n_c * 1024 + col] = hv;            // private, cached
        hv2[e] = hv;
      }
      stu32c(h1T + n_c * 1024 + colA,
             (unsigned)f2b(hv2[0]) | ((unsigned)f2b(hv2[1]) << 16));
      float sv = hv2[0] + hv2[1], sq = hv2[0] * hv2[0] + hv2[1] * hv2[1];
      sv += __shfl_xor(sv, 1); sq += __shfl_xor(sq, 1);
      sv += __shfl_xor(sv, 2); sq += __shfl_xor(sq, 2);
      sv += __shfl_xor(sv, 4); sq += __shfl_xor(sq, 4);
      if ((tid & 7) == 0){
        stfc(A.statsR + (size_t)t * 4096 + (blk - 64) * 64 + n_c, sv);
        stfc(A.statsR + (size_t)t * 4096 + (blk - 64) * 64 + 32 + n_c, sq);
      }
      gbar(A.bar, ++ep);
      // PC: gh1 on h1_t (cached ring, for next step's PB), overlaps PE
      ar[0] = FZ; ar[1] = FZ; az[0] = FZ; az[1] = FZ; ani[0] = FZ; ani[1] = FZ; anh[0] = FZ; anh[1] = FZ;
      #pragma unroll
      for (int ch = 0; ch < 8; ++ch){
        short8 a0 = ld8(h1T + r * 1024 + kq + ch * 32 + g4 * 8);
        short8 a1 = ld8(h1T + (16 + r) * 1024 + kq + ch * 32 + g4 * 8);
        ar[0] = mfma16(a0, wh[ch], ar[0]);        ar[1] = mfma16(a1, wh[ch], ar[1]);
        az[0] = mfma16(a0, wh[8 + ch], az[0]);    az[1] = mfma16(a1, wh[8 + ch], az[1]);
        anh[0] = mfma16(a0, wh[16 + ch], anh[0]); anh[1] = mfma16(a1, wh[16 + ch], anh[1]);
      }
      gbar(A.bar, ++ep);
    }
  } else if (blk < 196){
    // ---------------- PE: pred / emb_{t+1} / Gx_{t+1} on h1 (LN folded) ----------------
    const int tile = (blk - 128) * 4 + q;     // 0..271
    int jt, c0;
    const u16* wsrc; const float *Sv, *Bv;
    if (tile < 16)      { jt = 0; c0 = tile * 16;        wsrc = A.wpg;  Sv = A.Sp; Bv = A.Bp; }
    else if (tile < 80) { jt = 1; c0 = (tile - 16) * 16; wsrc = A.Wdpg; Sv = A.S1; Bv = A.B1; }
    else                { jt = 2; c0 = (tile - 80) * 16; wsrc = A.Wgpg; Sv = A.S2; Bv = A.B2; }
    short8 w[32];
    #pragma unroll
    for (int ch = 0; ch < 32; ++ch)
      w[ch] = ld8(wsrc + (size_t)(c0 + r) * 1024 + ch * 32 + g4 * 8);
    const float Sc = Sv[c0 + r], Bc = Bv[c0 + r];
    const int col = c0 + r;
    int ep = 1; gbar(A.bar, ep);
    #pragma unroll 1
    for (int t = 0; t < DEC_STEPS; ++t){
      const u16*   h1T = A.h1R + (size_t)t * 32768;
      const float* stT = A.statsR + (size_t)t * 4096;
      gbar(A.bar, ++ep);   // PA idle
      gbar(A.bar, ++ep);   // PB idle
      // PC (cached ring reads)
      float sacc = 0.f;
      #pragma unroll
      for (int b2 = 0; b2 < 64; ++b2) sacc += stT[b2 * 64 + lane];
      float muA[2][4], rsA[2][4];
      #pragma unroll
      for (int m = 0; m < 2; ++m)
        #pragma unroll
        for (int j = 0; j < 4; ++j){
          int n = m * 16 + g4 * 4 + j;
          float sv = __shfl(sacc, n), sq = __shfl(sacc, 32 + n);
          float mu = sv * (1.f / 1024.f);
          muA[m][j] = mu;
          rsA[m][j] = rsqrtf(sq * (1.f / 1024.f) - mu * mu + 1e-5f);
        }
      f32x4 a0 = FZ, a1 = FZ;
      #pragma unroll
      for (int ch = 0; ch < 32; ++ch){
        short8 x0 = ld8(h1T + r * 1024 + ch * 32 + g4 * 8);
        short8 x1 = ld8(h1T + (16 + r) * 1024 + ch * 32 + g4 * 8);
        a0 = mfma16(x0, w[ch], a0);
        a1 = mfma16(x1, w[ch], a1);
      }
      u16* embN = A.embR + (size_t)(t + 1) * 32768;
      #pragma unroll
      for (int m = 0; m < 2; ++m)
        #pragma unroll
        for (int j = 0; j < 4; ++j){
          int n = m * 16 + g4 * 4 + j;
          float acc = (m ? a1[j] : a0[j]);
          float v = rsA[m][j] * (acc - muA[m][j] * Sc) + Bc;
          if (jt == 0){
            A.out[(size_t)n * (256 * 540) + (size_t)col * 540 + t] = v;   // cached; kernel-end flush
          } else if (jt == 1){
            float pre = v + ldfc(A.Xal + n * 1024 + col);
            st16c(embN + n * 1024 + col, (unsigned)f2b(gelu_f(pre)));
          } else {
            stfc(A.Gx + n * 3072 + col, v + ldfc(A.Gal + n * 3072 + col));
          }
        }
      gbar(A.bar, ++ep);
    }
  } else {
    // ---------------- AL: audio/lxm partials for step t+1 ----------------
    const int wg = (blk - 196) * 4 + q;       // 0..63
    const int at0 = wg * 4;
    short8 w[48];
    float vb[4];
    #pragma unroll
    for (int j = 0; j < 4; ++j){
      int at = at0 + j;
      if (at < 64){
        #pragma unroll
        for (int ch = 0; ch < 12; ++ch)
          w[j * 12 + ch] = ld8(A.wd + (size_t)(at * 16 + r) * 640 + 256 + ch * 32 + g4 * 8);
        vb[j] = A.vX[at * 16 + r];
      } else {
        #pragma unroll
        for (int ch = 0; ch < 12; ++ch)
          w[j * 12 + ch] = ld8(A.wih0 + (size_t)((at - 64) * 16 + r) * 1664 + 1280 + ch * 32 + g4 * 8);
        vb[j] = A.vG[(at - 64) * 16 + r];
      }
    }
    int ep = 1; gbar(A.bar, ep);
    #pragma unroll 1
    for (int t = 0; t < DEC_STEPS; ++t){
      gbar(A.bar, ++ep);   // PA idle
      // PB: aud_seq/lxm_b read-only -> normal cached loads
      int tn = t + 1; if (tn > 539) tn = 539;
      int bn = tn / 30;
      short8 af0[12], af1[12];
      #pragma unroll
      for (int ch = 0; ch < 12; ++ch){
        int kk = ch * 32 + g4 * 8;
        if (ch < 8){
          af0[ch] = ld8(A.aud_seq + ((size_t)tn * 32 + r) * 256 + kk);
          af1[ch] = ld8(A.aud_seq + ((size_t)tn * 32 + 16 + r) * 256 + kk);
        } else {
          af0[ch] = ld8(A.lxm_b + ((size_t)bn * 32 + r) * 128 + kk - 256);
          af1[ch] = ld8(A.lxm_b + ((size_t)bn * 32 + 16 + r) * 128 + kk - 256);
        }
      }
      #pragma unroll
      for (int j = 0; j < 4; ++j){
        f32x4 c0a = FZ, c1a = FZ;
        #pragma unroll
        for (int ch = 0; ch < 12; ++ch){
          c0a = mfma16(af0[ch], w[j * 12 + ch], c0a);
          c1a = mfma16(af1[ch], w[j * 12 + ch], c1a);
        }
        int at = at0 + j;
        #pragma unroll
        for (int m = 0; m < 2; ++m)
          #pragma unroll
          for (int jj = 0; jj < 4; ++jj){
            int n = m * 16 + g4 * 4 + jj;
            float v = (m ? c1a[jj] : c0a[jj]) + vb[j];
            if (at < 64) stfc(A.Xal + n * 1024 + at * 16 + r, v);
            else         stfc(A.Gal + n * 3072 + (at - 64) * 16 + r, v);
          }
      }
      gbar(A.bar, ++ep);   // end PB
      gbar(A.bar, ++ep);   // PC idle
    }
  }
}

// ---------------------------------------------------------------------------

extern "C" void kernel_launch(void* const* d_in, const int* in_sizes, int n_in,
                              void* d_out, int out_size, void* d_ws, size_t ws_size,
                              hipStream_t stream) {
  enum { I_AUD=0, I_MO=1, I_LXM=2, I_AEW0=3, I_AEB0=4, I_AEW1=5, I_AEB1=6, I_AEW2=7, I_AEB2=8,
         I_AEW3=9, I_AEB3=10, I_AELNG=11, I_AELNB=12, I_CIW0=13, I_CIB0=14, I_CIW1=15, I_CIB1=16,
         I_CIW2=17, I_CIB2=18, I_DECW=19, I_DECB=20, I_WIH0=21, I_WHH0=22, I_BIH0=23, I_BHH0=24,
         I_WIH1=25, I_WHH1=26, I_BIH1=27, I_BHH1=28, I_LNG=29, I_LNB=30, I_PREDW=31, I_PREDB=32 };

  char* base = (char*)d_ws;
  size_t off = 0;
  auto alloc = [&](size_t bytes)->void*{
    void* p = base + off;
    off += (bytes + 255) & ~(size_t)255;
    return p;
  };

  // bf16 weight blobs
  u16* wd_b   = (u16*)alloc((size_t)1024*640*2);
  u16* wih0_b = (u16*)alloc((size_t)3072*1664*2);
  u16* whh0_b = (u16*)alloc((size_t)3072*1024*2);
  u16* wih1_b = (u16*)alloc((size_t)3072*1024*2);
  u16* whh1_b = (u16*)alloc((size_t)3072*1024*2);
  u16* wc0    = (u16*)alloc((size_t)1024*384*2);
  u16* wc1    = (u16*)alloc((size_t)1024*1024*2);
  u16* wc2    = (u16*)alloc((size_t)2048*1024*2);
  u16* w0k    = (u16*)alloc((size_t)256*896*2);
  u16* w1k    = (u16*)alloc((size_t)256*1280*2);
  u16* w2k    = (u16*)alloc((size_t)256*1024*2);
  u16* w3k    = (u16*)alloc((size_t)256*256*2);
  u16* wpT    = (u16*)alloc((size_t)1024*256*2);
  u16* wpg    = (u16*)alloc((size_t)256*1024*2);
  u16* Wdpg   = (u16*)alloc((size_t)1024*1024*2);
  u16* Wgpg   = (u16*)alloc((size_t)3072*1024*2);
  float* Sp = (float*)alloc(256*4);   float* Bp = (float*)alloc(256*4);
  float* S1 = (float*)alloc(1024*4);  float* B1 = (float*)alloc(1024*4);
  float* S2 = (float*)alloc(3072*4);  float* B2 = (float*)alloc(3072*4);
  float* vX = (float*)alloc(1024*4);  float* vG = (float*)alloc(3072*4);
  // sequences / state
  u16* aud_seq = (u16*)alloc((size_t)540*32*256*2);
  u16* lxm_b   = (u16*)alloc((size_t)18*32*128*2);
  u16* xc      = (u16*)alloc((size_t)32*384*2);
  u16* xc0     = (u16*)alloc((size_t)32*640*2);
  u16* ci1     = (u16*)alloc((size_t)32*1024*2);
  u16* ci2     = (u16*)alloc((size_t)32*1024*2);
  float* hraw  = (float*)alloc((size_t)32*2048*4);
  u16* h0i     = (u16*)alloc((size_t)32*1024*2);
  u16* h1i     = (u16*)alloc((size_t)32*1024*2);
  float* h0f   = (float*)alloc((size_t)32*1024*4);
  float* h1f   = (float*)alloc((size_t)32*1024*4);
  u16* pre_mo  = (u16*)alloc((size_t)32*256*2);
  float* Gx    = (float*)alloc((size_t)32*3072*4);
  float* Xal   = (float*)alloc((size_t)32*1024*4);
  float* Gal   = (float*)alloc((size_t)32*3072*4);
  int* bar     = (int*)alloc(16384);
  // encoder transients (dead before decode) -- rings alias this region
  char* enc_base = base + off;
  u16* O0   = (u16*)alloc((size_t)48384*256*2);
  u16* O1   = (u16*)alloc((size_t)46080*256*2);
  u16* O2   = (u16*)alloc((size_t)23040*256*2);
  float* O3 = (float*)alloc((size_t)23040*256*4);
  u16* Abuf = (u16*)alloc((size_t)23040*1280*2);
  // composition temps alias Abuf (free after conv GEMMs)
  float* Wdp_f = (float*)Abuf;                                  // 4 MB
  float* Wgp_f = (float*)((char*)Abuf + (size_t)1024*1024*4 + 256);  // 12.6 MB
  // rings alias the encoder region (<=110 MB of its 136 MB)
  u16* embR     = (u16*)enc_base;                  // 541 slots x 64 KB
  u16* h0R      = embR + (size_t)541*32768;        // 540 slots x 64 KB
  u16* h1R      = h0R + (size_t)540*32768;         // 540 slots x 64 KB
  float* statsR = (float*)(h1R + (size_t)540*32768); // 540 slots x 16 KB
  (void)ws_size; (void)in_sizes; (void)n_in; (void)out_size;

  const float* aud = (const float*)d_in[I_AUD];
  const float* mo  = (const float*)d_in[I_MO];
  const float* lxm = (const float*)d_in[I_LXM];
  float* out = (float*)d_out;

  auto cdiv = [](long long a, long long b)->int{ return (int)((a + b - 1) / b); };
  auto cvt = [&](int idx, u16* dst, int n){
    f2b_k<<<cdiv(n,256), 256, 0, stream>>>((const float*)d_in[idx], dst, n);
  };

  // ---- weight conversion ----
  cvt(I_DECW, wd_b,   1024*640);
  cvt(I_WIH0, wih0_b, 3072*1664);
  cvt(I_WHH0, whh0_b, 3072*1024);
  cvt(I_WIH1, wih1_b, 3072*1024);
  cvt(I_WHH1, whh1_b, 3072*1024);
  cvt(I_CIW0, wc0,    1024*384);
  cvt(I_CIW1, wc1,    1024*1024);
  cvt(I_CIW2, wc2,    2048*1024);
  cvt(I_AEW0, w0k,    256*896);
  cvt(I_AEW1, w1k,    256*1280);
  cvt(I_AEW2, w2k,    256*1024);
  cvt(I_AEW3, w3k,    256*256);

  // ---- encoder ----
  for (int c = 0; c < 2; ++c){
    int row0 = c * 24192;
    long long tot = (long long)24192 * 896;
    im2col0_k<<<cdiv(tot,256), 256, 0, stream>>>(aud, Abuf, row0, tot);
    gemm_bt<<<dim3(24192/64, 4), 256, 0, stream>>>(Abuf, 896, w0k, 896, (const float*)d_in[I_AEB0],
        O0 + (size_t)row0*256, 24192, 256, 896, GELU_FLG|BF16_FLG);
  }
  for (int c = 0; c < 2; ++c){
    int row0 = c * 23040;
    long long tot = (long long)23040 * 1280;
    im2col1_k<<<cdiv(tot,256), 256, 0, stream>>>(O0, Abuf, row0, tot);
    gemm_bt<<<dim3(23040/64, 4), 256, 0, stream>>>(Abuf, 1280, w1k, 1280, (const float*)d_in[I_AEB1],
        O1 + (size_t)row0*256, 23040, 256, 1280, GELU_FLG|BF16_FLG);
  }
  {
    long long tot = (long long)23040 * 1024;
    im2col2_k<<<cdiv(tot,256), 256, 0, stream>>>(O1, Abuf, 0, tot);
    gemm_bt<<<dim3(23040/64, 4), 256, 0, stream>>>(Abuf, 1024, w2k, 1024, (const float*)d_in[I_AEB2],
        O2, 23040, 256, 1024, GELU_FLG|BF16_FLG);
  }
  gemm_bt<<<dim3(23040/64, 4), 256, 0, stream>>>(O2, 256, w3k, 256, (const float*)d_in[I_AEB3],
      O3, 23040, 256, 256, GELU_FLG);
  enc_ln_k<<<4320, 256, 0, stream>>>(O3, (const float*)d_in[I_AELNG], (const float*)d_in[I_AELNB], aud_seq);

  // ---- lxm + cell-init chain ----
  lxm_g_k<<<cdiv(18*32*128,256), 256, 0, stream>>>(lxm, lxm_b);
  gather_xc_k<<<cdiv(32*384,256), 256, 0, stream>>>(mo, lxm, xc, pre_mo);
  gemm_bt<<<dim3(1,16), 256, 0, stream>>>(xc, 384, wc0, 384, (const float*)d_in[I_CIB0],
      ci1, 32, 1024, 384, GELU_FLG|BF16_FLG);
  gemm_bt<<<dim3(1,16), 256, 0, stream>>>(ci1, 1024, wc1, 1024, (const float*)d_in[I_CIB1],
      ci2, 32, 1024, 1024, GELU_FLG|BF16_FLG);
  gemm_bt<<<dim3(1,32), 256, 0, stream>>>(ci2, 1024, wc2, 1024, (const float*)d_in[I_CIB2],
      hraw, 32, 2048, 1024, 0);
  split_h_k<<<cdiv(32*1024,256), 256, 0, stream>>>(hraw, h0i, h1i, h0f, h1f);

  // ---- composition precompute ----
  t_wpT_k<<<cdiv(1024*256,256), 256, 0, stream>>>((const float*)d_in[I_PREDW], wpT);
  // Wdp = Wd_p @ Wp  (wd cols 0..255), Wgp = Wih0_p @ Wp (wih0 cols 1024..1279)
  gemm_bt<<<dim3(16,16), 256, 0, stream>>>(wd_b, 640, wpT, 256, nullptr, Wdp_f, 1024, 1024, 256, 0);
  gemm_bt<<<dim3(48,16), 256, 0, stream>>>(wih0_b + 1024, 1664, wpT, 256, nullptr, Wgp_f, 3072, 1024, 256, 0);
  foldW_k<<<cdiv(1024,4), 256, 0, stream>>>(Wdp_f, (const float*)d_in[I_LNG], (const float*)d_in[I_LNB],
      nullptr, Wdpg, S1, B1, 1024);
  foldW_k<<<cdiv(3072,4), 256, 0, stream>>>(Wgp_f, (const float*)d_in[I_LNG], (const float*)d_in[I_LNB],
      nullptr, Wgpg, S2, B2, 3072);
  foldW_k<<<cdiv(256,4), 256, 0, stream>>>((const float*)d_in[I_PREDW], (const float*)d_in[I_LNG],
      (const float*)d_in[I_LNB], (const float*)d_in[I_PREDB], wpg, Sp, Bp, 256);
  // vX = db + Wd_p @ pb ; vG = Wih0_p @ pb
  vfold_k<<<cdiv(1024,4), 256, 0, stream>>>((const float*)d_in[I_DECW], 640, 0,
      (const float*)d_in[I_PREDB], (const float*)d_in[I_DECB], vX, 1024);
  vfold_k<<<cdiv(3072,4), 256, 0, stream>>>((const float*)d_in[I_WIH0], 1664, 1024,
      (const float*)d_in[I_PREDB], nullptr, vG, 3072);

  // ---- t=0 boot values: emb_0 (ring slot 0) and Gx_0 from the real xcat_0 ----
  build_xc0_k<<<cdiv(32*640,256), 256, 0, stream>>>(pre_mo, aud_seq, lxm_b, xc0);
  gemm_bt<<<dim3(1,16), 256, 0, stream>>>(xc0, 640, wd_b, 640, (const float*)d_in[I_DECB],
      embR, 32, 1024, 640, GELU_FLG|BF16_FLG);
  gemm_bt<<<dim3(1,48), 256, 0, stream>>>(xc0, 640, wih0_b + 1024, 1664, nullptr,
      Gx, 32, 3072, 640, 0);

  hipMemsetAsync(bar, 0, 16384, stream);

  // ---- persistent decoder ----
  DecArgs da;
  da.aud_seq = aud_seq; da.lxm_b = lxm_b;
  da.wih0 = wih0_b; da.whh0 = whh0_b; da.wih1 = wih1_b; da.whh1 = whh1_b; da.wd = wd_b;
  da.wpg = wpg; da.Wdpg = Wdpg; da.Wgpg = Wgpg;
  da.Sp = Sp; da.Bp = Bp; da.S1 = S1; da.B1 = B1; da.S2 = S2; da.B2 = B2; da.vX = vX; da.vG = vG;
  da.bih0 = (const float*)d_in[I_BIH0]; da.bhh0 = (const float*)d_in[I_BHH0];
  da.bih1 = (const float*)d_in[I_BIH1]; da.bhh1 = (const float*)d_in[I_BHH1];
  da.h0init = h0i; da.h1init = h1i;
  da.embR = embR; da.h0R = h0R; da.h1R = h1R; da.statsR = statsR;
  da.h0f = h0f; da.h1f = h1f; da.Gx = Gx; da.Xal = Xal; da.Gal = Gal;
  da.out = out; da.bar = bar;
  decode_k<<<dim3(NBLK), dim3(256), 0, stream>>>(da);
}